// Round 1
// 1624.654 us; speedup vs baseline: 1.0047x; 1.0047x over previous
//
#include <hip/hip_runtime.h>
#include <math.h>

#define N_NODES 100000
#define N_EDGES 3200000
#define HDIM 128

// csr_fill windowing: 8 dst-windows (one per XCD), edge list cut into slices
#define NWIN 8
#define WINSZ 12500                 // ceil(100000 / 8)
#define NSLICE 128
#define SLICE_E (N_EDGES / NSLICE)  // 25000, multiple of 4

typedef __attribute__((ext_vector_type(8))) short bf16x8;
typedef __attribute__((ext_vector_type(4))) float f32x4;

__device__ __forceinline__ unsigned short f2bf(float f) {
  union { float f; unsigned u; } v; v.f = f;
  unsigned r = v.u + 0x7fffu + ((v.u >> 16) & 1u);
  return (unsigned short)(r >> 16);
}
__device__ __forceinline__ float bflo(unsigned p) {
  union { unsigned u; float f; } v; v.u = p << 16; return v.f;
}
__device__ __forceinline__ float bfhi(unsigned p) {
  union { unsigned u; float f; } v; v.u = p & 0xffff0000u; return v.f;
}

// ---------------------------------------------------------------------------
__global__ __launch_bounds__(256) void zero_i32(int* __restrict__ p, int n) {
  int i = blockIdx.x * 256 + threadIdx.x;
  if (i < n) p[i] = 0;
}
__global__ __launch_bounds__(256) void zero_f32(float* __restrict__ p, int n) {
  int i = blockIdx.x * 256 + threadIdx.x;
  if (i < n) p[i] = 0.f;
}

// ---------------------------------------------------------------------------
// Repack a [384][128] fp32 weight matrix (row-major [col][k]) into
// MFMA-B-fragment-ordered bf16 (lane*16B contiguous per fragment).
// ---------------------------------------------------------------------------
__global__ __launch_bounds__(256) void repack_frag_b(
    const float* __restrict__ src, short* __restrict__ dst)
{
  int o = blockIdx.x * 256 + threadIdx.x;      // 0 .. 384*128-1
  if (o >= 384 * 128) return;
  int j    = o & 7;
  int lane = (o >> 3) & 63;
  int ks   = (o >> 9) & 3;
  int t    = o >> 11;
  int m  = lane & 15;
  int g4 = lane >> 4;
  dst[o] = (short)f2bf(src[(t * 16 + m) * 128 + ks * 32 + g4 * 8 + j]);
}

// ---------------------------------------------------------------------------
// Tiled fp32 GEMM, K fixed at 128 (emb, weight folds). Optional bf16-pack
// epilogue mirror (xpack != nullptr -> also emit packed bf16 rows).
// ---------------------------------------------------------------------------
template<bool BT>
__global__ __launch_bounds__(256) void gemm_k128(
    const float* __restrict__ A, const float* __restrict__ W,
    const float* __restrict__ bias, float* __restrict__ Y,
    unsigned* __restrict__ xpack, int M, int OUT)
{
  __shared__ alignas(16) float lds_a[32 * 68];
  __shared__ alignas(16) float lds_b[32 * 132];
  const int tid = threadIdx.x;
  const int tx = tid & 15;
  const int ty = tid >> 4;
  const int rowBase = blockIdx.x * 64;
  const int colBase = blockIdx.y * 128;

  float acc[4][8];
#pragma unroll
  for (int r = 0; r < 4; r++)
#pragma unroll
    for (int c = 0; c < 8; c++) acc[r][c] = 0.f;

  for (int k0 = 0; k0 < 128; k0 += 32) {
#pragma unroll
    for (int i = 0; i < 2; i++) {
      int idx = tid + i * 256;
      int r   = idx >> 3;
      int kk  = (idx & 7) << 2;
      int gr  = rowBase + r;
      float4 v = make_float4(0.f, 0.f, 0.f, 0.f);
      if (gr < M) v = *(const float4*)(A + (size_t)gr * HDIM + k0 + kk);
      lds_a[(kk + 0) * 68 + r] = v.x;
      lds_a[(kk + 1) * 68 + r] = v.y;
      lds_a[(kk + 2) * 68 + r] = v.z;
      lds_a[(kk + 3) * 68 + r] = v.w;
    }
    if (!BT) {
#pragma unroll
      for (int i = 0; i < 4; i++) {
        int idx = tid + i * 256;
        int kk  = idx >> 5;
        int j   = (idx & 31) << 2;
        int gj  = colBase + j;
        float4 v = make_float4(0.f, 0.f, 0.f, 0.f);
        if (gj < OUT) v = *(const float4*)(W + (size_t)(k0 + kk) * OUT + gj);
        *((float4*)&lds_b[kk * 132 + j]) = v;
      }
    } else {
#pragma unroll
      for (int i = 0; i < 4; i++) {
        int idx = tid + i * 256;
        int j   = idx >> 3;
        int k4  = (idx & 7) << 2;
        int gj  = colBase + j;
        float4 v = make_float4(0.f, 0.f, 0.f, 0.f);
        if (gj < OUT) v = *(const float4*)(W + (size_t)gj * HDIM + k0 + k4);
        lds_b[(k4 + 0) * 132 + j] = v.x;
        lds_b[(k4 + 1) * 132 + j] = v.y;
        lds_b[(k4 + 2) * 132 + j] = v.z;
        lds_b[(k4 + 3) * 132 + j] = v.w;
      }
    }
    __syncthreads();
#pragma unroll 8
    for (int kk = 0; kk < 32; kk++) {
      float4 a4 = *(const float4*)&lds_a[kk * 68 + ty * 4];
      float4 b0 = *(const float4*)&lds_b[kk * 132 + tx * 8];
      float4 b1 = *(const float4*)&lds_b[kk * 132 + tx * 8 + 4];
      float av[4] = {a4.x, a4.y, a4.z, a4.w};
      float bv[8] = {b0.x, b0.y, b0.z, b0.w, b1.x, b1.y, b1.z, b1.w};
#pragma unroll
      for (int r = 0; r < 4; r++)
#pragma unroll
        for (int c = 0; c < 8; c++)
          acc[r][c] = fmaf(av[r], bv[c], acc[r][c]);
    }
    __syncthreads();
  }

  int col = colBase + tx * 8;
  if (col >= OUT) return;
  float bv[8];
#pragma unroll
  for (int c = 0; c < 8; c++) bv[c] = bias ? bias[col + c] : 0.f;
#pragma unroll
  for (int r = 0; r < 4; r++) {
    int gr = rowBase + ty * 4 + r;
    if (gr >= M) continue;
    float* yp = Y + (size_t)gr * OUT + col;
    float4 o0 = make_float4(acc[r][0] + bv[0], acc[r][1] + bv[1],
                            acc[r][2] + bv[2], acc[r][3] + bv[3]);
    float4 o1 = make_float4(acc[r][4] + bv[4], acc[r][5] + bv[5],
                            acc[r][6] + bv[6], acc[r][7] + bv[7]);
    *(float4*)yp       = o0;
    *(float4*)(yp + 4) = o1;
    if (xpack) {                       // packed bf16 mirror (emb path)
      uint4 p;
      p.x = (unsigned)f2bf(o0.x) | ((unsigned)f2bf(o0.y) << 16);
      p.y = (unsigned)f2bf(o0.z) | ((unsigned)f2bf(o0.w) << 16);
      p.z = (unsigned)f2bf(o1.x) | ((unsigned)f2bf(o1.y) << 16);
      p.w = (unsigned)f2bf(o1.z) | ((unsigned)f2bf(o1.w) << 16);
      *(uint4*)&xpack[(size_t)gr * 64 + (col >> 1)] = p;
    }
  }
}

// ---------------------------------------------------------------------------
// CSR build (by destination), edges packed as int2{src, w_bits}.
// ---------------------------------------------------------------------------
__global__ __launch_bounds__(256) void csr_hist(
    const int* __restrict__ ei, int* __restrict__ deg)
{
  int e = blockIdx.x * 256 + threadIdx.x;
  if (e < N_EDGES) atomicAdd(&deg[ei[N_EDGES + e]], 1);
}

// ---- hierarchical exclusive scan of deg[N] -> rowptr[N+1] ----
__global__ __launch_bounds__(256) void scan_blk(
    const int* __restrict__ deg, int* __restrict__ rowptr,
    int* __restrict__ blksum)
{
  __shared__ int lds[256];
  int tid  = threadIdx.x;
  int idx0 = blockIdx.x * 2048 + tid * 8;
  int v[8];
  int local = 0;
#pragma unroll
  for (int j = 0; j < 8; j++) {
    int i = idx0 + j;
    v[j] = (i < N_NODES) ? deg[i] : 0;
    local += v[j];
  }
  lds[tid] = local;
  __syncthreads();
  int inc = local;
  for (int off = 1; off < 256; off <<= 1) {
    int t = (tid >= off) ? lds[tid - off] : 0;
    __syncthreads();
    lds[tid] += t;
    __syncthreads();
  }
  int run = lds[tid] - inc;
#pragma unroll
  for (int j = 0; j < 8; j++) {
    int i = idx0 + j;
    if (i < N_NODES) rowptr[i] = run;
    run += v[j];
  }
  if (tid == 255) blksum[blockIdx.x] = lds[255];
}

__global__ void scan_top(int* __restrict__ blksum, int nblk,
                         int* __restrict__ rowptr)
{
  int tid = threadIdx.x;             // 64 threads
  int orig = (tid < nblk) ? blksum[tid] : 0;
  int v = orig;
  for (int off = 1; off < 64; off <<= 1) {
    int t = __shfl_up(v, off, 64);
    if (tid >= off) v += t;
  }
  if (tid < nblk) blksum[tid] = v - orig;
  if (tid == 63) rowptr[N_NODES] = v;
}

__global__ __launch_bounds__(256) void scan_add(
    int* __restrict__ rowptr, const int* __restrict__ blksum)
{
  int i = blockIdx.x * 256 + threadIdx.x;
  if (i < N_NODES) rowptr[i] += blksum[i >> 11];
}

// ---------------------------------------------------------------------------
// XCD-windowed CSR fill. Grid (NWIN, NSLICE), blockIdx.x = dst-window.
// Linear workgroup id = bx + NWIN*by  ==> id % 8 == bx, so all blocks of a
// window land on the same XCD (round-robin dispatch). Each window's epak
// region (~3.2 MB) then stays resident in ONE XCD's L2: the 8 partial 8-B
// writes per 64-B line merge locally before a single full-line eviction,
// instead of 8 cross-XCD partial evictions (measured 200 MB WRITE_SIZE).
// Cost: dst[] is re-scanned once per window (L3-resident after csr_hist).
// ---------------------------------------------------------------------------
__global__ __launch_bounds__(256) void csr_fill_win(
    const int* __restrict__ ei, const float* __restrict__ ew,
    const int* __restrict__ rowptr, int* __restrict__ cnt,
    int2* __restrict__ epak)
{
  const int w  = blockIdx.x;                  // 0..7  == target XCD
  const int lo = w * WINSZ, hi = lo + WINSZ;
  const int e0 = blockIdx.y * SLICE_E;
  const int e1 = e0 + SLICE_E;                // exact (E divisible by NSLICE)
  for (int eb = e0 + (int)threadIdx.x * 4; eb < e1; eb += 1024) {
    int4 d4 = *(const int4*)(ei + N_EDGES + eb);
    int dv[4] = {d4.x, d4.y, d4.z, d4.w};
#pragma unroll
    for (int j = 0; j < 4; j++) {
      int d = dv[j];
      if (d >= lo && d < hi) {
        int e = eb + j;
        int pos = rowptr[d] + atomicAdd(&cnt[d], 1);
        epak[pos] = make_int2(ei[e], __float_as_int(ew[e]));
      }
    }
  }
}

// ---------------------------------------------------------------------------
// Pull aggregation on bf16 x: z[n] = sum w_e * x[src_e], fp32 accumulate,
// bf16 packed output. One wave/node, lane covers cols {2*lane, 2*lane+1}.
// ---------------------------------------------------------------------------
__global__ __launch_bounds__(256) void agg_pull(
    const unsigned* __restrict__ xbp, const int* __restrict__ rowptr,
    const int2* __restrict__ epak, unsigned* __restrict__ zbp)
{
  int node = blockIdx.x * 4 + (threadIdx.x >> 6);
  if (node >= N_NODES) return;
  int lane = threadIdx.x & 63;
  int s0 = rowptr[node], s1 = rowptr[node + 1];
  float v0 = 0.f, v1 = 0.f;
  int e = s0;
  for (; e + 3 < s1; e += 4) {
    int2 e0 = epak[e], e1 = epak[e + 1], e2 = epak[e + 2], e3 = epak[e + 3];
    unsigned p0 = xbp[(size_t)e0.x * 64 + lane];
    unsigned p1 = xbp[(size_t)e1.x * 64 + lane];
    unsigned p2 = xbp[(size_t)e2.x * 64 + lane];
    unsigned p3 = xbp[(size_t)e3.x * 64 + lane];
    float w0 = __int_as_float(e0.y), w1 = __int_as_float(e1.y);
    float w2 = __int_as_float(e2.y), w3 = __int_as_float(e3.y);
    v0 = fmaf(w0, bflo(p0), v0); v1 = fmaf(w0, bfhi(p0), v1);
    v0 = fmaf(w1, bflo(p1), v0); v1 = fmaf(w1, bfhi(p1), v1);
    v0 = fmaf(w2, bflo(p2), v0); v1 = fmaf(w2, bfhi(p2), v1);
    v0 = fmaf(w3, bflo(p3), v0); v1 = fmaf(w3, bfhi(p3), v1);
  }
  for (; e < s1; e++) {
    int2 ep = epak[e];
    unsigned p = xbp[(size_t)ep.x * 64 + lane];
    float w = __int_as_float(ep.y);
    v0 = fmaf(w, bflo(p), v0); v1 = fmaf(w, bfhi(p), v1);
  }
  zbp[(size_t)node * 64 + lane] =
      (unsigned)f2bf(v0) | ((unsigned)f2bf(v1) << 16);
}

// ---------------------------------------------------------------------------
// Fused GRU layer (bf16 MFMA), v2 partition: block = 64 rows; each of the
// 4 waves owns 2 of the 8 t-column-tiles (32 gate-cols x 3 gates) for ALL
// 64 rows. B-frag loads amortize over 4 row-tiles -> 4:1 MFMA:VMEM with
// 4-way independent MFMAs per load. Accums: 4rt x 2t x 4 sets = 128 VGPR.
// ---------------------------------------------------------------------------
__global__ __launch_bounds__(256) void gru_fused(
    const short* __restrict__ zb, short* __restrict__ xb,
    float* __restrict__ x,
    const short* __restrict__ Fb, const short* __restrict__ Wb,
    const float* __restrict__ bih, const float* __restrict__ bhh)
{
  const int wave = threadIdx.x >> 6, lane = threadIdx.x & 63;
  const int m  = lane & 15;
  const int g4 = lane >> 4;
  const int rowBase = blockIdx.x * 64;
  const int t0 = wave * 2;                 // this wave's t-pair (cols t0*16..)

  f32x4 aR[4][2], aZ[4][2], aN[4][2], aH[4][2];
#pragma unroll
  for (int rt = 0; rt < 4; rt++)
#pragma unroll
    for (int ti = 0; ti < 2; ti++) {
      aR[rt][ti] = (f32x4){0.f, 0.f, 0.f, 0.f};
      aZ[rt][ti] = (f32x4){0.f, 0.f, 0.f, 0.f};
      aN[rt][ti] = (f32x4){0.f, 0.f, 0.f, 0.f};
      aH[rt][ti] = (f32x4){0.f, 0.f, 0.f, 0.f};
    }

  size_t arowc[4];
#pragma unroll
  for (int rt = 0; rt < 4; rt++) {
    int arow = rowBase + rt * 16 + m;
    arowc[rt] = (size_t)(arow < N_NODES ? arow : N_NODES - 1) * 128 + g4 * 8;
  }

  // ---- phase 0: z @ F -> r,z,i_n ----
#pragma unroll
  for (int ks = 0; ks < 4; ks++) {
    bf16x8 a[4];
#pragma unroll
    for (int rt = 0; rt < 4; rt++)
      a[rt] = *(const bf16x8*)(zb + arowc[rt] + ks * 32);
    const int bo = ks * 512 + lane * 8;
#pragma unroll
    for (int ti = 0; ti < 2; ti++) {
      const short* bp = Fb + (t0 + ti) * 2048 + bo;
      bf16x8 br = *(const bf16x8*)(bp);
      bf16x8 bz = *(const bf16x8*)(bp + 16384);
      bf16x8 bn = *(const bf16x8*)(bp + 32768);
#pragma unroll
      for (int rt = 0; rt < 4; rt++) {
        aR[rt][ti] = __builtin_amdgcn_mfma_f32_16x16x32_bf16(a[rt], br, aR[rt][ti], 0, 0, 0);
        aZ[rt][ti] = __builtin_amdgcn_mfma_f32_16x16x32_bf16(a[rt], bz, aZ[rt][ti], 0, 0, 0);
        aN[rt][ti] = __builtin_amdgcn_mfma_f32_16x16x32_bf16(a[rt], bn, aN[rt][ti], 0, 0, 0);
      }
    }
  }
  // ---- phase 1: x @ Whh^T -> r,z,h_n ----
#pragma unroll
  for (int ks = 0; ks < 4; ks++) {
    bf16x8 a[4];
#pragma unroll
    for (int rt = 0; rt < 4; rt++)
      a[rt] = *(const bf16x8*)(xb + arowc[rt] + ks * 32);
    const int bo = ks * 512 + lane * 8;
#pragma unroll
    for (int ti = 0; ti < 2; ti++) {
      const short* bp = Wb + (t0 + ti) * 2048 + bo;
      bf16x8 br = *(const bf16x8*)(bp);
      bf16x8 bz = *(const bf16x8*)(bp + 16384);
      bf16x8 bn = *(const bf16x8*)(bp + 32768);
#pragma unroll
      for (int rt = 0; rt < 4; rt++) {
        aR[rt][ti] = __builtin_amdgcn_mfma_f32_16x16x32_bf16(a[rt], br, aR[rt][ti], 0, 0, 0);
        aZ[rt][ti] = __builtin_amdgcn_mfma_f32_16x16x32_bf16(a[rt], bz, aZ[rt][ti], 0, 0, 0);
        aH[rt][ti] = __builtin_amdgcn_mfma_f32_16x16x32_bf16(a[rt], bn, aH[rt][ti], 0, 0, 0);
      }
    }
  }

  // ---- epilogue: gates + state update (C/D: col=lane&15, row=g4*4+reg) ----
#pragma unroll
  for (int ti = 0; ti < 2; ti++) {
    int col = (t0 + ti) * 16 + m;
    float b_r = bih[col] + bhh[col];
    float b_z = bih[128 + col] + bhh[128 + col];
    float b_i = bih[256 + col];
    float b_h = bhh[256 + col];
#pragma unroll
    for (int rt = 0; rt < 4; rt++) {
#pragma unroll
      for (int r = 0; r < 4; r++) {
        int gr = rowBase + rt * 16 + g4 * 4 + r;
        if (gr < N_NODES) {
          float rg = 1.f / (1.f + __expf(-(aR[rt][ti][r] + b_r)));
          float zg = 1.f / (1.f + __expf(-(aZ[rt][ti][r] + b_z)));
          float ng = tanhf(aN[rt][ti][r] + b_i + rg * (aH[rt][ti][r] + b_h));
          size_t o = (size_t)gr * 128 + col;
          float xo = x[o];
          float xn = (1.f - zg) * ng + zg * xo;
          x[o] = xn;
          xb[o] = (short)f2bf(xn);
        }
      }
    }
  }
}

// ---------------------------------------------------------------------------
// BatchNorm stats (fp32 master x)
// ---------------------------------------------------------------------------
__global__ __launch_bounds__(256) void bn_stats(
    const float* __restrict__ x, float* __restrict__ sums)
{
  __shared__ float ls[256], lq[256];
  int tid  = threadIdx.x;
  int col  = tid & 127, half = tid >> 7;
  int r0   = blockIdx.x * 128;
  int rend = min(N_NODES, r0 + 128);
  float s = 0.f, q = 0.f;
  for (int r = r0 + half; r < rend; r += 2) {
    float v = x[(size_t)r * HDIM + col];
    s += v; q += v * v;
  }
  ls[tid] = s; lq[tid] = q;
  __syncthreads();
  if (tid < 128) {
    atomicAdd(&sums[col],       ls[tid] + ls[tid + 128]);
    atomicAdd(&sums[128 + col], lq[tid] + lq[tid + 128]);
  }
}

__global__ void bn_finalize(float* __restrict__ sums,
                            const float* __restrict__ gamma,
                            const float* __restrict__ beta)
{
  int j = threadIdx.x;
  float mean = sums[j] / (float)N_NODES;
  float var  = sums[128 + j] / (float)N_NODES - mean * mean;
  float inv  = rsqrtf(var + 1e-5f);
  sums[256 + j] = gamma[j] * inv;
  sums[384 + j] = beta[j] - mean * gamma[j] * inv;
}

// ---------------------------------------------------------------------------
// Fused head: out = bn(x) @ mlpW + h @ e2 + c2, BN folded into A-load of x.
// Same proven 64-row x 128-col(tiled) structure as gemm_k128; two K-passes
// (src 0: x/mlpW with BN fold, src 1: h/e2), single output write.
// ---------------------------------------------------------------------------
__global__ __launch_bounds__(256) void head_fused(
    const float* __restrict__ x, const float* __restrict__ h,
    const float* __restrict__ sums,      // scale at [256..], shift at [384..]
    const float* __restrict__ mlpW,      // [128][40]
    const float* __restrict__ e2,        // [128][40]
    const float* __restrict__ c2,        // [40]
    float* __restrict__ out)             // [N][40]
{
  __shared__ alignas(16) float lds_a[32 * 68];
  __shared__ alignas(16) float lds_b[32 * 132];
  const int tid = threadIdx.x;
  const int tx = tid & 15;
  const int ty = tid >> 4;
  const int rowBase = blockIdx.x * 64;
  const int OUT = 40;

  float acc[4][8];
#pragma unroll
  for (int r = 0; r < 4; r++)
#pragma unroll
    for (int c = 0; c < 8; c++) acc[r][c] = 0.f;

  for (int src = 0; src < 2; src++) {
    const float* A = src ? h : x;
    const float* W = src ? e2 : mlpW;
    for (int k0 = 0; k0 < 128; k0 += 32) {
#pragma unroll
      for (int i = 0; i < 2; i++) {
        int idx = tid + i * 256;
        int r   = idx >> 3;
        int kk  = (idx & 7) << 2;
        int gr  = rowBase + r;
        float4 v = make_float4(0.f, 0.f, 0.f, 0.f);
        if (gr < N_NODES) v = *(const float4*)(A + (size_t)gr * HDIM + k0 + kk);
        if (src == 0) {   // fold BatchNorm apply into the x tile load
          float4 sc = *(const float4*)(sums + 256 + k0 + kk);
          float4 sh = *(const float4*)(sums + 384 + k0 + kk);
          v.x = fmaf(v.x, sc.x, sh.x);
          v.y = fmaf(v.y, sc.y, sh.y);
          v.z = fmaf(v.z, sc.z, sh.z);
          v.w = fmaf(v.w, sc.w, sh.w);
        }
        lds_a[(kk + 0) * 68 + r] = v.x;
        lds_a[(kk + 1) * 68 + r] = v.y;
        lds_a[(kk + 2) * 68 + r] = v.z;
        lds_a[(kk + 3) * 68 + r] = v.w;
      }
#pragma unroll
      for (int i = 0; i < 4; i++) {
        int idx = tid + i * 256;
        int kk  = idx >> 5;
        int j   = (idx & 31) << 2;
        float4 v = make_float4(0.f, 0.f, 0.f, 0.f);
        if (j < OUT) v = *(const float4*)(W + (size_t)(k0 + kk) * OUT + j);
        *((float4*)&lds_b[kk * 132 + j]) = v;
      }
      __syncthreads();
#pragma unroll 8
      for (int kk = 0; kk < 32; kk++) {
        float4 a4 = *(const float4*)&lds_a[kk * 68 + ty * 4];
        float4 b0 = *(const float4*)&lds_b[kk * 132 + tx * 8];
        float4 b1 = *(const float4*)&lds_b[kk * 132 + tx * 8 + 4];
        float av[4] = {a4.x, a4.y, a4.z, a4.w};
        float bv[8] = {b0.x, b0.y, b0.z, b0.w, b1.x, b1.y, b1.z, b1.w};
#pragma unroll
        for (int r = 0; r < 4; r++)
#pragma unroll
          for (int c = 0; c < 8; c++)
            acc[r][c] = fmaf(av[r], bv[c], acc[r][c]);
      }
      __syncthreads();
    }
  }

  int col = tx * 8;
  if (col >= OUT) return;            // tx 0..4 write (cols 0..39)
  float bv[8];
#pragma unroll
  for (int c = 0; c < 8; c++) bv[c] = c2[col + c];
#pragma unroll
  for (int r = 0; r < 4; r++) {
    int gr = rowBase + ty * 4 + r;
    if (gr >= N_NODES) continue;
    float* yp = out + (size_t)gr * OUT + col;
    float4 o0 = make_float4(acc[r][0] + bv[0], acc[r][1] + bv[1],
                            acc[r][2] + bv[2], acc[r][3] + bv[3]);
    float4 o1 = make_float4(acc[r][4] + bv[4], acc[r][5] + bv[5],
                            acc[r][6] + bv[6], acc[r][7] + bv[7]);
    *(float4*)yp       = o0;
    *(float4*)(yp + 4) = o1;
  }
}

// ---------------------------------------------------------------------------
// Residual fold constants: E2 = embW @ mlpW  [128][40], c2 = mlpB + embB@mlpW
// ---------------------------------------------------------------------------
__global__ void prep_e2(const float* __restrict__ embW,
                        const float* __restrict__ embB,
                        const float* __restrict__ mlpW,
                        const float* __restrict__ mlpB,
                        float* __restrict__ e2, float* __restrict__ c2)
{
  int tid = threadIdx.x;
#pragma unroll
  for (int t = 0; t < 20; t++) {
    int idx = tid * 20 + t;
    int f = idx / 40, j = idx - f * 40;
    float s = 0.f;
    for (int k = 0; k < 128; k++)
      s = fmaf(embW[f * 128 + k], mlpW[k * 40 + j], s);
    e2[idx] = s;
  }
  if (tid < 40) {
    float s = mlpB[tid];
    for (int k = 0; k < 128; k++)
      s = fmaf(embB[k], mlpW[k * 40 + tid], s);
    c2[tid] = s;
  }
}

// ---------------------------------------------------------------------------
extern "C" void kernel_launch(void* const* d_in, const int* in_sizes, int n_in,
                              void* d_out, int out_size, void* d_ws, size_t ws_size,
                              hipStream_t stream)
{
  const float* h     = (const float*)d_in[0];
  const int*   ei    = (const int*)d_in[1];
  const float* ew    = (const float*)d_in[2];
  const float* embW  = (const float*)d_in[3];
  const float* embB  = (const float*)d_in[4];
  const float* convW = (const float*)d_in[5];   // [3][128][128]
  const float* Wih   = (const float*)d_in[6];   // [384][128]
  const float* Whh   = (const float*)d_in[7];   // [384][128]
  const float* bih   = (const float*)d_in[8];
  const float* bhh   = (const float*)d_in[9];
  const float* gamma = (const float*)d_in[10];
  const float* beta  = (const float*)d_in[11];
  const float* mlpW  = (const float*)d_in[12];
  const float* mlpB  = (const float*)d_in[13];
  float* out = (float*)d_out;

  float* ws = (float*)d_ws;
  const size_t NH = (size_t)N_NODES * HDIM;      // 12.8M
  float*    x      = ws;                          // [N][128] fp32 master
  unsigned* xbp    = (unsigned*)(ws + NH);        // [N][64] packed bf16
  unsigned* zbp    = xbp + NH / 2;                // [N][64] packed bf16
  int2*     epak   = (int2*)(zbp + NH / 2);       // [E] {src, w}
  int*      rowptr = (int*)(epak + N_EDGES);      // N+4
  int*      cnt    = rowptr + N_NODES + 4;        // N
  int*      deg    = cnt + N_NODES;               // N
  int*      blksum = deg + N_NODES;               // 64
  float*    Ffold  = (float*)(blksum + 64);       // [3][384][128] fp32
  short*    Fbp    = (short*)(Ffold + 3 * 384 * 128);  // frag-order bf16
  short*    Wbp    = Fbp + 3 * 384 * 128;         // frag-order bf16 of Whh
  float*    sums   = (float*)(Wbp + 384 * 128);
  float*    e2     = sums + 512;
  float*    c2     = e2 + 5120;
  // total ~131 MB

  dim3 blk(256);
  const int MB = (N_NODES + 63) / 64;
  const int EB = (N_EDGES + 255) / 256;
  const int RB = (384 * 128 + 255) / 256;
  const int SB = (N_NODES + 2047) / 2048;         // 49 scan blocks (<=64)

  // ---- constants ----
  prep_e2<<<1, 256, 0, stream>>>(embW, embB, mlpW, mlpB, e2, c2);
  for (int l = 0; l < 3; l++)
    gemm_k128<true><<<dim3(6, 1), blk, 0, stream>>>(
        Wih, convW + (size_t)l * HDIM * HDIM, nullptr,
        Ffold + (size_t)l * 384 * HDIM, nullptr, 384, 128);
  for (int l = 0; l < 3; l++)
    repack_frag_b<<<RB, blk, 0, stream>>>(
        Ffold + (size_t)l * 384 * HDIM, Fbp + (size_t)l * 384 * HDIM);
  repack_frag_b<<<RB, blk, 0, stream>>>(Whh, Wbp);

  // ---- CSR build ----
  zero_i32<<<(2 * N_NODES + 255) / 256, blk, 0, stream>>>(cnt, 2 * N_NODES);
  csr_hist<<<EB, blk, 0, stream>>>(ei, deg);
  scan_blk<<<SB, blk, 0, stream>>>(deg, rowptr, blksum);
  scan_top<<<1, 64, 0, stream>>>(blksum, SB, rowptr);
  scan_add<<<(N_NODES + 255) / 256, blk, 0, stream>>>(rowptr, blksum);
  csr_fill_win<<<dim3(NWIN, NSLICE), blk, 0, stream>>>(ei, ew, rowptr, cnt, epak);

  // ---- embedding: x = h @ embW + embB ; bf16 mirror fused in epilogue ----
  gemm_k128<false><<<dim3(MB, 1), blk, 0, stream>>>(h, embW, embB, x, xbp,
                                                    N_NODES, 128);

  // ---- 3 GRU layers: pull-agg (bf16) + fused MFMA GRU ----
  for (int l = 0; l < 3; l++) {
    agg_pull<<<(N_NODES + 3) / 4, blk, 0, stream>>>(xbp, rowptr, epak, zbp);
    gru_fused<<<MB, blk, 0, stream>>>(
        (const short*)zbp, (short*)xbp, x,
        Fbp + (size_t)l * 384 * HDIM, Wbp, bih, bhh);
  }

  // ---- BatchNorm stats + fully fused head (BN apply + both GEMMs) ----
  zero_f32<<<2, blk, 0, stream>>>(sums, 512);
  bn_stats<<<(N_NODES + 127) / 128, blk, 0, stream>>>(x, sums);
  bn_finalize<<<1, 128, 0, stream>>>(sums, gamma, beta);
  head_fused<<<dim3(MB, 1), blk, 0, stream>>>(x, h, sums, mlpW, e2, c2, out);
}

// Round 2
// 1387.046 us; speedup vs baseline: 1.1768x; 1.1713x over previous
//
#include <hip/hip_runtime.h>
#include <math.h>

#define N_NODES 100000
#define N_EDGES 3200000
#define HDIM 128

// ---- bucket sort CSR build ----
#define NB 196        // buckets of 512 consecutive dst nodes (100000/512 -> 196)
#define BSH 9         // 512 nodes per bucket
#define BSLOT 18432   // tmp slots per bucket (avg fill 16327, +16 sigma headroom)

typedef __attribute__((ext_vector_type(8))) short bf16x8;
typedef __attribute__((ext_vector_type(4))) float f32x4;

__device__ __forceinline__ unsigned short f2bf(float f) {
  union { float f; unsigned u; } v; v.f = f;
  unsigned r = v.u + 0x7fffu + ((v.u >> 16) & 1u);
  return (unsigned short)(r >> 16);
}
__device__ __forceinline__ float bflo(unsigned p) {
  union { unsigned u; float f; } v; v.u = p << 16; return v.f;
}
__device__ __forceinline__ float bfhi(unsigned p) {
  union { unsigned u; float f; } v; v.u = p & 0xffff0000u; return v.f;
}

// ---------------------------------------------------------------------------
__global__ __launch_bounds__(256) void zero_i32(int* __restrict__ p, int n) {
  int i = blockIdx.x * 256 + threadIdx.x;
  if (i < n) p[i] = 0;
}
__global__ __launch_bounds__(256) void zero_f32(float* __restrict__ p, int n) {
  int i = blockIdx.x * 256 + threadIdx.x;
  if (i < n) p[i] = 0.f;
}

// ---------------------------------------------------------------------------
// Repack a [384][128] fp32 weight matrix (row-major [col][k]) into
// MFMA-B-fragment-ordered bf16 (lane*16B contiguous per fragment).
// ---------------------------------------------------------------------------
__global__ __launch_bounds__(256) void repack_frag_b(
    const float* __restrict__ src, short* __restrict__ dst)
{
  int o = blockIdx.x * 256 + threadIdx.x;      // 0 .. 384*128-1
  if (o >= 384 * 128) return;
  int j    = o & 7;
  int lane = (o >> 3) & 63;
  int ks   = (o >> 9) & 3;
  int t    = o >> 11;
  int m  = lane & 15;
  int g4 = lane >> 4;
  dst[o] = (short)f2bf(src[(t * 16 + m) * 128 + ks * 32 + g4 * 8 + j]);
}

// ---------------------------------------------------------------------------
// Tiled fp32 GEMM, K fixed at 128 (emb, weight folds). Optional bf16-pack
// epilogue mirror (xpack != nullptr -> also emit packed bf16 rows).
// ---------------------------------------------------------------------------
template<bool BT>
__global__ __launch_bounds__(256) void gemm_k128(
    const float* __restrict__ A, const float* __restrict__ W,
    const float* __restrict__ bias, float* __restrict__ Y,
    unsigned* __restrict__ xpack, int M, int OUT)
{
  __shared__ alignas(16) float lds_a[32 * 68];
  __shared__ alignas(16) float lds_b[32 * 132];
  const int tid = threadIdx.x;
  const int tx = tid & 15;
  const int ty = tid >> 4;
  const int rowBase = blockIdx.x * 64;
  const int colBase = blockIdx.y * 128;

  float acc[4][8];
#pragma unroll
  for (int r = 0; r < 4; r++)
#pragma unroll
    for (int c = 0; c < 8; c++) acc[r][c] = 0.f;

  for (int k0 = 0; k0 < 128; k0 += 32) {
#pragma unroll
    for (int i = 0; i < 2; i++) {
      int idx = tid + i * 256;
      int r   = idx >> 3;
      int kk  = (idx & 7) << 2;
      int gr  = rowBase + r;
      float4 v = make_float4(0.f, 0.f, 0.f, 0.f);
      if (gr < M) v = *(const float4*)(A + (size_t)gr * HDIM + k0 + kk);
      lds_a[(kk + 0) * 68 + r] = v.x;
      lds_a[(kk + 1) * 68 + r] = v.y;
      lds_a[(kk + 2) * 68 + r] = v.z;
      lds_a[(kk + 3) * 68 + r] = v.w;
    }
    if (!BT) {
#pragma unroll
      for (int i = 0; i < 4; i++) {
        int idx = tid + i * 256;
        int kk  = idx >> 5;
        int j   = (idx & 31) << 2;
        int gj  = colBase + j;
        float4 v = make_float4(0.f, 0.f, 0.f, 0.f);
        if (gj < OUT) v = *(const float4*)(W + (size_t)(k0 + kk) * OUT + gj);
        *((float4*)&lds_b[kk * 132 + j]) = v;
      }
    } else {
#pragma unroll
      for (int i = 0; i < 4; i++) {
        int idx = tid + i * 256;
        int j   = idx >> 3;
        int k4  = (idx & 7) << 2;
        int gj  = colBase + j;
        float4 v = make_float4(0.f, 0.f, 0.f, 0.f);
        if (gj < OUT) v = *(const float4*)(W + (size_t)gj * HDIM + k0 + k4);
        lds_b[(k4 + 0) * 132 + j] = v.x;
        lds_b[(k4 + 1) * 132 + j] = v.y;
        lds_b[(k4 + 2) * 132 + j] = v.z;
        lds_b[(k4 + 3) * 132 + j] = v.w;
      }
    }
    __syncthreads();
#pragma unroll 8
    for (int kk = 0; kk < 32; kk++) {
      float4 a4 = *(const float4*)&lds_a[kk * 68 + ty * 4];
      float4 b0 = *(const float4*)&lds_b[kk * 132 + tx * 8];
      float4 b1 = *(const float4*)&lds_b[kk * 132 + tx * 8 + 4];
      float av[4] = {a4.x, a4.y, a4.z, a4.w};
      float bv[8] = {b0.x, b0.y, b0.z, b0.w, b1.x, b1.y, b1.z, b1.w};
#pragma unroll
      for (int r = 0; r < 4; r++)
#pragma unroll
        for (int c = 0; c < 8; c++)
          acc[r][c] = fmaf(av[r], bv[c], acc[r][c]);
    }
    __syncthreads();
  }

  int col = colBase + tx * 8;
  if (col >= OUT) return;
  float bv[8];
#pragma unroll
  for (int c = 0; c < 8; c++) bv[c] = bias ? bias[col + c] : 0.f;
#pragma unroll
  for (int r = 0; r < 4; r++) {
    int gr = rowBase + ty * 4 + r;
    if (gr >= M) continue;
    float* yp = Y + (size_t)gr * OUT + col;
    float4 o0 = make_float4(acc[r][0] + bv[0], acc[r][1] + bv[1],
                            acc[r][2] + bv[2], acc[r][3] + bv[3]);
    float4 o1 = make_float4(acc[r][4] + bv[4], acc[r][5] + bv[5],
                            acc[r][6] + bv[6], acc[r][7] + bv[7]);
    *(float4*)yp       = o0;
    *(float4*)(yp + 4) = o1;
    if (xpack) {                       // packed bf16 mirror (emb path)
      uint4 p;
      p.x = (unsigned)f2bf(o0.x) | ((unsigned)f2bf(o0.y) << 16);
      p.y = (unsigned)f2bf(o0.z) | ((unsigned)f2bf(o0.w) << 16);
      p.z = (unsigned)f2bf(o1.x) | ((unsigned)f2bf(o1.y) << 16);
      p.w = (unsigned)f2bf(o1.z) | ((unsigned)f2bf(o1.w) << 16);
      *(uint4*)&xpack[(size_t)gr * 64 + (col >> 1)] = p;
    }
  }
}

// ---------------------------------------------------------------------------
// CSR build, two-pass bucket sort. Replaces hist+scan+fill: the random 8-B
// scatter (8x cross-XCD write amplification, 200 MB measured) becomes
// (1) a run-coalesced partition into 196 dst-buckets, then (2) per-bucket
// placement where read AND write working sets are ~130 KB and line lifetime
// is one block -> full-line L2 merges. Also eliminates csr_hist's 3.2M
// random global atomics: node degrees come from per-bucket LDS histograms.
// Edge record in tmp: x = src | (local_dst << 17)  (17+9 = 26 bits), y = w.
// ---------------------------------------------------------------------------
__global__ __launch_bounds__(256) void csr_part1(
    const int* __restrict__ ei, const float* __restrict__ ew,
    int* __restrict__ bcnt,        // [NB*16] padded counters (one line each)
    int2* __restrict__ tmp)        // [NB*BSLOT]
{
  __shared__ int hist[NB];
  __shared__ int gbase[NB];
  const int tid = threadIdx.x;
  for (int i = tid; i < NB; i += 256) hist[i] = 0;
  __syncthreads();
  const int e0 = blockIdx.x * 2048 + tid * 8;   // 8 consecutive edges/thread
  const bool act = (e0 < N_EDGES);              // tail remainder is %8==0
  int4 s0, s1, d0, d1; float4 w0, w1;
  int rb[8];
  if (act) {
    s0 = *(const int4*)(ei + e0);
    s1 = *(const int4*)(ei + e0 + 4);
    d0 = *(const int4*)(ei + N_EDGES + e0);
    d1 = *(const int4*)(ei + N_EDGES + e0 + 4);
    w0 = *(const float4*)(ew + e0);
    w1 = *(const float4*)(ew + e0 + 4);
    int dv[8] = {d0.x, d0.y, d0.z, d0.w, d1.x, d1.y, d1.z, d1.w};
#pragma unroll
    for (int j = 0; j < 8; j++) {
      int b = dv[j] >> BSH;
      int r = atomicAdd(&hist[b], 1);
      rb[j] = (r << 8) | b;                     // rank<2048 (11b), b<196 (8b)
    }
  }
  __syncthreads();
  for (int i = tid; i < NB; i += 256) {
    int c = hist[i];
    gbase[i] = c ? atomicAdd(&bcnt[i * 16], c) : 0;  // one reserve per bucket
  }
  __syncthreads();
  if (act) {
    int sv[8] = {s0.x, s0.y, s0.z, s0.w, s1.x, s1.y, s1.z, s1.w};
    int dv[8] = {d0.x, d0.y, d0.z, d0.w, d1.x, d1.y, d1.z, d1.w};
    int wv[8] = {__float_as_int(w0.x), __float_as_int(w0.y),
                 __float_as_int(w0.z), __float_as_int(w0.w),
                 __float_as_int(w1.x), __float_as_int(w1.y),
                 __float_as_int(w1.z), __float_as_int(w1.w)};
#pragma unroll
    for (int j = 0; j < 8; j++) {
      int b  = rb[j] & 255;
      int of = gbase[b] + (rb[j] >> 8);
      if (of < BSLOT)                            // memory-safety guard only
        tmp[b * BSLOT + of] =
            make_int2(sv[j] | ((dv[j] & 511) << 17), wv[j]);
    }
  }
}

// exclusive scan of bucket counts -> bucket start offsets; rowptr[N] = E
__global__ void csr_scanb(const int* __restrict__ bcnt,
                          int* __restrict__ bstart, int* __restrict__ rowptr)
{
  __shared__ int l[256];
  int t = threadIdx.x;
  int v = (t < NB) ? min(bcnt[t * 16], BSLOT) : 0;
  l[t] = v;
  __syncthreads();
  for (int off = 1; off < 256; off <<= 1) {
    int u = (t >= off) ? l[t - off] : 0;
    __syncthreads();
    l[t] += u;
    __syncthreads();
  }
  if (t < NB) bstart[t] = l[t] - v;
  if (t == 255) rowptr[N_NODES] = l[255];
}

// per bucket: LDS node-hist -> LDS scan -> rowptr slice (coalesced) ->
// final in-bucket placement (reads+writes stay in ~130 KB, L2-resident).
__global__ __launch_bounds__(256) void csr_part2(
    const int2* __restrict__ tmp, const int* __restrict__ bcnt,
    const int* __restrict__ bstart, int* __restrict__ rowptr,
    int2* __restrict__ epak)
{
  __shared__ int cnt[512];
  __shared__ int lofs[512];
  __shared__ int s2[256];
  const int b      = blockIdx.x;
  const int tid    = threadIdx.x;
  const int nbase  = b << BSH;
  const int nn     = min(512, N_NODES - nbase);
  const int ecount = min(bcnt[b * 16], BSLOT);
  const long tbase = (long)b * BSLOT;
  const int obase  = bstart[b];
  for (int i = tid; i < 512; i += 256) cnt[i] = 0;
  __syncthreads();
  // pass A: per-node histogram of this bucket
  for (int e = tid; e < ecount; e += 256) {
    int2 rec = tmp[tbase + e];
    atomicAdd(&cnt[(rec.x >> 17) & 511], 1);
  }
  __syncthreads();
  // exclusive scan over 512 node counts (pairs + Hillis-Steele on 256)
  int c0 = cnt[2 * tid], c1 = cnt[2 * tid + 1];
  s2[tid] = c0 + c1;
  __syncthreads();
  int inc = s2[tid];
  for (int off = 1; off < 256; off <<= 1) {
    int u = (tid >= off) ? s2[tid - off] : 0;
    __syncthreads();
    s2[tid] += u;
    __syncthreads();
  }
  int ex = s2[tid] - inc;
  lofs[2 * tid]     = ex;
  lofs[2 * tid + 1] = ex + c0;
  __syncthreads();
  // rowptr slice, coalesced (replaces csr_hist + global scan entirely)
  for (int i = tid; i < nn; i += 256) rowptr[nbase + i] = obase + lofs[i];
  for (int i = tid; i < 512; i += 256) cnt[i] = 0;
  __syncthreads();
  // pass B: place edges at final CSR positions (within-row order arbitrary)
  for (int e = tid; e < ecount; e += 256) {
    int2 rec = tmp[tbase + e];
    int ldst = (rec.x >> 17) & 511;
    int r = atomicAdd(&cnt[ldst], 1);
    epak[obase + lofs[ldst] + r] = make_int2(rec.x & 0x1FFFF, rec.y);
  }
}

// ---------------------------------------------------------------------------
// Pull aggregation on bf16 x: z[n] = sum w_e * x[src_e], fp32 accumulate,
// bf16 packed output. One wave/node, lane covers cols {2*lane, 2*lane+1}.
// ---------------------------------------------------------------------------
__global__ __launch_bounds__(256) void agg_pull(
    const unsigned* __restrict__ xbp, const int* __restrict__ rowptr,
    const int2* __restrict__ epak, unsigned* __restrict__ zbp)
{
  int node = blockIdx.x * 4 + (threadIdx.x >> 6);
  if (node >= N_NODES) return;
  int lane = threadIdx.x & 63;
  int s0 = rowptr[node], s1 = rowptr[node + 1];
  float v0 = 0.f, v1 = 0.f;
  int e = s0;
  for (; e + 3 < s1; e += 4) {
    int2 e0 = epak[e], e1 = epak[e + 1], e2 = epak[e + 2], e3 = epak[e + 3];
    unsigned p0 = xbp[(size_t)e0.x * 64 + lane];
    unsigned p1 = xbp[(size_t)e1.x * 64 + lane];
    unsigned p2 = xbp[(size_t)e2.x * 64 + lane];
    unsigned p3 = xbp[(size_t)e3.x * 64 + lane];
    float w0 = __int_as_float(e0.y), w1 = __int_as_float(e1.y);
    float w2 = __int_as_float(e2.y), w3 = __int_as_float(e3.y);
    v0 = fmaf(w0, bflo(p0), v0); v1 = fmaf(w0, bfhi(p0), v1);
    v0 = fmaf(w1, bflo(p1), v0); v1 = fmaf(w1, bfhi(p1), v1);
    v0 = fmaf(w2, bflo(p2), v0); v1 = fmaf(w2, bfhi(p2), v1);
    v0 = fmaf(w3, bflo(p3), v0); v1 = fmaf(w3, bfhi(p3), v1);
  }
  for (; e < s1; e++) {
    int2 ep = epak[e];
    unsigned p = xbp[(size_t)ep.x * 64 + lane];
    float w = __int_as_float(ep.y);
    v0 = fmaf(w, bflo(p), v0); v1 = fmaf(w, bfhi(p), v1);
  }
  zbp[(size_t)node * 64 + lane] =
      (unsigned)f2bf(v0) | ((unsigned)f2bf(v1) << 16);
}

// ---------------------------------------------------------------------------
// Fused GRU layer (bf16 MFMA), v2 partition: block = 64 rows; each of the
// 4 waves owns 2 of the 8 t-column-tiles (32 gate-cols x 3 gates) for ALL
// 64 rows. B-frag loads amortize over 4 row-tiles -> 4:1 MFMA:VMEM with
// 4-way independent MFMAs per load. Accums: 4rt x 2t x 4 sets = 128 VGPR.
// ---------------------------------------------------------------------------
__global__ __launch_bounds__(256) void gru_fused(
    const short* __restrict__ zb, short* __restrict__ xb,
    float* __restrict__ x,
    const short* __restrict__ Fb, const short* __restrict__ Wb,
    const float* __restrict__ bih, const float* __restrict__ bhh)
{
  const int wave = threadIdx.x >> 6, lane = threadIdx.x & 63;
  const int m  = lane & 15;
  const int g4 = lane >> 4;
  const int rowBase = blockIdx.x * 64;
  const int t0 = wave * 2;                 // this wave's t-pair (cols t0*16..)

  f32x4 aR[4][2], aZ[4][2], aN[4][2], aH[4][2];
#pragma unroll
  for (int rt = 0; rt < 4; rt++)
#pragma unroll
    for (int ti = 0; ti < 2; ti++) {
      aR[rt][ti] = (f32x4){0.f, 0.f, 0.f, 0.f};
      aZ[rt][ti] = (f32x4){0.f, 0.f, 0.f, 0.f};
      aN[rt][ti] = (f32x4){0.f, 0.f, 0.f, 0.f};
      aH[rt][ti] = (f32x4){0.f, 0.f, 0.f, 0.f};
    }

  size_t arowc[4];
#pragma unroll
  for (int rt = 0; rt < 4; rt++) {
    int arow = rowBase + rt * 16 + m;
    arowc[rt] = (size_t)(arow < N_NODES ? arow : N_NODES - 1) * 128 + g4 * 8;
  }

  // ---- phase 0: z @ F -> r,z,i_n ----
#pragma unroll
  for (int ks = 0; ks < 4; ks++) {
    bf16x8 a[4];
#pragma unroll
    for (int rt = 0; rt < 4; rt++)
      a[rt] = *(const bf16x8*)(zb + arowc[rt] + ks * 32);
    const int bo = ks * 512 + lane * 8;
#pragma unroll
    for (int ti = 0; ti < 2; ti++) {
      const short* bp = Fb + (t0 + ti) * 2048 + bo;
      bf16x8 br = *(const bf16x8*)(bp);
      bf16x8 bz = *(const bf16x8*)(bp + 16384);
      bf16x8 bn = *(const bf16x8*)(bp + 32768);
#pragma unroll
      for (int rt = 0; rt < 4; rt++) {
        aR[rt][ti] = __builtin_amdgcn_mfma_f32_16x16x32_bf16(a[rt], br, aR[rt][ti], 0, 0, 0);
        aZ[rt][ti] = __builtin_amdgcn_mfma_f32_16x16x32_bf16(a[rt], bz, aZ[rt][ti], 0, 0, 0);
        aN[rt][ti] = __builtin_amdgcn_mfma_f32_16x16x32_bf16(a[rt], bn, aN[rt][ti], 0, 0, 0);
      }
    }
  }
  // ---- phase 1: x @ Whh^T -> r,z,h_n ----
#pragma unroll
  for (int ks = 0; ks < 4; ks++) {
    bf16x8 a[4];
#pragma unroll
    for (int rt = 0; rt < 4; rt++)
      a[rt] = *(const bf16x8*)(xb + arowc[rt] + ks * 32);
    const int bo = ks * 512 + lane * 8;
#pragma unroll
    for (int ti = 0; ti < 2; ti++) {
      const short* bp = Wb + (t0 + ti) * 2048 + bo;
      bf16x8 br = *(const bf16x8*)(bp);
      bf16x8 bz = *(const bf16x8*)(bp + 16384);
      bf16x8 bn = *(const bf16x8*)(bp + 32768);
#pragma unroll
      for (int rt = 0; rt < 4; rt++) {
        aR[rt][ti] = __builtin_amdgcn_mfma_f32_16x16x32_bf16(a[rt], br, aR[rt][ti], 0, 0, 0);
        aZ[rt][ti] = __builtin_amdgcn_mfma_f32_16x16x32_bf16(a[rt], bz, aZ[rt][ti], 0, 0, 0);
        aH[rt][ti] = __builtin_amdgcn_mfma_f32_16x16x32_bf16(a[rt], bn, aH[rt][ti], 0, 0, 0);
      }
    }
  }

  // ---- epilogue: gates + state update (C/D: col=lane&15, row=g4*4+reg) ----
#pragma unroll
  for (int ti = 0; ti < 2; ti++) {
    int col = (t0 + ti) * 16 + m;
    float b_r = bih[col] + bhh[col];
    float b_z = bih[128 + col] + bhh[128 + col];
    float b_i = bih[256 + col];
    float b_h = bhh[256 + col];
#pragma unroll
    for (int rt = 0; rt < 4; rt++) {
#pragma unroll
      for (int r = 0; r < 4; r++) {
        int gr = rowBase + rt * 16 + g4 * 4 + r;
        if (gr < N_NODES) {
          float rg = 1.f / (1.f + __expf(-(aR[rt][ti][r] + b_r)));
          float zg = 1.f / (1.f + __expf(-(aZ[rt][ti][r] + b_z)));
          float ng = tanhf(aN[rt][ti][r] + b_i + rg * (aH[rt][ti][r] + b_h));
          size_t o = (size_t)gr * 128 + col;
          float xo = x[o];
          float xn = (1.f - zg) * ng + zg * xo;
          x[o] = xn;
          xb[o] = (short)f2bf(xn);
        }
      }
    }
  }
}

// ---------------------------------------------------------------------------
// BatchNorm stats (fp32 master x)
// ---------------------------------------------------------------------------
__global__ __launch_bounds__(256) void bn_stats(
    const float* __restrict__ x, float* __restrict__ sums)
{
  __shared__ float ls[256], lq[256];
  int tid  = threadIdx.x;
  int col  = tid & 127, half = tid >> 7;
  int r0   = blockIdx.x * 128;
  int rend = min(N_NODES, r0 + 128);
  float s = 0.f, q = 0.f;
  for (int r = r0 + half; r < rend; r += 2) {
    float v = x[(size_t)r * HDIM + col];
    s += v; q += v * v;
  }
  ls[tid] = s; lq[tid] = q;
  __syncthreads();
  if (tid < 128) {
    atomicAdd(&sums[col],       ls[tid] + ls[tid + 128]);
    atomicAdd(&sums[128 + col], lq[tid] + lq[tid + 128]);
  }
}

__global__ void bn_finalize(float* __restrict__ sums,
                            const float* __restrict__ gamma,
                            const float* __restrict__ beta)
{
  int j = threadIdx.x;
  float mean = sums[j] / (float)N_NODES;
  float var  = sums[128 + j] / (float)N_NODES - mean * mean;
  float inv  = rsqrtf(var + 1e-5f);
  sums[256 + j] = gamma[j] * inv;
  sums[384 + j] = beta[j] - mean * gamma[j] * inv;
}

// ---------------------------------------------------------------------------
// Fused head: out = bn(x) @ mlpW + h @ e2 + c2, BN folded into A-load of x.
// ---------------------------------------------------------------------------
__global__ __launch_bounds__(256) void head_fused(
    const float* __restrict__ x, const float* __restrict__ h,
    const float* __restrict__ sums,      // scale at [256..], shift at [384..]
    const float* __restrict__ mlpW,      // [128][40]
    const float* __restrict__ e2,        // [128][40]
    const float* __restrict__ c2,        // [40]
    float* __restrict__ out)             // [N][40]
{
  __shared__ alignas(16) float lds_a[32 * 68];
  __shared__ alignas(16) float lds_b[32 * 132];
  const int tid = threadIdx.x;
  const int tx = tid & 15;
  const int ty = tid >> 4;
  const int rowBase = blockIdx.x * 64;
  const int OUT = 40;

  float acc[4][8];
#pragma unroll
  for (int r = 0; r < 4; r++)
#pragma unroll
    for (int c = 0; c < 8; c++) acc[r][c] = 0.f;

  for (int src = 0; src < 2; src++) {
    const float* A = src ? h : x;
    const float* W = src ? e2 : mlpW;
    for (int k0 = 0; k0 < 128; k0 += 32) {
#pragma unroll
      for (int i = 0; i < 2; i++) {
        int idx = tid + i * 256;
        int r   = idx >> 3;
        int kk  = (idx & 7) << 2;
        int gr  = rowBase + r;
        float4 v = make_float4(0.f, 0.f, 0.f, 0.f);
        if (gr < N_NODES) v = *(const float4*)(A + (size_t)gr * HDIM + k0 + kk);
        if (src == 0) {   // fold BatchNorm apply into the x tile load
          float4 sc = *(const float4*)(sums + 256 + k0 + kk);
          float4 sh = *(const float4*)(sums + 384 + k0 + kk);
          v.x = fmaf(v.x, sc.x, sh.x);
          v.y = fmaf(v.y, sc.y, sh.y);
          v.z = fmaf(v.z, sc.z, sh.z);
          v.w = fmaf(v.w, sc.w, sh.w);
        }
        lds_a[(kk + 0) * 68 + r] = v.x;
        lds_a[(kk + 1) * 68 + r] = v.y;
        lds_a[(kk + 2) * 68 + r] = v.z;
        lds_a[(kk + 3) * 68 + r] = v.w;
      }
#pragma unroll
      for (int i = 0; i < 4; i++) {
        int idx = tid + i * 256;
        int kk  = idx >> 5;
        int j   = (idx & 31) << 2;
        float4 v = make_float4(0.f, 0.f, 0.f, 0.f);
        if (j < OUT) v = *(const float4*)(W + (size_t)(k0 + kk) * OUT + j);
        *((float4*)&lds_b[kk * 132 + j]) = v;
      }
      __syncthreads();
#pragma unroll 8
      for (int kk = 0; kk < 32; kk++) {
        float4 a4 = *(const float4*)&lds_a[kk * 68 + ty * 4];
        float4 b0 = *(const float4*)&lds_b[kk * 132 + tx * 8];
        float4 b1 = *(const float4*)&lds_b[kk * 132 + tx * 8 + 4];
        float av[4] = {a4.x, a4.y, a4.z, a4.w};
        float bv[8] = {b0.x, b0.y, b0.z, b0.w, b1.x, b1.y, b1.z, b1.w};
#pragma unroll
        for (int r = 0; r < 4; r++)
#pragma unroll
          for (int c = 0; c < 8; c++)
            acc[r][c] = fmaf(av[r], bv[c], acc[r][c]);
      }
      __syncthreads();
    }
  }

  int col = tx * 8;
  if (col >= OUT) return;            // tx 0..4 write (cols 0..39)
  float bv[8];
#pragma unroll
  for (int c = 0; c < 8; c++) bv[c] = c2[col + c];
#pragma unroll
  for (int r = 0; r < 4; r++) {
    int gr = rowBase + ty * 4 + r;
    if (gr >= N_NODES) continue;
    float* yp = out + (size_t)gr * OUT + col;
    float4 o0 = make_float4(acc[r][0] + bv[0], acc[r][1] + bv[1],
                            acc[r][2] + bv[2], acc[r][3] + bv[3]);
    float4 o1 = make_float4(acc[r][4] + bv[4], acc[r][5] + bv[5],
                            acc[r][6] + bv[6], acc[r][7] + bv[7]);
    *(float4*)yp       = o0;
    *(float4*)(yp + 4) = o1;
  }
}

// ---------------------------------------------------------------------------
// Residual fold constants: E2 = embW @ mlpW  [128][40], c2 = mlpB + embB@mlpW
// ---------------------------------------------------------------------------
__global__ void prep_e2(const float* __restrict__ embW,
                        const float* __restrict__ embB,
                        const float* __restrict__ mlpW,
                        const float* __restrict__ mlpB,
                        float* __restrict__ e2, float* __restrict__ c2)
{
  int tid = threadIdx.x;
#pragma unroll
  for (int t = 0; t < 20; t++) {
    int idx = tid * 20 + t;
    int f = idx / 40, j = idx - f * 40;
    float s = 0.f;
    for (int k = 0; k < 128; k++)
      s = fmaf(embW[f * 128 + k], mlpW[k * 40 + j], s);
    e2[idx] = s;
  }
  if (tid < 40) {
    float s = mlpB[tid];
    for (int k = 0; k < 128; k++)
      s = fmaf(embB[k], mlpW[k * 40 + tid], s);
    c2[tid] = s;
  }
}

// ---------------------------------------------------------------------------
extern "C" void kernel_launch(void* const* d_in, const int* in_sizes, int n_in,
                              void* d_out, int out_size, void* d_ws, size_t ws_size,
                              hipStream_t stream)
{
  const float* h     = (const float*)d_in[0];
  const int*   ei    = (const int*)d_in[1];
  const float* ew    = (const float*)d_in[2];
  const float* embW  = (const float*)d_in[3];
  const float* embB  = (const float*)d_in[4];
  const float* convW = (const float*)d_in[5];   // [3][128][128]
  const float* Wih   = (const float*)d_in[6];   // [384][128]
  const float* Whh   = (const float*)d_in[7];   // [384][128]
  const float* bih   = (const float*)d_in[8];
  const float* bhh   = (const float*)d_in[9];
  const float* gamma = (const float*)d_in[10];
  const float* beta  = (const float*)d_in[11];
  const float* mlpW  = (const float*)d_in[12];
  const float* mlpB  = (const float*)d_in[13];
  float* out = (float*)d_out;

  float* ws = (float*)d_ws;
  const size_t NH = (size_t)N_NODES * HDIM;      // 12.8M
  float*    x      = ws;                          // [N][128] fp32 master
  unsigned* xbp    = (unsigned*)(ws + NH);        // [N][64] packed bf16
  unsigned* zbp    = xbp + NH / 2;                // [N][64] packed bf16
  int2*     epak   = (int2*)(zbp + NH / 2);       // [E] {src, w}
  int*      rowptr = (int*)(epak + N_EDGES);      // N+4
  int*      bcnt   = rowptr + N_NODES + 4;        // NB*16 padded counters
  int*      bstart = bcnt + NB * 16;              // NB (+pad)
  float*    Ffold  = (float*)(bstart + 256);      // [3][384][128] fp32
  short*    Fbp    = (short*)(Ffold + 3 * 384 * 128);  // frag-order bf16
  short*    Wbp    = Fbp + 3 * 384 * 128;         // frag-order bf16 of Whh
  float*    sums   = (float*)(Wbp + 384 * 128);
  float*    e2     = sums + 512;
  float*    c2     = e2 + 5120;
  // csr scratch: tmp [NB*BSLOT] int2 = 27.6 MB aliases xbp+zbp (both dead
  // until after the embedding GEMM / first agg_pull).
  int2*     tmp    = (int2*)xbp;

  dim3 blk(256);
  const int MB = (N_NODES + 63) / 64;
  const int RB = (384 * 128 + 255) / 256;
  const int P1B = (N_EDGES + 2047) / 2048;        // 1563 (tail %8 == 0)

  // ---- constants ----
  prep_e2<<<1, 256, 0, stream>>>(embW, embB, mlpW, mlpB, e2, c2);
  for (int l = 0; l < 3; l++)
    gemm_k128<true><<<dim3(6, 1), blk, 0, stream>>>(
        Wih, convW + (size_t)l * HDIM * HDIM, nullptr,
        Ffold + (size_t)l * 384 * HDIM, nullptr, 384, 128);
  for (int l = 0; l < 3; l++)
    repack_frag_b<<<RB, blk, 0, stream>>>(
        Ffold + (size_t)l * 384 * HDIM, Fbp + (size_t)l * 384 * HDIM);
  repack_frag_b<<<RB, blk, 0, stream>>>(Whh, Wbp);

  // ---- CSR build: bucket partition -> per-bucket place (no global scatter)
  zero_i32<<<(NB * 16 + 255) / 256, blk, 0, stream>>>(bcnt, NB * 16);
  csr_part1<<<P1B, blk, 0, stream>>>(ei, ew, bcnt, tmp);
  csr_scanb<<<1, 256, 0, stream>>>(bcnt, bstart, rowptr);
  csr_part2<<<NB, blk, 0, stream>>>(tmp, bcnt, bstart, rowptr, epak);

  // ---- embedding: x = h @ embW + embB ; bf16 mirror fused in epilogue ----
  gemm_k128<false><<<dim3(MB, 1), blk, 0, stream>>>(h, embW, embB, x, xbp,
                                                    N_NODES, 128);

  // ---- 3 GRU layers: pull-agg (bf16) + fused MFMA GRU ----
  for (int l = 0; l < 3; l++) {
    agg_pull<<<(N_NODES + 3) / 4, blk, 0, stream>>>(xbp, rowptr, epak, zbp);
    gru_fused<<<MB, blk, 0, stream>>>(
        (const short*)zbp, (short*)xbp, x,
        Fbp + (size_t)l * 384 * HDIM, Wbp, bih, bhh);
  }

  // ---- BatchNorm stats + fully fused head (BN apply + both GEMMs) ----
  zero_f32<<<2, blk, 0, stream>>>(sums, 512);
  bn_stats<<<(N_NODES + 127) / 128, blk, 0, stream>>>(x, sums);
  bn_finalize<<<1, 128, 0, stream>>>(sums, gamma, beta);
  head_fused<<<dim3(MB, 1), blk, 0, stream>>>(x, h, sums, mlpW, e2, c2, out);
}

// Round 4
// 1153.298 us; speedup vs baseline: 1.4153x; 1.2027x over previous
//
#include <hip/hip_runtime.h>
#include <math.h>

#define N_NODES 100000
#define N_EDGES 3200000
#define HDIM 128

// ---- bucket sort CSR build ----
#define NB 196        // buckets of 512 consecutive dst nodes (100000/512 -> 196)
#define BSH 9         // 512 nodes per bucket
#define BSLOT 18432   // tmp slots per bucket (avg fill 16327, +16 sigma headroom)

typedef __attribute__((ext_vector_type(8))) short bf16x8;
typedef __attribute__((ext_vector_type(4))) float f32x4;

__device__ __forceinline__ unsigned short f2bf(float f) {
  union { float f; unsigned u; } v; v.f = f;
  unsigned r = v.u + 0x7fffu + ((v.u >> 16) & 1u);
  return (unsigned short)(r >> 16);
}
__device__ __forceinline__ float bflo(unsigned p) {
  union { unsigned u; float f; } v; v.u = p << 16; return v.f;
}
__device__ __forceinline__ float bfhi(unsigned p) {
  union { unsigned u; float f; } v; v.u = p & 0xffff0000u; return v.f;
}
// fast sigmoid/tanh: v_exp + v_rcp (approx err ~1e-6 << bf16 quantum 4e-3
// already present in the data path; libm tanhf is ~40 branchy VALU instrs,
// fp32 division is the ~10-instr div_scale/div_fmas sequence).
__device__ __forceinline__ float fsigmoid(float v) {
  return __builtin_amdgcn_rcpf(1.f + __expf(-v));
}
__device__ __forceinline__ float ftanh(float v) {
  return 1.f - 2.f * __builtin_amdgcn_rcpf(1.f + __expf(2.f * v));
}

// ---------------------------------------------------------------------------
__global__ __launch_bounds__(256) void zero_i32(int* __restrict__ p, int n) {
  int i = blockIdx.x * 256 + threadIdx.x;
  if (i < n) p[i] = 0;
}
__global__ __launch_bounds__(256) void zero_f32(float* __restrict__ p, int n) {
  int i = blockIdx.x * 256 + threadIdx.x;
  if (i < n) p[i] = 0.f;
}

// ---------------------------------------------------------------------------
// Repack a [384][128] fp32 weight matrix (row-major [col][k]) into
// MFMA-B-fragment-ordered bf16 (lane*16B contiguous per fragment).
// ---------------------------------------------------------------------------
__global__ __launch_bounds__(256) void repack_frag_b(
    const float* __restrict__ src, short* __restrict__ dst)
{
  int o = blockIdx.x * 256 + threadIdx.x;      // 0 .. 384*128-1
  if (o >= 384 * 128) return;
  int j    = o & 7;
  int lane = (o >> 3) & 63;
  int ks   = (o >> 9) & 3;
  int t    = o >> 11;
  int m  = lane & 15;
  int g4 = lane >> 4;
  dst[o] = (short)f2bf(src[(t * 16 + m) * 128 + ks * 32 + g4 * 8 + j]);
}

// ---------------------------------------------------------------------------
// Tiled fp32 GEMM, K fixed at 128 (emb, weight folds). Optional bf16-pack
// epilogue mirror (xpack != nullptr -> also emit packed bf16 rows).
// ---------------------------------------------------------------------------
template<bool BT>
__global__ __launch_bounds__(256) void gemm_k128(
    const float* __restrict__ A, const float* __restrict__ W,
    const float* __restrict__ bias, float* __restrict__ Y,
    unsigned* __restrict__ xpack, int M, int OUT)
{
  __shared__ alignas(16) float lds_a[32 * 68];
  __shared__ alignas(16) float lds_b[32 * 132];
  const int tid = threadIdx.x;
  const int tx = tid & 15;
  const int ty = tid >> 4;
  const int rowBase = blockIdx.x * 64;
  const int colBase = blockIdx.y * 128;

  float acc[4][8];
#pragma unroll
  for (int r = 0; r < 4; r++)
#pragma unroll
    for (int c = 0; c < 8; c++) acc[r][c] = 0.f;

  for (int k0 = 0; k0 < 128; k0 += 32) {
#pragma unroll
    for (int i = 0; i < 2; i++) {
      int idx = tid + i * 256;
      int r   = idx >> 3;
      int kk  = (idx & 7) << 2;
      int gr  = rowBase + r;
      float4 v = make_float4(0.f, 0.f, 0.f, 0.f);
      if (gr < M) v = *(const float4*)(A + (size_t)gr * HDIM + k0 + kk);
      lds_a[(kk + 0) * 68 + r] = v.x;
      lds_a[(kk + 1) * 68 + r] = v.y;
      lds_a[(kk + 2) * 68 + r] = v.z;
      lds_a[(kk + 3) * 68 + r] = v.w;
    }
    if (!BT) {
#pragma unroll
      for (int i = 0; i < 4; i++) {
        int idx = tid + i * 256;
        int kk  = idx >> 5;
        int j   = (idx & 31) << 2;
        int gj  = colBase + j;
        float4 v = make_float4(0.f, 0.f, 0.f, 0.f);
        if (gj < OUT) v = *(const float4*)(W + (size_t)(k0 + kk) * OUT + gj);
        *((float4*)&lds_b[kk * 132 + j]) = v;
      }
    } else {
#pragma unroll
      for (int i = 0; i < 4; i++) {
        int idx = tid + i * 256;
        int j   = idx >> 3;
        int k4  = (idx & 7) << 2;
        int gj  = colBase + j;
        float4 v = make_float4(0.f, 0.f, 0.f, 0.f);
        if (gj < OUT) v = *(const float4*)(W + (size_t)gj * HDIM + k0 + k4);
        lds_b[(k4 + 0) * 132 + j] = v.x;
        lds_b[(k4 + 1) * 132 + j] = v.y;
        lds_b[(k4 + 2) * 132 + j] = v.z;
        lds_b[(k4 + 3) * 132 + j] = v.w;
      }
    }
    __syncthreads();
#pragma unroll 8
    for (int kk = 0; kk < 32; kk++) {
      float4 a4 = *(const float4*)&lds_a[kk * 68 + ty * 4];
      float4 b0 = *(const float4*)&lds_b[kk * 132 + tx * 8];
      float4 b1 = *(const float4*)&lds_b[kk * 132 + tx * 8 + 4];
      float av[4] = {a4.x, a4.y, a4.z, a4.w};
      float bv[8] = {b0.x, b0.y, b0.z, b0.w, b1.x, b1.y, b1.z, b1.w};
#pragma unroll
      for (int r = 0; r < 4; r++)
#pragma unroll
        for (int c = 0; c < 8; c++)
          acc[r][c] = fmaf(av[r], bv[c], acc[r][c]);
    }
    __syncthreads();
  }

  int col = colBase + tx * 8;
  if (col >= OUT) return;
  float bv[8];
#pragma unroll
  for (int c = 0; c < 8; c++) bv[c] = bias ? bias[col + c] : 0.f;
#pragma unroll
  for (int r = 0; r < 4; r++) {
    int gr = rowBase + ty * 4 + r;
    if (gr >= M) continue;
    float* yp = Y + (size_t)gr * OUT + col;
    float4 o0 = make_float4(acc[r][0] + bv[0], acc[r][1] + bv[1],
                            acc[r][2] + bv[2], acc[r][3] + bv[3]);
    float4 o1 = make_float4(acc[r][4] + bv[4], acc[r][5] + bv[5],
                            acc[r][6] + bv[6], acc[r][7] + bv[7]);
    *(float4*)yp       = o0;
    *(float4*)(yp + 4) = o1;
    if (xpack) {                       // packed bf16 mirror (emb path)
      uint4 p;
      p.x = (unsigned)f2bf(o0.x) | ((unsigned)f2bf(o0.y) << 16);
      p.y = (unsigned)f2bf(o0.z) | ((unsigned)f2bf(o0.w) << 16);
      p.z = (unsigned)f2bf(o1.x) | ((unsigned)f2bf(o1.y) << 16);
      p.w = (unsigned)f2bf(o1.z) | ((unsigned)f2bf(o1.w) << 16);
      *(uint4*)&xpack[(size_t)gr * 64 + (col >> 1)] = p;
    }
  }
}

// ---------------------------------------------------------------------------
// CSR build, two-pass bucket sort (see round-2 notes: kills the random 8-B
// global scatter and csr_hist's 3.2M random atomics).
// Edge record in tmp: x = src | (local_dst << 17)  (17+9 = 26 bits), y = w.
// ---------------------------------------------------------------------------
__global__ __launch_bounds__(256) void csr_part1(
    const int* __restrict__ ei, const float* __restrict__ ew,
    int* __restrict__ bcnt,        // [NB*16] padded counters (one line each)
    int2* __restrict__ tmp)        // [NB*BSLOT]
{
  __shared__ int hist[NB];
  __shared__ int gbase[NB];
  const int tid = threadIdx.x;
  for (int i = tid; i < NB; i += 256) hist[i] = 0;
  __syncthreads();
  const int e0 = blockIdx.x * 2048 + tid * 8;   // 8 consecutive edges/thread
  const bool act = (e0 < N_EDGES);              // tail remainder is %8==0
  int4 s0, s1, d0, d1; float4 w0, w1;
  int rb[8];
  if (act) {
    s0 = *(const int4*)(ei + e0);
    s1 = *(const int4*)(ei + e0 + 4);
    d0 = *(const int4*)(ei + N_EDGES + e0);
    d1 = *(const int4*)(ei + N_EDGES + e0 + 4);
    w0 = *(const float4*)(ew + e0);
    w1 = *(const float4*)(ew + e0 + 4);
    int dv[8] = {d0.x, d0.y, d0.z, d0.w, d1.x, d1.y, d1.z, d1.w};
#pragma unroll
    for (int j = 0; j < 8; j++) {
      int b = dv[j] >> BSH;
      int r = atomicAdd(&hist[b], 1);
      rb[j] = (r << 8) | b;                     // rank<2048 (11b), b<196 (8b)
    }
  }
  __syncthreads();
  for (int i = tid; i < NB; i += 256) {
    int c = hist[i];
    gbase[i] = c ? atomicAdd(&bcnt[i * 16], c) : 0;  // one reserve per bucket
  }
  __syncthreads();
  if (act) {
    int sv[8] = {s0.x, s0.y, s0.z, s0.w, s1.x, s1.y, s1.z, s1.w};
    int dv[8] = {d0.x, d0.y, d0.z, d0.w, d1.x, d1.y, d1.z, d1.w};
    int wv[8] = {__float_as_int(w0.x), __float_as_int(w0.y),
                 __float_as_int(w0.z), __float_as_int(w0.w),
                 __float_as_int(w1.x), __float_as_int(w1.y),
                 __float_as_int(w1.z), __float_as_int(w1.w)};
#pragma unroll
    for (int j = 0; j < 8; j++) {
      int b  = rb[j] & 255;
      int of = gbase[b] + (rb[j] >> 8);
      if (of < BSLOT)                            // memory-safety guard only
        tmp[b * BSLOT + of] =
            make_int2(sv[j] | ((dv[j] & 511) << 17), wv[j]);
    }
  }
}

// exclusive scan of bucket counts -> bucket start offsets; rowptr[N] = E
__global__ void csr_scanb(const int* __restrict__ bcnt,
                          int* __restrict__ bstart, int* __restrict__ rowptr)
{
  __shared__ int l[256];
  int t = threadIdx.x;
  int v = (t < NB) ? min(bcnt[t * 16], BSLOT) : 0;
  l[t] = v;
  __syncthreads();
  for (int off = 1; off < 256; off <<= 1) {
    int u = (t >= off) ? l[t - off] : 0;
    __syncthreads();
    l[t] += u;
    __syncthreads();
  }
  if (t < NB) bstart[t] = l[t] - v;
  if (t == 255) rowptr[N_NODES] = l[255];
}

// per bucket: LDS node-hist -> LDS scan -> rowptr slice (coalesced) ->
// final in-bucket placement (reads+writes stay in ~130 KB, L2-resident).
__global__ __launch_bounds__(256) void csr_part2(
    const int2* __restrict__ tmp, const int* __restrict__ bcnt,
    const int* __restrict__ bstart, int* __restrict__ rowptr,
    int2* __restrict__ epak)
{
  __shared__ int cnt[512];
  __shared__ int lofs[512];
  __shared__ int s2[256];
  const int b      = blockIdx.x;
  const int tid    = threadIdx.x;
  const int nbase  = b << BSH;
  const int nn     = min(512, N_NODES - nbase);
  const int ecount = min(bcnt[b * 16], BSLOT);
  const long tbase = (long)b * BSLOT;
  const int obase  = bstart[b];
  for (int i = tid; i < 512; i += 256) cnt[i] = 0;
  __syncthreads();
  // pass A: per-node histogram of this bucket
  for (int e = tid; e < ecount; e += 256) {
    int2 rec = tmp[tbase + e];
    atomicAdd(&cnt[(rec.x >> 17) & 511], 1);
  }
  __syncthreads();
  // exclusive scan over 512 node counts (pairs + Hillis-Steele on 256)
  int c0 = cnt[2 * tid], c1 = cnt[2 * tid + 1];
  s2[tid] = c0 + c1;
  __syncthreads();
  int inc = s2[tid];
  for (int off = 1; off < 256; off <<= 1) {
    int u = (tid >= off) ? s2[tid - off] : 0;
    __syncthreads();
    s2[tid] += u;
    __syncthreads();
  }
  int ex = s2[tid] - inc;
  lofs[2 * tid]     = ex;
  lofs[2 * tid + 1] = ex + c0;
  __syncthreads();
  // rowptr slice, coalesced (replaces csr_hist + global scan entirely)
  for (int i = tid; i < nn; i += 256) rowptr[nbase + i] = obase + lofs[i];
  for (int i = tid; i < 512; i += 256) cnt[i] = 0;
  __syncthreads();
  // pass B: place edges at final CSR positions (within-row order arbitrary)
  for (int e = tid; e < ecount; e += 256) {
    int2 rec = tmp[tbase + e];
    int ldst = (rec.x >> 17) & 511;
    int r = atomicAdd(&cnt[ldst], 1);
    epak[obase + lofs[ldst] + r] = make_int2(rec.x & 0x1FFFF, rec.y);
  }
}

// ---------------------------------------------------------------------------
// Pull aggregation on bf16 x: z[n] = sum w_e * x[src_e], fp32 accumulate,
// bf16 packed output. One wave/node, lane covers cols {2*lane, 2*lane+1}.
// ---------------------------------------------------------------------------
__global__ __launch_bounds__(256) void agg_pull(
    const unsigned* __restrict__ xbp, const int* __restrict__ rowptr,
    const int2* __restrict__ epak, unsigned* __restrict__ zbp)
{
  int node = blockIdx.x * 4 + (threadIdx.x >> 6);
  if (node >= N_NODES) return;
  int lane = threadIdx.x & 63;
  int s0 = rowptr[node], s1 = rowptr[node + 1];
  float v0 = 0.f, v1 = 0.f;
  int e = s0;
  for (; e + 3 < s1; e += 4) {
    int2 e0 = epak[e], e1 = epak[e + 1], e2 = epak[e + 2], e3 = epak[e + 3];
    unsigned p0 = xbp[(size_t)e0.x * 64 + lane];
    unsigned p1 = xbp[(size_t)e1.x * 64 + lane];
    unsigned p2 = xbp[(size_t)e2.x * 64 + lane];
    unsigned p3 = xbp[(size_t)e3.x * 64 + lane];
    float w0 = __int_as_float(e0.y), w1 = __int_as_float(e1.y);
    float w2 = __int_as_float(e2.y), w3 = __int_as_float(e3.y);
    v0 = fmaf(w0, bflo(p0), v0); v1 = fmaf(w0, bfhi(p0), v1);
    v0 = fmaf(w1, bflo(p1), v0); v1 = fmaf(w1, bfhi(p1), v1);
    v0 = fmaf(w2, bflo(p2), v0); v1 = fmaf(w2, bfhi(p2), v1);
    v0 = fmaf(w3, bflo(p3), v0); v1 = fmaf(w3, bfhi(p3), v1);
  }
  for (; e < s1; e++) {
    int2 ep = epak[e];
    unsigned p = xbp[(size_t)ep.x * 64 + lane];
    float w = __int_as_float(ep.y);
    v0 = fmaf(w, bflo(p), v0); v1 = fmaf(w, bfhi(p), v1);
  }
  zbp[(size_t)node * 64 + lane] =
      (unsigned)f2bf(v0) | ((unsigned)f2bf(v1) << 16);
}

// ---------------------------------------------------------------------------
// Fused GRU layer (bf16 MFMA), v3 partition: block = 32 rows (2 row-tiles),
// 4 waves each own 2 t-column-tiles for all 32 rows. Accumulators:
// 2rt x 2ti x 4 sets = 64 VGPR (was 128 at 64 rows -> VGPR 144 -> only
// 3 waves/SIMD, Occupancy 9.9%). launch_bounds(256,4) caps at 128 VGPR.
// 32 | 100000 exactly -> no row guards anywhere. Fast sigmoid/tanh replace
// libm tanhf + fp32 div (epilogue was the dominant serial VALU chain:
// VALUBusy 19% vs MfmaUtil 5%).
// ---------------------------------------------------------------------------
__global__ __launch_bounds__(256, 4) void gru_fused(
    const short* __restrict__ zb, short* __restrict__ xb,
    float* __restrict__ x,
    const short* __restrict__ Fb, const short* __restrict__ Wb,
    const float* __restrict__ bih, const float* __restrict__ bhh)
{
  const int wave = threadIdx.x >> 6, lane = threadIdx.x & 63;
  const int m  = lane & 15;
  const int g4 = lane >> 4;
  const int rowBase = blockIdx.x * 32;
  const int t0 = wave * 2;                 // this wave's t-pair (cols t0*16..)

  f32x4 aR[2][2], aZ[2][2], aN[2][2], aH[2][2];
#pragma unroll
  for (int rt = 0; rt < 2; rt++)
#pragma unroll
    for (int ti = 0; ti < 2; ti++) {
      aR[rt][ti] = (f32x4){0.f, 0.f, 0.f, 0.f};
      aZ[rt][ti] = (f32x4){0.f, 0.f, 0.f, 0.f};
      aN[rt][ti] = (f32x4){0.f, 0.f, 0.f, 0.f};
      aH[rt][ti] = (f32x4){0.f, 0.f, 0.f, 0.f};
    }

  size_t arowc[2];
#pragma unroll
  for (int rt = 0; rt < 2; rt++)
    arowc[rt] = (size_t)(rowBase + rt * 16 + m) * 128 + g4 * 8;

  // ---- phase 0: z @ F -> r,z,i_n ----
#pragma unroll
  for (int ks = 0; ks < 4; ks++) {
    bf16x8 a[2];
#pragma unroll
    for (int rt = 0; rt < 2; rt++)
      a[rt] = *(const bf16x8*)(zb + arowc[rt] + ks * 32);
    const int bo = ks * 512 + lane * 8;
#pragma unroll
    for (int ti = 0; ti < 2; ti++) {
      const short* bp = Fb + (t0 + ti) * 2048 + bo;
      bf16x8 br = *(const bf16x8*)(bp);
      bf16x8 bz = *(const bf16x8*)(bp + 16384);
      bf16x8 bn = *(const bf16x8*)(bp + 32768);
#pragma unroll
      for (int rt = 0; rt < 2; rt++) {
        aR[rt][ti] = __builtin_amdgcn_mfma_f32_16x16x32_bf16(a[rt], br, aR[rt][ti], 0, 0, 0);
        aZ[rt][ti] = __builtin_amdgcn_mfma_f32_16x16x32_bf16(a[rt], bz, aZ[rt][ti], 0, 0, 0);
        aN[rt][ti] = __builtin_amdgcn_mfma_f32_16x16x32_bf16(a[rt], bn, aN[rt][ti], 0, 0, 0);
      }
    }
  }
  // ---- phase 1: x @ Whh^T -> r,z,h_n ----
#pragma unroll
  for (int ks = 0; ks < 4; ks++) {
    bf16x8 a[2];
#pragma unroll
    for (int rt = 0; rt < 2; rt++)
      a[rt] = *(const bf16x8*)(xb + arowc[rt] + ks * 32);
    const int bo = ks * 512 + lane * 8;
#pragma unroll
    for (int ti = 0; ti < 2; ti++) {
      const short* bp = Wb + (t0 + ti) * 2048 + bo;
      bf16x8 br = *(const bf16x8*)(bp);
      bf16x8 bz = *(const bf16x8*)(bp + 16384);
      bf16x8 bn = *(const bf16x8*)(bp + 32768);
#pragma unroll
      for (int rt = 0; rt < 2; rt++) {
        aR[rt][ti] = __builtin_amdgcn_mfma_f32_16x16x32_bf16(a[rt], br, aR[rt][ti], 0, 0, 0);
        aZ[rt][ti] = __builtin_amdgcn_mfma_f32_16x16x32_bf16(a[rt], bz, aZ[rt][ti], 0, 0, 0);
        aH[rt][ti] = __builtin_amdgcn_mfma_f32_16x16x32_bf16(a[rt], bn, aH[rt][ti], 0, 0, 0);
      }
    }
  }

  // ---- epilogue: gates + state update (C/D: col=lane&15, row=g4*4+reg) ----
  // prefetch all 16 x_old values first so VMEM latency overlaps gate VALU
  float xo[2][2][4];
  size_t xoff[2][2];
#pragma unroll
  for (int ti = 0; ti < 2; ti++)
#pragma unroll
    for (int rt = 0; rt < 2; rt++) {
      size_t o = (size_t)(rowBase + rt * 16 + g4 * 4) * 128 + (t0 + ti) * 16 + m;
      xoff[ti][rt] = o;
#pragma unroll
      for (int r = 0; r < 4; r++) xo[ti][rt][r] = x[o + (size_t)r * 128];
    }
#pragma unroll
  for (int ti = 0; ti < 2; ti++) {
    int col = (t0 + ti) * 16 + m;
    float b_r = bih[col] + bhh[col];
    float b_z = bih[128 + col] + bhh[128 + col];
    float b_i = bih[256 + col];
    float b_h = bhh[256 + col];
#pragma unroll
    for (int rt = 0; rt < 2; rt++) {
#pragma unroll
      for (int r = 0; r < 4; r++) {
        float rg = fsigmoid(aR[rt][ti][r] + b_r);
        float zg = fsigmoid(aZ[rt][ti][r] + b_z);
        float ng = ftanh(aN[rt][ti][r] + b_i + rg * (aH[rt][ti][r] + b_h));
        float xn = (1.f - zg) * ng + zg * xo[ti][rt][r];
        size_t o = xoff[ti][rt] + (size_t)r * 128;
        x[o] = xn;
        xb[o] = (short)f2bf(xn);
      }
    }
  }
}

// ---------------------------------------------------------------------------
// BatchNorm stats (fp32 master x)
// ---------------------------------------------------------------------------
__global__ __launch_bounds__(256) void bn_stats(
    const float* __restrict__ x, float* __restrict__ sums)
{
  __shared__ float ls[256], lq[256];
  int tid  = threadIdx.x;
  int col  = tid & 127, half = tid >> 7;
  int r0   = blockIdx.x * 128;
  int rend = min(N_NODES, r0 + 128);
  float s = 0.f, q = 0.f;
  for (int r = r0 + half; r < rend; r += 2) {
    float v = x[(size_t)r * HDIM + col];
    s += v; q += v * v;
  }
  ls[tid] = s; lq[tid] = q;
  __syncthreads();
  if (tid < 128) {
    atomicAdd(&sums[col],       ls[tid] + ls[tid + 128]);
    atomicAdd(&sums[128 + col], lq[tid] + lq[tid + 128]);
  }
}

__global__ void bn_finalize(float* __restrict__ sums,
                            const float* __restrict__ gamma,
                            const float* __restrict__ beta)
{
  int j = threadIdx.x;
  float mean = sums[j] / (float)N_NODES;
  float var  = sums[128 + j] / (float)N_NODES - mean * mean;
  float inv  = rsqrtf(var + 1e-5f);
  sums[256 + j] = gamma[j] * inv;
  sums[384 + j] = beta[j] - mean * gamma[j] * inv;
}

// ---------------------------------------------------------------------------
// Fused head: out = bn(x) @ mlpW + h @ e2 + c2, BN folded into A-load of x.
// ---------------------------------------------------------------------------
__global__ __launch_bounds__(256) void head_fused(
    const float* __restrict__ x, const float* __restrict__ h,
    const float* __restrict__ sums,      // scale at [256..], shift at [384..]
    const float* __restrict__ mlpW,      // [128][40]
    const float* __restrict__ e2,        // [128][40]
    const float* __restrict__ c2,        // [40]
    float* __restrict__ out)             // [N][40]
{
  __shared__ alignas(16) float lds_a[32 * 68];
  __shared__ alignas(16) float lds_b[32 * 132];
  const int tid = threadIdx.x;
  const int tx = tid & 15;
  const int ty = tid >> 4;
  const int rowBase = blockIdx.x * 64;
  const int OUT = 40;

  float acc[4][8];
#pragma unroll
  for (int r = 0; r < 4; r++)
#pragma unroll
    for (int c = 0; c < 8; c++) acc[r][c] = 0.f;

  for (int src = 0; src < 2; src++) {
    const float* A = src ? h : x;
    const float* W = src ? e2 : mlpW;
    for (int k0 = 0; k0 < 128; k0 += 32) {
#pragma unroll
      for (int i = 0; i < 2; i++) {
        int idx = tid + i * 256;
        int r   = idx >> 3;
        int kk  = (idx & 7) << 2;
        int gr  = rowBase + r;
        float4 v = make_float4(0.f, 0.f, 0.f, 0.f);
        if (gr < N_NODES) v = *(const float4*)(A + (size_t)gr * HDIM + k0 + kk);
        if (src == 0) {   // fold BatchNorm apply into the x tile load
          float4 sc = *(const float4*)(sums + 256 + k0 + kk);
          float4 sh = *(const float4*)(sums + 384 + k0 + kk);
          v.x = fmaf(v.x, sc.x, sh.x);
          v.y = fmaf(v.y, sc.y, sh.y);
          v.z = fmaf(v.z, sc.z, sh.z);
          v.w = fmaf(v.w, sc.w, sh.w);
        }
        lds_a[(kk + 0) * 68 + r] = v.x;
        lds_a[(kk + 1) * 68 + r] = v.y;
        lds_a[(kk + 2) * 68 + r] = v.z;
        lds_a[(kk + 3) * 68 + r] = v.w;
      }
#pragma unroll
      for (int i = 0; i < 4; i++) {
        int idx = tid + i * 256;
        int kk  = idx >> 5;
        int j   = (idx & 31) << 2;
        float4 v = make_float4(0.f, 0.f, 0.f, 0.f);
        if (j < OUT) v = *(const float4*)(W + (size_t)(k0 + kk) * OUT + j);
        *((float4*)&lds_b[kk * 132 + j]) = v;
      }
      __syncthreads();
#pragma unroll 8
      for (int kk = 0; kk < 32; kk++) {
        float4 a4 = *(const float4*)&lds_a[kk * 68 + ty * 4];
        float4 b0 = *(const float4*)&lds_b[kk * 132 + tx * 8];
        float4 b1 = *(const float4*)&lds_b[kk * 132 + tx * 8 + 4];
        float av[4] = {a4.x, a4.y, a4.z, a4.w};
        float bv[8] = {b0.x, b0.y, b0.z, b0.w, b1.x, b1.y, b1.z, b1.w};
#pragma unroll
        for (int r = 0; r < 4; r++)
#pragma unroll
          for (int c = 0; c < 8; c++)
            acc[r][c] = fmaf(av[r], bv[c], acc[r][c]);
      }
      __syncthreads();
    }
  }

  int col = tx * 8;
  if (col >= OUT) return;            // tx 0..4 write (cols 0..39)
  float bv[8];
#pragma unroll
  for (int c = 0; c < 8; c++) bv[c] = c2[col + c];
#pragma unroll
  for (int r = 0; r < 4; r++) {
    int gr = rowBase + ty * 4 + r;
    if (gr >= N_NODES) continue;
    float* yp = out + (size_t)gr * OUT + col;
    float4 o0 = make_float4(acc[r][0] + bv[0], acc[r][1] + bv[1],
                            acc[r][2] + bv[2], acc[r][3] + bv[3]);
    float4 o1 = make_float4(acc[r][4] + bv[4], acc[r][5] + bv[5],
                            acc[r][6] + bv[6], acc[r][7] + bv[7]);
    *(float4*)yp       = o0;
    *(float4*)(yp + 4) = o1;
  }
}

// ---------------------------------------------------------------------------
// Residual fold constants: E2 = embW @ mlpW  [128][40], c2 = mlpB + embB@mlpW
// ---------------------------------------------------------------------------
__global__ void prep_e2(const float* __restrict__ embW,
                        const float* __restrict__ embB,
                        const float* __restrict__ mlpW,
                        const float* __restrict__ mlpB,
                        float* __restrict__ e2, float* __restrict__ c2)
{
  int tid = threadIdx.x;
#pragma unroll
  for (int t = 0; t < 20; t++) {
    int idx = tid * 20 + t;
    int f = idx / 40, j = idx - f * 40;
    float s = 0.f;
    for (int k = 0; k < 128; k++)
      s = fmaf(embW[f * 128 + k], mlpW[k * 40 + j], s);
    e2[idx] = s;
  }
  if (tid < 40) {
    float s = mlpB[tid];
    for (int k = 0; k < 128; k++)
      s = fmaf(embB[k], mlpW[k * 40 + tid], s);
    c2[tid] = s;
  }
}

// ---------------------------------------------------------------------------
extern "C" void kernel_launch(void* const* d_in, const int* in_sizes, int n_in,
                              void* d_out, int out_size, void* d_ws, size_t ws_size,
                              hipStream_t stream)
{
  const float* h     = (const float*)d_in[0];
  const int*   ei    = (const int*)d_in[1];
  const float* ew    = (const float*)d_in[2];
  const float* embW  = (const float*)d_in[3];
  const float* embB  = (const float*)d_in[4];
  const float* convW = (const float*)d_in[5];   // [3][128][128]
  const float* Wih   = (const float*)d_in[6];   // [384][128]
  const float* Whh   = (const float*)d_in[7];   // [384][128]
  const float* bih   = (const float*)d_in[8];
  const float* bhh   = (const float*)d_in[9];
  const float* gamma = (const float*)d_in[10];
  const float* beta  = (const float*)d_in[11];
  const float* mlpW  = (const float*)d_in[12];
  const float* mlpB  = (const float*)d_in[13];
  float* out = (float*)d_out;

  float* ws = (float*)d_ws;
  const size_t NH = (size_t)N_NODES * HDIM;      // 12.8M
  float*    x      = ws;                          // [N][128] fp32 master
  unsigned* xbp    = (unsigned*)(ws + NH);        // [N][64] packed bf16
  unsigned* zbp    = xbp + NH / 2;                // [N][64] packed bf16
  int2*     epak   = (int2*)(zbp + NH / 2);       // [E] {src, w}
  int*      rowptr = (int*)(epak + N_EDGES);      // N+4
  int*      bcnt   = rowptr + N_NODES + 4;        // NB*16 padded counters
  int*      bstart = bcnt + NB * 16;              // NB (+pad)
  float*    Ffold  = (float*)(bstart + 256);      // [3][384][128] fp32
  short*    Fbp    = (short*)(Ffold + 3 * 384 * 128);  // frag-order bf16
  short*    Wbp    = Fbp + 3 * 384 * 128;         // frag-order bf16 of Whh
  float*    sums   = (float*)(Wbp + 384 * 128);
  float*    e2     = sums + 512;
  float*    c2     = e2 + 5120;
  // csr scratch: tmp [NB*BSLOT] int2 = 27.6 MB aliases xbp+zbp (both dead
  // until after the embedding GEMM / first agg_pull).
  int2*     tmp    = (int2*)xbp;

  dim3 blk(256);
  const int MB = (N_NODES + 63) / 64;
  const int GB = N_NODES / 32;                    // 3125, exact
  const int RB = (384 * 128 + 255) / 256;
  const int P1B = (N_EDGES + 2047) / 2048;        // 1563 (tail %8 == 0)

  // ---- constants ----
  prep_e2<<<1, 256, 0, stream>>>(embW, embB, mlpW, mlpB, e2, c2);
  for (int l = 0; l < 3; l++)
    gemm_k128<true><<<dim3(6, 1), blk, 0, stream>>>(
        Wih, convW + (size_t)l * HDIM * HDIM, nullptr,
        Ffold + (size_t)l * 384 * HDIM, nullptr, 384, 128);
  for (int l = 0; l < 3; l++)
    repack_frag_b<<<RB, blk, 0, stream>>>(
        Ffold + (size_t)l * 384 * HDIM, Fbp + (size_t)l * 384 * HDIM);
  repack_frag_b<<<RB, blk, 0, stream>>>(Whh, Wbp);

  // ---- CSR build: bucket partition -> per-bucket place (no global scatter)
  zero_i32<<<(NB * 16 + 255) / 256, blk, 0, stream>>>(bcnt, NB * 16);
  csr_part1<<<P1B, blk, 0, stream>>>(ei, ew, bcnt, tmp);
  csr_scanb<<<1, 256, 0, stream>>>(bcnt, bstart, rowptr);
  csr_part2<<<NB, blk, 0, stream>>>(tmp, bcnt, bstart, rowptr, epak);

  // ---- embedding: x = h @ embW + embB ; bf16 mirror fused in epilogue ----
  gemm_k128<false><<<dim3(MB, 1), blk, 0, stream>>>(h, embW, embB, x, xbp,
                                                    N_NODES, 128);

  // ---- 3 GRU layers: pull-agg (bf16) + fused MFMA GRU ----
  for (int l = 0; l < 3; l++) {
    agg_pull<<<(N_NODES + 3) / 4, blk, 0, stream>>>(xbp, rowptr, epak, zbp);
    gru_fused<<<GB, blk, 0, stream>>>(
        (const short*)zbp, (short*)xbp, x,
        Fbp + (size_t)l * 384 * HDIM, Wbp, bih, bhh);
  }

  // ---- BatchNorm stats + fully fused head (BN apply + both GEMMs) ----
  zero_f32<<<2, blk, 0, stream>>>(sums, 512);
  bn_stats<<<(N_NODES + 127) / 128, blk, 0, stream>>>(x, sums);
  bn_finalize<<<1, 128, 0, stream>>>(sums, gamma, beta);
  head_fused<<<dim3(MB, 1), blk, 0, stream>>>(x, h, sums, mlpW, e2, c2, out);
}

// Round 5
// 1126.267 us; speedup vs baseline: 1.4493x; 1.0240x over previous
//
#include <hip/hip_runtime.h>
#include <math.h>

#define N_NODES 100000
#define N_EDGES 3200000
#define HDIM 128

// ---- bucket sort CSR build ----
#define NB 196        // buckets of 512 consecutive dst nodes (100000/512 -> 196)
#define BSH 9         // 512 nodes per bucket
#define BSLOT 18432   // tmp slots per bucket (avg fill 16327, +16 sigma headroom)

typedef __attribute__((ext_vector_type(8))) short bf16x8;
typedef __attribute__((ext_vector_type(4))) float f32x4;

__device__ __forceinline__ unsigned short f2bf(float f) {
  union { float f; unsigned u; } v; v.f = f;
  unsigned r = v.u + 0x7fffu + ((v.u >> 16) & 1u);
  return (unsigned short)(r >> 16);
}
__device__ __forceinline__ float bflo(unsigned p) {
  union { unsigned u; float f; } v; v.u = p << 16; return v.f;
}
__device__ __forceinline__ float bfhi(unsigned p) {
  union { unsigned u; float f; } v; v.u = p & 0xffff0000u; return v.f;
}
// fast sigmoid/tanh: v_exp + v_rcp (approx err ~1e-6 << bf16 quantum 4e-3
// already present in the data path; libm tanhf is ~40 branchy VALU instrs,
// fp32 division is the ~10-instr div_scale/div_fmas sequence).
__device__ __forceinline__ float fsigmoid(float v) {
  return __builtin_amdgcn_rcpf(1.f + __expf(-v));
}
__device__ __forceinline__ float ftanh(float v) {
  return 1.f - 2.f * __builtin_amdgcn_rcpf(1.f + __expf(2.f * v));
}

// ---------------------------------------------------------------------------
__global__ __launch_bounds__(256) void zero_i32(int* __restrict__ p, int n) {
  int i = blockIdx.x * 256 + threadIdx.x;
  if (i < n) p[i] = 0;
}
__global__ __launch_bounds__(256) void zero_f32(float* __restrict__ p, int n) {
  int i = blockIdx.x * 256 + threadIdx.x;
  if (i < n) p[i] = 0.f;
}

// ---------------------------------------------------------------------------
// Repack a [384][128] fp32 weight matrix (row-major [col][k]) into
// MFMA-B-fragment-ordered bf16 (lane*16B contiguous per fragment).
// ---------------------------------------------------------------------------
__global__ __launch_bounds__(256) void repack_frag_b(
    const float* __restrict__ src, short* __restrict__ dst)
{
  int o = blockIdx.x * 256 + threadIdx.x;      // 0 .. 384*128-1
  if (o >= 384 * 128) return;
  int j    = o & 7;
  int lane = (o >> 3) & 63;
  int ks   = (o >> 9) & 3;
  int t    = o >> 11;
  int m  = lane & 15;
  int g4 = lane >> 4;
  dst[o] = (short)f2bf(src[(t * 16 + m) * 128 + ks * 32 + g4 * 8 + j]);
}

// ---------------------------------------------------------------------------
// Tiled fp32 GEMM, K fixed at 128 (emb, weight folds). Optional bf16-pack
// epilogue mirror (xpack != nullptr -> also emit packed bf16 rows).
// ---------------------------------------------------------------------------
template<bool BT>
__global__ __launch_bounds__(256) void gemm_k128(
    const float* __restrict__ A, const float* __restrict__ W,
    const float* __restrict__ bias, float* __restrict__ Y,
    unsigned* __restrict__ xpack, int M, int OUT)
{
  __shared__ alignas(16) float lds_a[32 * 68];
  __shared__ alignas(16) float lds_b[32 * 132];
  const int tid = threadIdx.x;
  const int tx = tid & 15;
  const int ty = tid >> 4;
  const int rowBase = blockIdx.x * 64;
  const int colBase = blockIdx.y * 128;

  float acc[4][8];
#pragma unroll
  for (int r = 0; r < 4; r++)
#pragma unroll
    for (int c = 0; c < 8; c++) acc[r][c] = 0.f;

  for (int k0 = 0; k0 < 128; k0 += 32) {
#pragma unroll
    for (int i = 0; i < 2; i++) {
      int idx = tid + i * 256;
      int r   = idx >> 3;
      int kk  = (idx & 7) << 2;
      int gr  = rowBase + r;
      float4 v = make_float4(0.f, 0.f, 0.f, 0.f);
      if (gr < M) v = *(const float4*)(A + (size_t)gr * HDIM + k0 + kk);
      lds_a[(kk + 0) * 68 + r] = v.x;
      lds_a[(kk + 1) * 68 + r] = v.y;
      lds_a[(kk + 2) * 68 + r] = v.z;
      lds_a[(kk + 3) * 68 + r] = v.w;
    }
    if (!BT) {
#pragma unroll
      for (int i = 0; i < 4; i++) {
        int idx = tid + i * 256;
        int kk  = idx >> 5;
        int j   = (idx & 31) << 2;
        int gj  = colBase + j;
        float4 v = make_float4(0.f, 0.f, 0.f, 0.f);
        if (gj < OUT) v = *(const float4*)(W + (size_t)(k0 + kk) * OUT + gj);
        *((float4*)&lds_b[kk * 132 + j]) = v;
      }
    } else {
#pragma unroll
      for (int i = 0; i < 4; i++) {
        int idx = tid + i * 256;
        int j   = idx >> 3;
        int k4  = (idx & 7) << 2;
        int gj  = colBase + j;
        float4 v = make_float4(0.f, 0.f, 0.f, 0.f);
        if (gj < OUT) v = *(const float4*)(W + (size_t)gj * HDIM + k0 + k4);
        lds_b[(k4 + 0) * 132 + j] = v.x;
        lds_b[(k4 + 1) * 132 + j] = v.y;
        lds_b[(k4 + 2) * 132 + j] = v.z;
        lds_b[(k4 + 3) * 132 + j] = v.w;
      }
    }
    __syncthreads();
#pragma unroll 8
    for (int kk = 0; kk < 32; kk++) {
      float4 a4 = *(const float4*)&lds_a[kk * 68 + ty * 4];
      float4 b0 = *(const float4*)&lds_b[kk * 132 + tx * 8];
      float4 b1 = *(const float4*)&lds_b[kk * 132 + tx * 8 + 4];
      float av[4] = {a4.x, a4.y, a4.z, a4.w};
      float bv[8] = {b0.x, b0.y, b0.z, b0.w, b1.x, b1.y, b1.z, b1.w};
#pragma unroll
      for (int r = 0; r < 4; r++)
#pragma unroll
        for (int c = 0; c < 8; c++)
          acc[r][c] = fmaf(av[r], bv[c], acc[r][c]);
    }
    __syncthreads();
  }

  int col = colBase + tx * 8;
  if (col >= OUT) return;
  float bv[8];
#pragma unroll
  for (int c = 0; c < 8; c++) bv[c] = bias ? bias[col + c] : 0.f;
#pragma unroll
  for (int r = 0; r < 4; r++) {
    int gr = rowBase + ty * 4 + r;
    if (gr >= M) continue;
    float* yp = Y + (size_t)gr * OUT + col;
    float4 o0 = make_float4(acc[r][0] + bv[0], acc[r][1] + bv[1],
                            acc[r][2] + bv[2], acc[r][3] + bv[3]);
    float4 o1 = make_float4(acc[r][4] + bv[4], acc[r][5] + bv[5],
                            acc[r][6] + bv[6], acc[r][7] + bv[7]);
    *(float4*)yp       = o0;
    *(float4*)(yp + 4) = o1;
    if (xpack) {                       // packed bf16 mirror (emb path)
      uint4 p;
      p.x = (unsigned)f2bf(o0.x) | ((unsigned)f2bf(o0.y) << 16);
      p.y = (unsigned)f2bf(o0.z) | ((unsigned)f2bf(o0.w) << 16);
      p.z = (unsigned)f2bf(o1.x) | ((unsigned)f2bf(o1.y) << 16);
      p.w = (unsigned)f2bf(o1.z) | ((unsigned)f2bf(o1.w) << 16);
      *(uint4*)&xpack[(size_t)gr * 64 + (col >> 1)] = p;
    }
  }
}

// ---------------------------------------------------------------------------
// CSR build, two-pass bucket sort (see round-2 notes: kills the random 8-B
// global scatter and csr_hist's 3.2M random atomics).
// Edge record in tmp: x = src | (local_dst << 17)  (17+9 = 26 bits), y = w.
// Final epak record: x = src << 8 (byte offset of the 256-B xbp row,
// pre-scaled so agg_pull's gather address is a single add), y = w.
// ---------------------------------------------------------------------------
__global__ __launch_bounds__(256) void csr_part1(
    const int* __restrict__ ei, const float* __restrict__ ew,
    int* __restrict__ bcnt,        // [NB*16] padded counters (one line each)
    int2* __restrict__ tmp)        // [NB*BSLOT]
{
  __shared__ int hist[NB];
  __shared__ int gbase[NB];
  const int tid = threadIdx.x;
  for (int i = tid; i < NB; i += 256) hist[i] = 0;
  __syncthreads();
  const int e0 = blockIdx.x * 2048 + tid * 8;   // 8 consecutive edges/thread
  const bool act = (e0 < N_EDGES);              // tail remainder is %8==0
  int4 s0, s1, d0, d1; float4 w0, w1;
  int rb[8];
  if (act) {
    s0 = *(const int4*)(ei + e0);
    s1 = *(const int4*)(ei + e0 + 4);
    d0 = *(const int4*)(ei + N_EDGES + e0);
    d1 = *(const int4*)(ei + N_EDGES + e0 + 4);
    w0 = *(const float4*)(ew + e0);
    w1 = *(const float4*)(ew + e0 + 4);
    int dv[8] = {d0.x, d0.y, d0.z, d0.w, d1.x, d1.y, d1.z, d1.w};
#pragma unroll
    for (int j = 0; j < 8; j++) {
      int b = dv[j] >> BSH;
      int r = atomicAdd(&hist[b], 1);
      rb[j] = (r << 8) | b;                     // rank<2048 (11b), b<196 (8b)
    }
  }
  __syncthreads();
  for (int i = tid; i < NB; i += 256) {
    int c = hist[i];
    gbase[i] = c ? atomicAdd(&bcnt[i * 16], c) : 0;  // one reserve per bucket
  }
  __syncthreads();
  if (act) {
    int sv[8] = {s0.x, s0.y, s0.z, s0.w, s1.x, s1.y, s1.z, s1.w};
    int dv[8] = {d0.x, d0.y, d0.z, d0.w, d1.x, d1.y, d1.z, d1.w};
    int wv[8] = {__float_as_int(w0.x), __float_as_int(w0.y),
                 __float_as_int(w0.z), __float_as_int(w0.w),
                 __float_as_int(w1.x), __float_as_int(w1.y),
                 __float_as_int(w1.z), __float_as_int(w1.w)};
#pragma unroll
    for (int j = 0; j < 8; j++) {
      int b  = rb[j] & 255;
      int of = gbase[b] + (rb[j] >> 8);
      if (of < BSLOT)                            // memory-safety guard only
        tmp[b * BSLOT + of] =
            make_int2(sv[j] | ((dv[j] & 511) << 17), wv[j]);
    }
  }
}

// exclusive scan of bucket counts -> bucket start offsets; rowptr[N] = E
__global__ void csr_scanb(const int* __restrict__ bcnt,
                          int* __restrict__ bstart, int* __restrict__ rowptr)
{
  __shared__ int l[256];
  int t = threadIdx.x;
  int v = (t < NB) ? min(bcnt[t * 16], BSLOT) : 0;
  l[t] = v;
  __syncthreads();
  for (int off = 1; off < 256; off <<= 1) {
    int u = (t >= off) ? l[t - off] : 0;
    __syncthreads();
    l[t] += u;
    __syncthreads();
  }
  if (t < NB) bstart[t] = l[t] - v;
  if (t == 255) rowptr[N_NODES] = l[255];
}

// per bucket: LDS node-hist -> LDS scan -> rowptr slice (coalesced) ->
// final in-bucket placement (reads+writes stay in ~130 KB, L2-resident).
__global__ __launch_bounds__(256) void csr_part2(
    const int2* __restrict__ tmp, const int* __restrict__ bcnt,
    const int* __restrict__ bstart, int* __restrict__ rowptr,
    int2* __restrict__ epak)
{
  __shared__ int cnt[512];
  __shared__ int lofs[512];
  __shared__ int s2[256];
  const int b      = blockIdx.x;
  const int tid    = threadIdx.x;
  const int nbase  = b << BSH;
  const int nn     = min(512, N_NODES - nbase);
  const int ecount = min(bcnt[b * 16], BSLOT);
  const long tbase = (long)b * BSLOT;
  const int obase  = bstart[b];
  for (int i = tid; i < 512; i += 256) cnt[i] = 0;
  __syncthreads();
  // pass A: per-node histogram of this bucket
  for (int e = tid; e < ecount; e += 256) {
    int2 rec = tmp[tbase + e];
    atomicAdd(&cnt[(rec.x >> 17) & 511], 1);
  }
  __syncthreads();
  // exclusive scan over 512 node counts (pairs + Hillis-Steele on 256)
  int c0 = cnt[2 * tid], c1 = cnt[2 * tid + 1];
  s2[tid] = c0 + c1;
  __syncthreads();
  int inc = s2[tid];
  for (int off = 1; off < 256; off <<= 1) {
    int u = (tid >= off) ? s2[tid - off] : 0;
    __syncthreads();
    s2[tid] += u;
    __syncthreads();
  }
  int ex = s2[tid] - inc;
  lofs[2 * tid]     = ex;
  lofs[2 * tid + 1] = ex + c0;
  __syncthreads();
  // rowptr slice, coalesced (replaces csr_hist + global scan entirely)
  for (int i = tid; i < nn; i += 256) rowptr[nbase + i] = obase + lofs[i];
  for (int i = tid; i < 512; i += 256) cnt[i] = 0;
  __syncthreads();
  // pass B: place edges at final CSR positions (within-row order arbitrary).
  // src is pre-scaled to its xbp byte offset (src*256) for agg_pull.
  for (int e = tid; e < ecount; e += 256) {
    int2 rec = tmp[tbase + e];
    int ldst = (rec.x >> 17) & 511;
    int r = atomicAdd(&cnt[ldst], 1);
    epak[obase + lofs[ldst] + r] = make_int2((rec.x & 0x1FFFF) << 8, rec.y);
  }
}

// ---------------------------------------------------------------------------
// Pull aggregation on bf16 x: z[n] = sum w_e * x[src_e], fp32 accumulate,
// bf16 packed output. One wave/node, lane covers cols {2*lane, 2*lane+1}.
// v2: epak.x holds the row's BYTE offset (pre-scaled in csr_part2) so the
// gather address is base+lane*4+epak.x (one v_add); 8-edge unroll with
// paired int4 epak loads doubles gathers in flight (latency-bound fix)
// and halves epak load instructions. 4*25000 == N exactly -> no guard.
// ---------------------------------------------------------------------------
__global__ __launch_bounds__(256) void agg_pull(
    const unsigned* __restrict__ xbp, const int* __restrict__ rowptr,
    const int2* __restrict__ epak, unsigned* __restrict__ zbp)
{
  const int node = blockIdx.x * 4 + (threadIdx.x >> 6);
  const int lane = threadIdx.x & 63;
  const char* xb = (const char*)xbp + lane * 4;
  int e = rowptr[node];
  const int s1 = rowptr[node + 1];
  float v0 = 0.f, v1 = 0.f;
  // alignment pre-step: make e even so int4 loads on epak are 16-B aligned
  if ((e & 1) && e < s1) {
    int2 ep = epak[e++];
    unsigned p = *(const unsigned*)(xb + ep.x);
    float w = __int_as_float(ep.y);
    v0 = fmaf(w, bflo(p), v0); v1 = fmaf(w, bfhi(p), v1);
  }
  const int n8 = e + ((s1 - e) & ~7);
  for (; e < n8; e += 8) {
    int4 ea = *(const int4*)(epak + e);
    int4 eb = *(const int4*)(epak + e + 2);
    int4 ec = *(const int4*)(epak + e + 4);
    int4 ed = *(const int4*)(epak + e + 6);
    unsigned p0 = *(const unsigned*)(xb + ea.x);
    unsigned p1 = *(const unsigned*)(xb + ea.z);
    unsigned p2 = *(const unsigned*)(xb + eb.x);
    unsigned p3 = *(const unsigned*)(xb + eb.z);
    unsigned p4 = *(const unsigned*)(xb + ec.x);
    unsigned p5 = *(const unsigned*)(xb + ec.z);
    unsigned p6 = *(const unsigned*)(xb + ed.x);
    unsigned p7 = *(const unsigned*)(xb + ed.z);
    float w0 = __int_as_float(ea.y), w1 = __int_as_float(ea.w);
    float w2 = __int_as_float(eb.y), w3 = __int_as_float(eb.w);
    float w4 = __int_as_float(ec.y), w5 = __int_as_float(ec.w);
    float w6 = __int_as_float(ed.y), w7 = __int_as_float(ed.w);
    v0 = fmaf(w0, bflo(p0), v0); v1 = fmaf(w0, bfhi(p0), v1);
    v0 = fmaf(w1, bflo(p1), v0); v1 = fmaf(w1, bfhi(p1), v1);
    v0 = fmaf(w2, bflo(p2), v0); v1 = fmaf(w2, bfhi(p2), v1);
    v0 = fmaf(w3, bflo(p3), v0); v1 = fmaf(w3, bfhi(p3), v1);
    v0 = fmaf(w4, bflo(p4), v0); v1 = fmaf(w4, bfhi(p4), v1);
    v0 = fmaf(w5, bflo(p5), v0); v1 = fmaf(w5, bfhi(p5), v1);
    v0 = fmaf(w6, bflo(p6), v0); v1 = fmaf(w6, bfhi(p6), v1);
    v0 = fmaf(w7, bflo(p7), v0); v1 = fmaf(w7, bfhi(p7), v1);
  }
  for (; e < s1; e++) {
    int2 ep = epak[e];
    unsigned p = *(const unsigned*)(xb + ep.x);
    float w = __int_as_float(ep.y);
    v0 = fmaf(w, bflo(p), v0); v1 = fmaf(w, bfhi(p), v1);
  }
  zbp[(size_t)node * 64 + lane] =
      (unsigned)f2bf(v0) | ((unsigned)f2bf(v1) << 16);
}

// ---------------------------------------------------------------------------
// Fused GRU layer (bf16 MFMA), v3 partition: block = 32 rows (2 row-tiles),
// 4 waves each own 2 t-column-tiles for all 32 rows. Accumulators:
// 2rt x 2ti x 4 sets = 64 VGPR. launch_bounds(256,4) caps at 128 VGPR.
// 32 | 100000 exactly -> no row guards. Fast sigmoid/tanh (see helpers).
// ---------------------------------------------------------------------------
__global__ __launch_bounds__(256, 4) void gru_fused(
    const short* __restrict__ zb, short* __restrict__ xb,
    float* __restrict__ x,
    const short* __restrict__ Fb, const short* __restrict__ Wb,
    const float* __restrict__ bih, const float* __restrict__ bhh)
{
  const int wave = threadIdx.x >> 6, lane = threadIdx.x & 63;
  const int m  = lane & 15;
  const int g4 = lane >> 4;
  const int rowBase = blockIdx.x * 32;
  const int t0 = wave * 2;                 // this wave's t-pair (cols t0*16..)

  f32x4 aR[2][2], aZ[2][2], aN[2][2], aH[2][2];
#pragma unroll
  for (int rt = 0; rt < 2; rt++)
#pragma unroll
    for (int ti = 0; ti < 2; ti++) {
      aR[rt][ti] = (f32x4){0.f, 0.f, 0.f, 0.f};
      aZ[rt][ti] = (f32x4){0.f, 0.f, 0.f, 0.f};
      aN[rt][ti] = (f32x4){0.f, 0.f, 0.f, 0.f};
      aH[rt][ti] = (f32x4){0.f, 0.f, 0.f, 0.f};
    }

  size_t arowc[2];
#pragma unroll
  for (int rt = 0; rt < 2; rt++)
    arowc[rt] = (size_t)(rowBase + rt * 16 + m) * 128 + g4 * 8;

  // ---- phase 0: z @ F -> r,z,i_n ----
#pragma unroll
  for (int ks = 0; ks < 4; ks++) {
    bf16x8 a[2];
#pragma unroll
    for (int rt = 0; rt < 2; rt++)
      a[rt] = *(const bf16x8*)(zb + arowc[rt] + ks * 32);
    const int bo = ks * 512 + lane * 8;
#pragma unroll
    for (int ti = 0; ti < 2; ti++) {
      const short* bp = Fb + (t0 + ti) * 2048 + bo;
      bf16x8 br = *(const bf16x8*)(bp);
      bf16x8 bz = *(const bf16x8*)(bp + 16384);
      bf16x8 bn = *(const bf16x8*)(bp + 32768);
#pragma unroll
      for (int rt = 0; rt < 2; rt++) {
        aR[rt][ti] = __builtin_amdgcn_mfma_f32_16x16x32_bf16(a[rt], br, aR[rt][ti], 0, 0, 0);
        aZ[rt][ti] = __builtin_amdgcn_mfma_f32_16x16x32_bf16(a[rt], bz, aZ[rt][ti], 0, 0, 0);
        aN[rt][ti] = __builtin_amdgcn_mfma_f32_16x16x32_bf16(a[rt], bn, aN[rt][ti], 0, 0, 0);
      }
    }
  }
  // ---- phase 1: x @ Whh^T -> r,z,h_n ----
#pragma unroll
  for (int ks = 0; ks < 4; ks++) {
    bf16x8 a[2];
#pragma unroll
    for (int rt = 0; rt < 2; rt++)
      a[rt] = *(const bf16x8*)(xb + arowc[rt] + ks * 32);
    const int bo = ks * 512 + lane * 8;
#pragma unroll
    for (int ti = 0; ti < 2; ti++) {
      const short* bp = Wb + (t0 + ti) * 2048 + bo;
      bf16x8 br = *(const bf16x8*)(bp);
      bf16x8 bz = *(const bf16x8*)(bp + 16384);
      bf16x8 bn = *(const bf16x8*)(bp + 32768);
#pragma unroll
      for (int rt = 0; rt < 2; rt++) {
        aR[rt][ti] = __builtin_amdgcn_mfma_f32_16x16x32_bf16(a[rt], br, aR[rt][ti], 0, 0, 0);
        aZ[rt][ti] = __builtin_amdgcn_mfma_f32_16x16x32_bf16(a[rt], bz, aZ[rt][ti], 0, 0, 0);
        aH[rt][ti] = __builtin_amdgcn_mfma_f32_16x16x32_bf16(a[rt], bn, aH[rt][ti], 0, 0, 0);
      }
    }
  }

  // ---- epilogue: gates + state update (C/D: col=lane&15, row=g4*4+reg) ----
  // prefetch all 16 x_old values first so VMEM latency overlaps gate VALU
  float xo[2][2][4];
  size_t xoff[2][2];
#pragma unroll
  for (int ti = 0; ti < 2; ti++)
#pragma unroll
    for (int rt = 0; rt < 2; rt++) {
      size_t o = (size_t)(rowBase + rt * 16 + g4 * 4) * 128 + (t0 + ti) * 16 + m;
      xoff[ti][rt] = o;
#pragma unroll
      for (int r = 0; r < 4; r++) xo[ti][rt][r] = x[o + (size_t)r * 128];
    }
#pragma unroll
  for (int ti = 0; ti < 2; ti++) {
    int col = (t0 + ti) * 16 + m;
    float b_r = bih[col] + bhh[col];
    float b_z = bih[128 + col] + bhh[128 + col];
    float b_i = bih[256 + col];
    float b_h = bhh[256 + col];
#pragma unroll
    for (int rt = 0; rt < 2; rt++) {
#pragma unroll
      for (int r = 0; r < 4; r++) {
        float rg = fsigmoid(aR[rt][ti][r] + b_r);
        float zg = fsigmoid(aZ[rt][ti][r] + b_z);
        float ng = ftanh(aN[rt][ti][r] + b_i + rg * (aH[rt][ti][r] + b_h));
        float xn = (1.f - zg) * ng + zg * xo[ti][rt][r];
        size_t o = xoff[ti][rt] + (size_t)r * 128;
        x[o] = xn;
        xb[o] = (short)f2bf(xn);
      }
    }
  }
}

// ---------------------------------------------------------------------------
// BatchNorm stats (fp32 master x)
// ---------------------------------------------------------------------------
__global__ __launch_bounds__(256) void bn_stats(
    const float* __restrict__ x, float* __restrict__ sums)
{
  __shared__ float ls[256], lq[256];
  int tid  = threadIdx.x;
  int col  = tid & 127, half = tid >> 7;
  int r0   = blockIdx.x * 128;
  int rend = min(N_NODES, r0 + 128);
  float s = 0.f, q = 0.f;
  for (int r = r0 + half; r < rend; r += 2) {
    float v = x[(size_t)r * HDIM + col];
    s += v; q += v * v;
  }
  ls[tid] = s; lq[tid] = q;
  __syncthreads();
  if (tid < 128) {
    atomicAdd(&sums[col],       ls[tid] + ls[tid + 128]);
    atomicAdd(&sums[128 + col], lq[tid] + lq[tid + 128]);
  }
}

__global__ void bn_finalize(float* __restrict__ sums,
                            const float* __restrict__ gamma,
                            const float* __restrict__ beta)
{
  int j = threadIdx.x;
  float mean = sums[j] / (float)N_NODES;
  float var  = sums[128 + j] / (float)N_NODES - mean * mean;
  float inv  = rsqrtf(var + 1e-5f);
  sums[256 + j] = gamma[j] * inv;
  sums[384 + j] = beta[j] - mean * gamma[j] * inv;
}

// ---------------------------------------------------------------------------
// Fused head: out = bn(x) @ mlpW + h @ e2 + c2, BN folded into A-load of x.
// ---------------------------------------------------------------------------
__global__ __launch_bounds__(256) void head_fused(
    const float* __restrict__ x, const float* __restrict__ h,
    const float* __restrict__ sums,      // scale at [256..], shift at [384..]
    const float* __restrict__ mlpW,      // [128][40]
    const float* __restrict__ e2,        // [128][40]
    const float* __restrict__ c2,        // [40]
    float* __restrict__ out)             // [N][40]
{
  __shared__ alignas(16) float lds_a[32 * 68];
  __shared__ alignas(16) float lds_b[32 * 132];
  const int tid = threadIdx.x;
  const int tx = tid & 15;
  const int ty = tid >> 4;
  const int rowBase = blockIdx.x * 64;
  const int OUT = 40;

  float acc[4][8];
#pragma unroll
  for (int r = 0; r < 4; r++)
#pragma unroll
    for (int c = 0; c < 8; c++) acc[r][c] = 0.f;

  for (int src = 0; src < 2; src++) {
    const float* A = src ? h : x;
    const float* W = src ? e2 : mlpW;
    for (int k0 = 0; k0 < 128; k0 += 32) {
#pragma unroll
      for (int i = 0; i < 2; i++) {
        int idx = tid + i * 256;
        int r   = idx >> 3;
        int kk  = (idx & 7) << 2;
        int gr  = rowBase + r;
        float4 v = make_float4(0.f, 0.f, 0.f, 0.f);
        if (gr < N_NODES) v = *(const float4*)(A + (size_t)gr * HDIM + k0 + kk);
        if (src == 0) {   // fold BatchNorm apply into the x tile load
          float4 sc = *(const float4*)(sums + 256 + k0 + kk);
          float4 sh = *(const float4*)(sums + 384 + k0 + kk);
          v.x = fmaf(v.x, sc.x, sh.x);
          v.y = fmaf(v.y, sc.y, sh.y);
          v.z = fmaf(v.z, sc.z, sh.z);
          v.w = fmaf(v.w, sc.w, sh.w);
        }
        lds_a[(kk + 0) * 68 + r] = v.x;
        lds_a[(kk + 1) * 68 + r] = v.y;
        lds_a[(kk + 2) * 68 + r] = v.z;
        lds_a[(kk + 3) * 68 + r] = v.w;
      }
#pragma unroll
      for (int i = 0; i < 4; i++) {
        int idx = tid + i * 256;
        int kk  = idx >> 5;
        int j   = (idx & 31) << 2;
        float4 v = make_float4(0.f, 0.f, 0.f, 0.f);
        if (j < OUT) v = *(const float4*)(W + (size_t)(k0 + kk) * OUT + j);
        *((float4*)&lds_b[kk * 132 + j]) = v;
      }
      __syncthreads();
#pragma unroll 8
      for (int kk = 0; kk < 32; kk++) {
        float4 a4 = *(const float4*)&lds_a[kk * 68 + ty * 4];
        float4 b0 = *(const float4*)&lds_b[kk * 132 + tx * 8];
        float4 b1 = *(const float4*)&lds_b[kk * 132 + tx * 8 + 4];
        float av[4] = {a4.x, a4.y, a4.z, a4.w};
        float bv[8] = {b0.x, b0.y, b0.z, b0.w, b1.x, b1.y, b1.z, b1.w};
#pragma unroll
        for (int r = 0; r < 4; r++)
#pragma unroll
          for (int c = 0; c < 8; c++)
            acc[r][c] = fmaf(av[r], bv[c], acc[r][c]);
      }
      __syncthreads();
    }
  }

  int col = tx * 8;
  if (col >= OUT) return;            // tx 0..4 write (cols 0..39)
  float bv[8];
#pragma unroll
  for (int c = 0; c < 8; c++) bv[c] = c2[col + c];
#pragma unroll
  for (int r = 0; r < 4; r++) {
    int gr = rowBase + ty * 4 + r;
    if (gr >= N_NODES) continue;
    float* yp = out + (size_t)gr * OUT + col;
    float4 o0 = make_float4(acc[r][0] + bv[0], acc[r][1] + bv[1],
                            acc[r][2] + bv[2], acc[r][3] + bv[3]);
    float4 o1 = make_float4(acc[r][4] + bv[4], acc[r][5] + bv[5],
                            acc[r][6] + bv[6], acc[r][7] + bv[7]);
    *(float4*)yp       = o0;
    *(float4*)(yp + 4) = o1;
  }
}

// ---------------------------------------------------------------------------
// Residual fold constants: E2 = embW @ mlpW  [128][40], c2 = mlpB + embB@mlpW
// ---------------------------------------------------------------------------
__global__ void prep_e2(const float* __restrict__ embW,
                        const float* __restrict__ embB,
                        const float* __restrict__ mlpW,
                        const float* __restrict__ mlpB,
                        float* __restrict__ e2, float* __restrict__ c2)
{
  int tid = threadIdx.x;
#pragma unroll
  for (int t = 0; t < 20; t++) {
    int idx = tid * 20 + t;
    int f = idx / 40, j = idx - f * 40;
    float s = 0.f;
    for (int k = 0; k < 128; k++)
      s = fmaf(embW[f * 128 + k], mlpW[k * 40 + j], s);
    e2[idx] = s;
  }
  if (tid < 40) {
    float s = mlpB[tid];
    for (int k = 0; k < 128; k++)
      s = fmaf(embB[k], mlpW[k * 40 + tid], s);
    c2[tid] = s;
  }
}

// ---------------------------------------------------------------------------
extern "C" void kernel_launch(void* const* d_in, const int* in_sizes, int n_in,
                              void* d_out, int out_size, void* d_ws, size_t ws_size,
                              hipStream_t stream)
{
  const float* h     = (const float*)d_in[0];
  const int*   ei    = (const int*)d_in[1];
  const float* ew    = (const float*)d_in[2];
  const float* embW  = (const float*)d_in[3];
  const float* embB  = (const float*)d_in[4];
  const float* convW = (const float*)d_in[5];   // [3][128][128]
  const float* Wih   = (const float*)d_in[6];   // [384][128]
  const float* Whh   = (const float*)d_in[7];   // [384][128]
  const float* bih   = (const float*)d_in[8];
  const float* bhh   = (const float*)d_in[9];
  const float* gamma = (const float*)d_in[10];
  const float* beta  = (const float*)d_in[11];
  const float* mlpW  = (const float*)d_in[12];
  const float* mlpB  = (const float*)d_in[13];
  float* out = (float*)d_out;

  float* ws = (float*)d_ws;
  const size_t NH = (size_t)N_NODES * HDIM;      // 12.8M
  float*    x      = ws;                          // [N][128] fp32 master
  unsigned* xbp    = (unsigned*)(ws + NH);        // [N][64] packed bf16
  unsigned* zbp    = xbp + NH / 2;                // [N][64] packed bf16
  int2*     epak   = (int2*)(zbp + NH / 2);       // [E] {src_byteoff, w}
  int*      rowptr = (int*)(epak + N_EDGES);      // N+4
  int*      bcnt   = rowptr + N_NODES + 4;        // NB*16 padded counters
  int*      bstart = bcnt + NB * 16;              // NB (+pad)
  float*    Ffold  = (float*)(bstart + 256);      // [3][384][128] fp32
  short*    Fbp    = (short*)(Ffold + 3 * 384 * 128);  // frag-order bf16
  short*    Wbp    = Fbp + 3 * 384 * 128;         // frag-order bf16 of Whh
  float*    sums   = (float*)(Wbp + 384 * 128);
  float*    e2     = sums + 512;
  float*    c2     = e2 + 5120;
  // csr scratch: tmp [NB*BSLOT] int2 = 27.6 MB aliases xbp+zbp (both dead
  // until after the embedding GEMM / first agg_pull).
  int2*     tmp    = (int2*)xbp;

  dim3 blk(256);
  const int MB = (N_NODES + 63) / 64;
  const int GB = N_NODES / 32;                    // 3125, exact
  const int RB = (384 * 128 + 255) / 256;
  const int P1B = (N_EDGES + 2047) / 2048;        // 1563 (tail %8 == 0)

  // ---- constants ----
  prep_e2<<<1, 256, 0, stream>>>(embW, embB, mlpW, mlpB, e2, c2);
  for (int l = 0; l < 3; l++)
    gemm_k128<true><<<dim3(6, 1), blk, 0, stream>>>(
        Wih, convW + (size_t)l * HDIM * HDIM, nullptr,
        Ffold + (size_t)l * 384 * HDIM, nullptr, 384, 128);
  for (int l = 0; l < 3; l++)
    repack_frag_b<<<RB, blk, 0, stream>>>(
        Ffold + (size_t)l * 384 * HDIM, Fbp + (size_t)l * 384 * HDIM);
  repack_frag_b<<<RB, blk, 0, stream>>>(Whh, Wbp);

  // ---- CSR build: bucket partition -> per-bucket place (no global scatter)
  zero_i32<<<(NB * 16 + 255) / 256, blk, 0, stream>>>(bcnt, NB * 16);
  csr_part1<<<P1B, blk, 0, stream>>>(ei, ew, bcnt, tmp);
  csr_scanb<<<1, 256, 0, stream>>>(bcnt, bstart, rowptr);
  csr_part2<<<NB, blk, 0, stream>>>(tmp, bcnt, bstart, rowptr, epak);

  // ---- embedding: x = h @ embW + embB ; bf16 mirror fused in epilogue ----
  gemm_k128<false><<<dim3(MB, 1), blk, 0, stream>>>(h, embW, embB, x, xbp,
                                                    N_NODES, 128);

  // ---- 3 GRU layers: pull-agg (bf16) + fused MFMA GRU ----
  for (int l = 0; l < 3; l++) {
    agg_pull<<<N_NODES / 4, blk, 0, stream>>>(xbp, rowptr, epak, zbp);
    gru_fused<<<GB, blk, 0, stream>>>(
        (const short*)zbp, (short*)xbp, x,
        Fbp + (size_t)l * 384 * HDIM, Wbp, bih, bhh);
  }

  // ---- BatchNorm stats + fully fused head (BN apply + both GEMMs) ----
  zero_f32<<<2, blk, 0, stream>>>(sums, 512);
  bn_stats<<<(N_NODES + 127) / 128, blk, 0, stream>>>(x, sums);
  bn_finalize<<<1, 128, 0, stream>>>(sums, gamma, beta);
  head_fused<<<dim3(MB, 1), blk, 0, stream>>>(x, h, sums, mlpW, e2, c2, out);
}

// Round 6
// 1097.879 us; speedup vs baseline: 1.4868x; 1.0259x over previous
//
#include <hip/hip_runtime.h>
#include <math.h>

#define N_NODES 100000
#define N_EDGES 3200000
#define HDIM 128

// ---- bucket sort CSR build ----
#define NB 196        // buckets of 512 consecutive dst nodes (100000/512 -> 196)
#define BSH 9         // 512 nodes per bucket
#define BSLOT 18432   // tmp slots per bucket (avg fill 16327, +16 sigma headroom)

typedef __attribute__((ext_vector_type(8))) short bf16x8;
typedef __attribute__((ext_vector_type(4))) float f32x4;

__device__ __forceinline__ unsigned short f2bf(float f) {
  union { float f; unsigned u; } v; v.f = f;
  unsigned r = v.u + 0x7fffu + ((v.u >> 16) & 1u);
  return (unsigned short)(r >> 16);
}
__device__ __forceinline__ float bflo(unsigned p) {
  union { unsigned u; float f; } v; v.u = p << 16; return v.f;
}
__device__ __forceinline__ float bfhi(unsigned p) {
  union { unsigned u; float f; } v; v.u = p & 0xffff0000u; return v.f;
}
// fast sigmoid/tanh: v_exp + v_rcp (approx err ~1e-6 << bf16 quantum 4e-3
// already present in the data path).
__device__ __forceinline__ float fsigmoid(float v) {
  return __builtin_amdgcn_rcpf(1.f + __expf(-v));
}
__device__ __forceinline__ float ftanh(float v) {
  return 1.f - 2.f * __builtin_amdgcn_rcpf(1.f + __expf(2.f * v));
}

// ---------------------------------------------------------------------------
__global__ __launch_bounds__(256) void zero_i32(int* __restrict__ p, int n) {
  int i = blockIdx.x * 256 + threadIdx.x;
  if (i < n) p[i] = 0;
}
__global__ __launch_bounds__(256) void zero_f32(float* __restrict__ p, int n) {
  int i = blockIdx.x * 256 + threadIdx.x;
  if (i < n) p[i] = 0.f;
}

// ---------------------------------------------------------------------------
// Repack a [384][128] fp32 weight matrix (row-major [col][k]) into
// MFMA-B-fragment-ordered bf16 (lane*16B contiguous per fragment).
// ---------------------------------------------------------------------------
__global__ __launch_bounds__(256) void repack_frag_b(
    const float* __restrict__ src, short* __restrict__ dst)
{
  int o = blockIdx.x * 256 + threadIdx.x;      // 0 .. 384*128-1
  if (o >= 384 * 128) return;
  int j    = o & 7;
  int lane = (o >> 3) & 63;
  int ks   = (o >> 9) & 3;
  int t    = o >> 11;
  int m  = lane & 15;
  int g4 = lane >> 4;
  dst[o] = (short)f2bf(src[(t * 16 + m) * 128 + ks * 32 + g4 * 8 + j]);
}

// ---------------------------------------------------------------------------
// Tiled fp32 GEMM, K fixed at 128 (emb, weight folds). Optional bf16-pack
// epilogue mirror (xpack != nullptr -> also emit packed bf16 rows).
// ---------------------------------------------------------------------------
template<bool BT>
__global__ __launch_bounds__(256) void gemm_k128(
    const float* __restrict__ A, const float* __restrict__ W,
    const float* __restrict__ bias, float* __restrict__ Y,
    unsigned* __restrict__ xpack, int M, int OUT)
{
  __shared__ alignas(16) float lds_a[32 * 68];
  __shared__ alignas(16) float lds_b[32 * 132];
  const int tid = threadIdx.x;
  const int tx = tid & 15;
  const int ty = tid >> 4;
  const int rowBase = blockIdx.x * 64;
  const int colBase = blockIdx.y * 128;

  float acc[4][8];
#pragma unroll
  for (int r = 0; r < 4; r++)
#pragma unroll
    for (int c = 0; c < 8; c++) acc[r][c] = 0.f;

  for (int k0 = 0; k0 < 128; k0 += 32) {
#pragma unroll
    for (int i = 0; i < 2; i++) {
      int idx = tid + i * 256;
      int r   = idx >> 3;
      int kk  = (idx & 7) << 2;
      int gr  = rowBase + r;
      float4 v = make_float4(0.f, 0.f, 0.f, 0.f);
      if (gr < M) v = *(const float4*)(A + (size_t)gr * HDIM + k0 + kk);
      lds_a[(kk + 0) * 68 + r] = v.x;
      lds_a[(kk + 1) * 68 + r] = v.y;
      lds_a[(kk + 2) * 68 + r] = v.z;
      lds_a[(kk + 3) * 68 + r] = v.w;
    }
    if (!BT) {
#pragma unroll
      for (int i = 0; i < 4; i++) {
        int idx = tid + i * 256;
        int kk  = idx >> 5;
        int j   = (idx & 31) << 2;
        int gj  = colBase + j;
        float4 v = make_float4(0.f, 0.f, 0.f, 0.f);
        if (gj < OUT) v = *(const float4*)(W + (size_t)(k0 + kk) * OUT + gj);
        *((float4*)&lds_b[kk * 132 + j]) = v;
      }
    } else {
#pragma unroll
      for (int i = 0; i < 4; i++) {
        int idx = tid + i * 256;
        int j   = idx >> 3;
        int k4  = (idx & 7) << 2;
        int gj  = colBase + j;
        float4 v = make_float4(0.f, 0.f, 0.f, 0.f);
        if (gj < OUT) v = *(const float4*)(W + (size_t)gj * HDIM + k0 + k4);
        lds_b[(k4 + 0) * 132 + j] = v.x;
        lds_b[(k4 + 1) * 132 + j] = v.y;
        lds_b[(k4 + 2) * 132 + j] = v.z;
        lds_b[(k4 + 3) * 132 + j] = v.w;
      }
    }
    __syncthreads();
#pragma unroll 8
    for (int kk = 0; kk < 32; kk++) {
      float4 a4 = *(const float4*)&lds_a[kk * 68 + ty * 4];
      float4 b0 = *(const float4*)&lds_b[kk * 132 + tx * 8];
      float4 b1 = *(const float4*)&lds_b[kk * 132 + tx * 8 + 4];
      float av[4] = {a4.x, a4.y, a4.z, a4.w};
      float bv[8] = {b0.x, b0.y, b0.z, b0.w, b1.x, b1.y, b1.z, b1.w};
#pragma unroll
      for (int r = 0; r < 4; r++)
#pragma unroll
        for (int c = 0; c < 8; c++)
          acc[r][c] = fmaf(av[r], bv[c], acc[r][c]);
    }
    __syncthreads();
  }

  int col = colBase + tx * 8;
  if (col >= OUT) return;
  float bv[8];
#pragma unroll
  for (int c = 0; c < 8; c++) bv[c] = bias ? bias[col + c] : 0.f;
#pragma unroll
  for (int r = 0; r < 4; r++) {
    int gr = rowBase + ty * 4 + r;
    if (gr >= M) continue;
    float* yp = Y + (size_t)gr * OUT + col;
    float4 o0 = make_float4(acc[r][0] + bv[0], acc[r][1] + bv[1],
                            acc[r][2] + bv[2], acc[r][3] + bv[3]);
    float4 o1 = make_float4(acc[r][4] + bv[4], acc[r][5] + bv[5],
                            acc[r][6] + bv[6], acc[r][7] + bv[7]);
    *(float4*)yp       = o0;
    *(float4*)(yp + 4) = o1;
    if (xpack) {                       // packed bf16 mirror (emb path)
      uint4 p;
      p.x = (unsigned)f2bf(o0.x) | ((unsigned)f2bf(o0.y) << 16);
      p.y = (unsigned)f2bf(o0.z) | ((unsigned)f2bf(o0.w) << 16);
      p.z = (unsigned)f2bf(o1.x) | ((unsigned)f2bf(o1.y) << 16);
      p.w = (unsigned)f2bf(o1.z) | ((unsigned)f2bf(o1.w) << 16);
      *(uint4*)&xpack[(size_t)gr * 64 + (col >> 1)] = p;
    }
  }
}

// ---------------------------------------------------------------------------
// CSR build, two-pass bucket sort (see round-2 notes: kills the random 8-B
// global scatter and csr_hist's 3.2M random atomics).
// Edge record in tmp: x = src | (local_dst << 17)  (17+9 = 26 bits), y = w.
// Final epak record: x = src << 8 (byte offset of the 256-B xbp row,
// pre-scaled so agg_pull's gather address is a single add), y = w.
// ---------------------------------------------------------------------------
__global__ __launch_bounds__(256) void csr_part1(
    const int* __restrict__ ei, const float* __restrict__ ew,
    int* __restrict__ bcnt,        // [NB*16] padded counters (one line each)
    int2* __restrict__ tmp)        // [NB*BSLOT]
{
  __shared__ int hist[NB];
  __shared__ int gbase[NB];
  const int tid = threadIdx.x;
  for (int i = tid; i < NB; i += 256) hist[i] = 0;
  __syncthreads();
  const int e0 = blockIdx.x * 2048 + tid * 8;   // 8 consecutive edges/thread
  const bool act = (e0 < N_EDGES);              // tail remainder is %8==0
  int4 s0, s1, d0, d1; float4 w0, w1;
  int rb[8];
  if (act) {
    s0 = *(const int4*)(ei + e0);
    s1 = *(const int4*)(ei + e0 + 4);
    d0 = *(const int4*)(ei + N_EDGES + e0);
    d1 = *(const int4*)(ei + N_EDGES + e0 + 4);
    w0 = *(const float4*)(ew + e0);
    w1 = *(const float4*)(ew + e0 + 4);
    int dv[8] = {d0.x, d0.y, d0.z, d0.w, d1.x, d1.y, d1.z, d1.w};
#pragma unroll
    for (int j = 0; j < 8; j++) {
      int b = dv[j] >> BSH;
      int r = atomicAdd(&hist[b], 1);
      rb[j] = (r << 8) | b;                     // rank<2048 (11b), b<196 (8b)
    }
  }
  __syncthreads();
  for (int i = tid; i < NB; i += 256) {
    int c = hist[i];
    gbase[i] = c ? atomicAdd(&bcnt[i * 16], c) : 0;  // one reserve per bucket
  }
  __syncthreads();
  if (act) {
    int sv[8] = {s0.x, s0.y, s0.z, s0.w, s1.x, s1.y, s1.z, s1.w};
    int dv[8] = {d0.x, d0.y, d0.z, d0.w, d1.x, d1.y, d1.z, d1.w};
    int wv[8] = {__float_as_int(w0.x), __float_as_int(w0.y),
                 __float_as_int(w0.z), __float_as_int(w0.w),
                 __float_as_int(w1.x), __float_as_int(w1.y),
                 __float_as_int(w1.z), __float_as_int(w1.w)};
#pragma unroll
    for (int j = 0; j < 8; j++) {
      int b  = rb[j] & 255;
      int of = gbase[b] + (rb[j] >> 8);
      if (of < BSLOT)                            // memory-safety guard only
        tmp[b * BSLOT + of] =
            make_int2(sv[j] | ((dv[j] & 511) << 17), wv[j]);
    }
  }
}

// exclusive scan of bucket counts -> bucket start offsets; rowptr[N] = E
__global__ void csr_scanb(const int* __restrict__ bcnt,
                          int* __restrict__ bstart, int* __restrict__ rowptr)
{
  __shared__ int l[256];
  int t = threadIdx.x;
  int v = (t < NB) ? min(bcnt[t * 16], BSLOT) : 0;
  l[t] = v;
  __syncthreads();
  for (int off = 1; off < 256; off <<= 1) {
    int u = (t >= off) ? l[t - off] : 0;
    __syncthreads();
    l[t] += u;
    __syncthreads();
  }
  if (t < NB) bstart[t] = l[t] - v;
  if (t == 255) rowptr[N_NODES] = l[255];
}

// per bucket: LDS node-hist -> LDS scan -> rowptr slice (coalesced) ->
// final in-bucket placement (reads+writes stay in ~130 KB, L2-resident).
__global__ __launch_bounds__(256) void csr_part2(
    const int2* __restrict__ tmp, const int* __restrict__ bcnt,
    const int* __restrict__ bstart, int* __restrict__ rowptr,
    int2* __restrict__ epak)
{
  __shared__ int cnt[512];
  __shared__ int lofs[512];
  __shared__ int s2[256];
  const int b      = blockIdx.x;
  const int tid    = threadIdx.x;
  const int nbase  = b << BSH;
  const int nn     = min(512, N_NODES - nbase);
  const int ecount = min(bcnt[b * 16], BSLOT);
  const long tbase = (long)b * BSLOT;
  const int obase  = bstart[b];
  for (int i = tid; i < 512; i += 256) cnt[i] = 0;
  __syncthreads();
  // pass A: per-node histogram of this bucket
  for (int e = tid; e < ecount; e += 256) {
    int2 rec = tmp[tbase + e];
    atomicAdd(&cnt[(rec.x >> 17) & 511], 1);
  }
  __syncthreads();
  // exclusive scan over 512 node counts (pairs + Hillis-Steele on 256)
  int c0 = cnt[2 * tid], c1 = cnt[2 * tid + 1];
  s2[tid] = c0 + c1;
  __syncthreads();
  int inc = s2[tid];
  for (int off = 1; off < 256; off <<= 1) {
    int u = (tid >= off) ? s2[tid - off] : 0;
    __syncthreads();
    s2[tid] += u;
    __syncthreads();
  }
  int ex = s2[tid] - inc;
  lofs[2 * tid]     = ex;
  lofs[2 * tid + 1] = ex + c0;
  __syncthreads();
  // rowptr slice, coalesced (replaces csr_hist + global scan entirely)
  for (int i = tid; i < nn; i += 256) rowptr[nbase + i] = obase + lofs[i];
  for (int i = tid; i < 512; i += 256) cnt[i] = 0;
  __syncthreads();
  // pass B: place edges at final CSR positions (within-row order arbitrary).
  // src is pre-scaled to its xbp byte offset (src*256) for agg_pull.
  for (int e = tid; e < ecount; e += 256) {
    int2 rec = tmp[tbase + e];
    int ldst = (rec.x >> 17) & 511;
    int r = atomicAdd(&cnt[ldst], 1);
    epak[obase + lofs[ldst] + r] = make_int2((rec.x & 0x1FFFF) << 8, rec.y);
  }
}

// ---------------------------------------------------------------------------
// Pull aggregation on bf16 x: z[n] = sum w_e * x[src_e], fp32 accumulate,
// bf16 packed output. One wave/node, lane covers cols {2*lane, 2*lane+1}.
// v3 (scalar path): node is readfirstlane-anchored -> rowptr/e/epak are
// wave-uniform, so the edge stream compiles to s_load (constant cache,
// SALU bookkeeping) and leaves the vector-memory pipe to the gathers.
// Gather address = s[row_base] + v[lane*4] (loop-invariant VGPR). Unroll 16
// doubles gathers in flight (~4 KB/wave outstanding).
// ---------------------------------------------------------------------------
__global__ __launch_bounds__(256) void agg_pull(
    const unsigned* __restrict__ xbp, const int* __restrict__ rowptr,
    const int2* __restrict__ epak, unsigned* __restrict__ zbp)
{
  const int node =
      __builtin_amdgcn_readfirstlane(blockIdx.x * 4 + (threadIdx.x >> 6));
  const int lane = threadIdx.x & 63;
  const unsigned lane4 = lane * 4;
  const char* xbc = (const char*)xbp;
  int e = rowptr[node];
  const int s1 = rowptr[node + 1];
  float v0 = 0.f, v1 = 0.f;
  // alignment pre-step: make e even so int4 loads on epak are 16-B aligned
  if ((e & 1) && e < s1) {
    int2 ep = epak[e++];
    unsigned p = *(const unsigned*)(xbc + (unsigned)ep.x + lane4);
    float w = __int_as_float(ep.y);
    v0 = fmaf(w, bflo(p), v0); v1 = fmaf(w, bfhi(p), v1);
  }
  const int n16 = e + ((s1 - e) & ~15);
  for (; e < n16; e += 16) {
    int4 q[8];
#pragma unroll
    for (int j = 0; j < 8; j++) q[j] = *(const int4*)(epak + e + 2 * j);
    unsigned p[16];
#pragma unroll
    for (int j = 0; j < 8; j++) {
      p[2 * j]     = *(const unsigned*)(xbc + (unsigned)q[j].x + lane4);
      p[2 * j + 1] = *(const unsigned*)(xbc + (unsigned)q[j].z + lane4);
    }
#pragma unroll
    for (int j = 0; j < 8; j++) {
      float wa = __int_as_float(q[j].y), wb = __int_as_float(q[j].w);
      v0 = fmaf(wa, bflo(p[2 * j]), v0);
      v1 = fmaf(wa, bfhi(p[2 * j]), v1);
      v0 = fmaf(wb, bflo(p[2 * j + 1]), v0);
      v1 = fmaf(wb, bfhi(p[2 * j + 1]), v1);
    }
  }
  const int n4 = e + ((s1 - e) & ~3);
  for (; e < n4; e += 4) {
    int4 qa = *(const int4*)(epak + e);
    int4 qb = *(const int4*)(epak + e + 2);
    unsigned p0 = *(const unsigned*)(xbc + (unsigned)qa.x + lane4);
    unsigned p1 = *(const unsigned*)(xbc + (unsigned)qa.z + lane4);
    unsigned p2 = *(const unsigned*)(xbc + (unsigned)qb.x + lane4);
    unsigned p3 = *(const unsigned*)(xbc + (unsigned)qb.z + lane4);
    float w0 = __int_as_float(qa.y), w1 = __int_as_float(qa.w);
    float w2 = __int_as_float(qb.y), w3 = __int_as_float(qb.w);
    v0 = fmaf(w0, bflo(p0), v0); v1 = fmaf(w0, bfhi(p0), v1);
    v0 = fmaf(w1, bflo(p1), v0); v1 = fmaf(w1, bfhi(p1), v1);
    v0 = fmaf(w2, bflo(p2), v0); v1 = fmaf(w2, bfhi(p2), v1);
    v0 = fmaf(w3, bflo(p3), v0); v1 = fmaf(w3, bfhi(p3), v1);
  }
  for (; e < s1; e++) {
    int2 ep = epak[e];
    unsigned p = *(const unsigned*)(xbc + (unsigned)ep.x + lane4);
    float w = __int_as_float(ep.y);
    v0 = fmaf(w, bflo(p), v0); v1 = fmaf(w, bfhi(p), v1);
  }
  zbp[(size_t)node * 64 + lane] =
      (unsigned)f2bf(v0) | ((unsigned)f2bf(v1) << 16);
}

// ---------------------------------------------------------------------------
// Fused GRU layer (bf16 MFMA), v3 partition: block = 32 rows (2 row-tiles),
// 4 waves each own 2 t-column-tiles for all 32 rows. Accumulators:
// 2rt x 2ti x 4 sets = 64 VGPR. launch_bounds(256,4) caps at 128 VGPR.
// 32 | 100000 exactly -> no row guards. Fast sigmoid/tanh (see helpers).
// ---------------------------------------------------------------------------
__global__ __launch_bounds__(256, 4) void gru_fused(
    const short* __restrict__ zb, short* __restrict__ xb,
    float* __restrict__ x,
    const short* __restrict__ Fb, const short* __restrict__ Wb,
    const float* __restrict__ bih, const float* __restrict__ bhh)
{
  const int wave = threadIdx.x >> 6, lane = threadIdx.x & 63;
  const int m  = lane & 15;
  const int g4 = lane >> 4;
  const int rowBase = blockIdx.x * 32;
  const int t0 = wave * 2;                 // this wave's t-pair (cols t0*16..)

  f32x4 aR[2][2], aZ[2][2], aN[2][2], aH[2][2];
#pragma unroll
  for (int rt = 0; rt < 2; rt++)
#pragma unroll
    for (int ti = 0; ti < 2; ti++) {
      aR[rt][ti] = (f32x4){0.f, 0.f, 0.f, 0.f};
      aZ[rt][ti] = (f32x4){0.f, 0.f, 0.f, 0.f};
      aN[rt][ti] = (f32x4){0.f, 0.f, 0.f, 0.f};
      aH[rt][ti] = (f32x4){0.f, 0.f, 0.f, 0.f};
    }

  size_t arowc[2];
#pragma unroll
  for (int rt = 0; rt < 2; rt++)
    arowc[rt] = (size_t)(rowBase + rt * 16 + m) * 128 + g4 * 8;

  // ---- phase 0: z @ F -> r,z,i_n ----
#pragma unroll
  for (int ks = 0; ks < 4; ks++) {
    bf16x8 a[2];
#pragma unroll
    for (int rt = 0; rt < 2; rt++)
      a[rt] = *(const bf16x8*)(zb + arowc[rt] + ks * 32);
    const int bo = ks * 512 + lane * 8;
#pragma unroll
    for (int ti = 0; ti < 2; ti++) {
      const short* bp = Fb + (t0 + ti) * 2048 + bo;
      bf16x8 br = *(const bf16x8*)(bp);
      bf16x8 bz = *(const bf16x8*)(bp + 16384);
      bf16x8 bn = *(const bf16x8*)(bp + 32768);
#pragma unroll
      for (int rt = 0; rt < 2; rt++) {
        aR[rt][ti] = __builtin_amdgcn_mfma_f32_16x16x32_bf16(a[rt], br, aR[rt][ti], 0, 0, 0);
        aZ[rt][ti] = __builtin_amdgcn_mfma_f32_16x16x32_bf16(a[rt], bz, aZ[rt][ti], 0, 0, 0);
        aN[rt][ti] = __builtin_amdgcn_mfma_f32_16x16x32_bf16(a[rt], bn, aN[rt][ti], 0, 0, 0);
      }
    }
  }
  // ---- phase 1: x @ Whh^T -> r,z,h_n ----
#pragma unroll
  for (int ks = 0; ks < 4; ks++) {
    bf16x8 a[2];
#pragma unroll
    for (int rt = 0; rt < 2; rt++)
      a[rt] = *(const bf16x8*)(xb + arowc[rt] + ks * 32);
    const int bo = ks * 512 + lane * 8;
#pragma unroll
    for (int ti = 0; ti < 2; ti++) {
      const short* bp = Wb + (t0 + ti) * 2048 + bo;
      bf16x8 br = *(const bf16x8*)(bp);
      bf16x8 bz = *(const bf16x8*)(bp + 16384);
      bf16x8 bn = *(const bf16x8*)(bp + 32768);
#pragma unroll
      for (int rt = 0; rt < 2; rt++) {
        aR[rt][ti] = __builtin_amdgcn_mfma_f32_16x16x32_bf16(a[rt], br, aR[rt][ti], 0, 0, 0);
        aZ[rt][ti] = __builtin_amdgcn_mfma_f32_16x16x32_bf16(a[rt], bz, aZ[rt][ti], 0, 0, 0);
        aH[rt][ti] = __builtin_amdgcn_mfma_f32_16x16x32_bf16(a[rt], bn, aH[rt][ti], 0, 0, 0);
      }
    }
  }

  // ---- epilogue: gates + state update (C/D: col=lane&15, row=g4*4+reg) ----
  // prefetch all 16 x_old values first so VMEM latency overlaps gate VALU
  float xo[2][2][4];
  size_t xoff[2][2];
#pragma unroll
  for (int ti = 0; ti < 2; ti++)
#pragma unroll
    for (int rt = 0; rt < 2; rt++) {
      size_t o = (size_t)(rowBase + rt * 16 + g4 * 4) * 128 + (t0 + ti) * 16 + m;
      xoff[ti][rt] = o;
#pragma unroll
      for (int r = 0; r < 4; r++) xo[ti][rt][r] = x[o + (size_t)r * 128];
    }
#pragma unroll
  for (int ti = 0; ti < 2; ti++) {
    int col = (t0 + ti) * 16 + m;
    float b_r = bih[col] + bhh[col];
    float b_z = bih[128 + col] + bhh[128 + col];
    float b_i = bih[256 + col];
    float b_h = bhh[256 + col];
#pragma unroll
    for (int rt = 0; rt < 2; rt++) {
#pragma unroll
      for (int r = 0; r < 4; r++) {
        float rg = fsigmoid(aR[rt][ti][r] + b_r);
        float zg = fsigmoid(aZ[rt][ti][r] + b_z);
        float ng = ftanh(aN[rt][ti][r] + b_i + rg * (aH[rt][ti][r] + b_h));
        float xn = (1.f - zg) * ng + zg * xo[ti][rt][r];
        size_t o = xoff[ti][rt] + (size_t)r * 128;
        x[o] = xn;
        xb[o] = (short)f2bf(xn);
      }
    }
  }
}

// ---------------------------------------------------------------------------
// BatchNorm stats (fp32 master x)
// ---------------------------------------------------------------------------
__global__ __launch_bounds__(256) void bn_stats(
    const float* __restrict__ x, float* __restrict__ sums)
{
  __shared__ float ls[256], lq[256];
  int tid  = threadIdx.x;
  int col  = tid & 127, half = tid >> 7;
  int r0   = blockIdx.x * 128;
  int rend = min(N_NODES, r0 + 128);
  float s = 0.f, q = 0.f;
  for (int r = r0 + half; r < rend; r += 2) {
    float v = x[(size_t)r * HDIM + col];
    s += v; q += v * v;
  }
  ls[tid] = s; lq[tid] = q;
  __syncthreads();
  if (tid < 128) {
    atomicAdd(&sums[col],       ls[tid] + ls[tid + 128]);
    atomicAdd(&sums[128 + col], lq[tid] + lq[tid + 128]);
  }
}

__global__ void bn_finalize(float* __restrict__ sums,
                            const float* __restrict__ gamma,
                            const float* __restrict__ beta)
{
  int j = threadIdx.x;
  float mean = sums[j] / (float)N_NODES;
  float var  = sums[128 + j] / (float)N_NODES - mean * mean;
  float inv  = rsqrtf(var + 1e-5f);
  sums[256 + j] = gamma[j] * inv;
  sums[384 + j] = beta[j] - mean * gamma[j] * inv;
}

// ---------------------------------------------------------------------------
// Fused head: out = bn(x) @ mlpW + h @ e2 + c2, BN folded into A-load of x.
// ---------------------------------------------------------------------------
__global__ __launch_bounds__(256) void head_fused(
    const float* __restrict__ x, const float* __restrict__ h,
    const float* __restrict__ sums,      // scale at [256..], shift at [384..]
    const float* __restrict__ mlpW,      // [128][40]
    const float* __restrict__ e2,        // [128][40]
    const float* __restrict__ c2,        // [40]
    float* __restrict__ out)             // [N][40]
{
  __shared__ alignas(16) float lds_a[32 * 68];
  __shared__ alignas(16) float lds_b[32 * 132];
  const int tid = threadIdx.x;
  const int tx = tid & 15;
  const int ty = tid >> 4;
  const int rowBase = blockIdx.x * 64;
  const int OUT = 40;

  float acc[4][8];
#pragma unroll
  for (int r = 0; r < 4; r++)
#pragma unroll
    for (int c = 0; c < 8; c++) acc[r][c] = 0.f;

  for (int src = 0; src < 2; src++) {
    const float* A = src ? h : x;
    const float* W = src ? e2 : mlpW;
    for (int k0 = 0; k0 < 128; k0 += 32) {
#pragma unroll
      for (int i = 0; i < 2; i++) {
        int idx = tid + i * 256;
        int r   = idx >> 3;
        int kk  = (idx & 7) << 2;
        int gr  = rowBase + r;
        float4 v = make_float4(0.f, 0.f, 0.f, 0.f);
        if (gr < N_NODES) v = *(const float4*)(A + (size_t)gr * HDIM + k0 + kk);
        if (src == 0) {   // fold BatchNorm apply into the x tile load
          float4 sc = *(const float4*)(sums + 256 + k0 + kk);
          float4 sh = *(const float4*)(sums + 384 + k0 + kk);
          v.x = fmaf(v.x, sc.x, sh.x);
          v.y = fmaf(v.y, sc.y, sh.y);
          v.z = fmaf(v.z, sc.z, sh.z);
          v.w = fmaf(v.w, sc.w, sh.w);
        }
        lds_a[(kk + 0) * 68 + r] = v.x;
        lds_a[(kk + 1) * 68 + r] = v.y;
        lds_a[(kk + 2) * 68 + r] = v.z;
        lds_a[(kk + 3) * 68 + r] = v.w;
      }
#pragma unroll
      for (int i = 0; i < 4; i++) {
        int idx = tid + i * 256;
        int kk  = idx >> 5;
        int j   = (idx & 31) << 2;
        float4 v = make_float4(0.f, 0.f, 0.f, 0.f);
        if (j < OUT) v = *(const float4*)(W + (size_t)(k0 + kk) * OUT + j);
        *((float4*)&lds_b[kk * 132 + j]) = v;
      }
      __syncthreads();
#pragma unroll 8
      for (int kk = 0; kk < 32; kk++) {
        float4 a4 = *(const float4*)&lds_a[kk * 68 + ty * 4];
        float4 b0 = *(const float4*)&lds_b[kk * 132 + tx * 8];
        float4 b1 = *(const float4*)&lds_b[kk * 132 + tx * 8 + 4];
        float av[4] = {a4.x, a4.y, a4.z, a4.w};
        float bv[8] = {b0.x, b0.y, b0.z, b0.w, b1.x, b1.y, b1.z, b1.w};
#pragma unroll
        for (int r = 0; r < 4; r++)
#pragma unroll
          for (int c = 0; c < 8; c++)
            acc[r][c] = fmaf(av[r], bv[c], acc[r][c]);
      }
      __syncthreads();
    }
  }

  int col = tx * 8;
  if (col >= OUT) return;            // tx 0..4 write (cols 0..39)
  float bv[8];
#pragma unroll
  for (int c = 0; c < 8; c++) bv[c] = c2[col + c];
#pragma unroll
  for (int r = 0; r < 4; r++) {
    int gr = rowBase + ty * 4 + r;
    if (gr >= N_NODES) continue;
    float* yp = out + (size_t)gr * OUT + col;
    float4 o0 = make_float4(acc[r][0] + bv[0], acc[r][1] + bv[1],
                            acc[r][2] + bv[2], acc[r][3] + bv[3]);
    float4 o1 = make_float4(acc[r][4] + bv[4], acc[r][5] + bv[5],
                            acc[r][6] + bv[6], acc[r][7] + bv[7]);
    *(float4*)yp       = o0;
    *(float4*)(yp + 4) = o1;
  }
}

// ---------------------------------------------------------------------------
// Residual fold constants: E2 = embW @ mlpW  [128][40], c2 = mlpB + embB@mlpW
// ---------------------------------------------------------------------------
__global__ void prep_e2(const float* __restrict__ embW,
                        const float* __restrict__ embB,
                        const float* __restrict__ mlpW,
                        const float* __restrict__ mlpB,
                        float* __restrict__ e2, float* __restrict__ c2)
{
  int tid = threadIdx.x;
#pragma unroll
  for (int t = 0; t < 20; t++) {
    int idx = tid * 20 + t;
    int f = idx / 40, j = idx - f * 40;
    float s = 0.f;
    for (int k = 0; k < 128; k++)
      s = fmaf(embW[f * 128 + k], mlpW[k * 40 + j], s);
    e2[idx] = s;
  }
  if (tid < 40) {
    float s = mlpB[tid];
    for (int k = 0; k < 128; k++)
      s = fmaf(embB[k], mlpW[k * 40 + tid], s);
    c2[tid] = s;
  }
}

// ---------------------------------------------------------------------------
extern "C" void kernel_launch(void* const* d_in, const int* in_sizes, int n_in,
                              void* d_out, int out_size, void* d_ws, size_t ws_size,
                              hipStream_t stream)
{
  const float* h     = (const float*)d_in[0];
  const int*   ei    = (const int*)d_in[1];
  const float* ew    = (const float*)d_in[2];
  const float* embW  = (const float*)d_in[3];
  const float* embB  = (const float*)d_in[4];
  const float* convW = (const float*)d_in[5];   // [3][128][128]
  const float* Wih   = (const float*)d_in[6];   // [384][128]
  const float* Whh   = (const float*)d_in[7];   // [384][128]
  const float* bih   = (const float*)d_in[8];
  const float* bhh   = (const float*)d_in[9];
  const float* gamma = (const float*)d_in[10];
  const float* beta  = (const float*)d_in[11];
  const float* mlpW  = (const float*)d_in[12];
  const float* mlpB  = (const float*)d_in[13];
  float* out = (float*)d_out;

  float* ws = (float*)d_ws;
  const size_t NH = (size_t)N_NODES * HDIM;      // 12.8M
  float*    x      = ws;                          // [N][128] fp32 master
  unsigned* xbp    = (unsigned*)(ws + NH);        // [N][64] packed bf16
  unsigned* zbp    = xbp + NH / 2;                // [N][64] packed bf16
  int2*     epak   = (int2*)(zbp + NH / 2);       // [E] {src_byteoff, w}
  int*      rowptr = (int*)(epak + N_EDGES);      // N+4
  int*      bcnt   = rowptr + N_NODES + 4;        // NB*16 padded counters
  int*      bstart = bcnt + NB * 16;              // NB (+pad)
  float*    Ffold  = (float*)(bstart + 256);      // [3][384][128] fp32
  short*    Fbp    = (short*)(Ffold + 3 * 384 * 128);  // frag-order bf16
  short*    Wbp    = Fbp + 3 * 384 * 128;         // frag-order bf16 of Whh
  float*    sums   = (float*)(Wbp + 384 * 128);
  float*    e2     = sums + 512;
  float*    c2     = e2 + 5120;
  // csr scratch: tmp [NB*BSLOT] int2 = 27.6 MB aliases xbp+zbp (both dead
  // until after the embedding GEMM / first agg_pull).
  int2*     tmp    = (int2*)xbp;

  dim3 blk(256);
  const int MB = (N_NODES + 63) / 64;
  const int GB = N_NODES / 32;                    // 3125, exact
  const int RB = (384 * 128 + 255) / 256;
  const int P1B = (N_EDGES + 2047) / 2048;        // 1563 (tail %8 == 0)

  // ---- constants ----
  prep_e2<<<1, 256, 0, stream>>>(embW, embB, mlpW, mlpB, e2, c2);
  for (int l = 0; l < 3; l++)
    gemm_k128<true><<<dim3(6, 1), blk, 0, stream>>>(
        Wih, convW + (size_t)l * HDIM * HDIM, nullptr,
        Ffold + (size_t)l * 384 * HDIM, nullptr, 384, 128);
  for (int l = 0; l < 3; l++)
    repack_frag_b<<<RB, blk, 0, stream>>>(
        Ffold + (size_t)l * 384 * HDIM, Fbp + (size_t)l * 384 * HDIM);
  repack_frag_b<<<RB, blk, 0, stream>>>(Whh, Wbp);

  // ---- CSR build: bucket partition -> per-bucket place (no global scatter)
  zero_i32<<<(NB * 16 + 255) / 256, blk, 0, stream>>>(bcnt, NB * 16);
  csr_part1<<<P1B, blk, 0, stream>>>(ei, ew, bcnt, tmp);
  csr_scanb<<<1, 256, 0, stream>>>(bcnt, bstart, rowptr);
  csr_part2<<<NB, blk, 0, stream>>>(tmp, bcnt, bstart, rowptr, epak);

  // ---- embedding: x = h @ embW + embB ; bf16 mirror fused in epilogue ----
  gemm_k128<false><<<dim3(MB, 1), blk, 0, stream>>>(h, embW, embB, x, xbp,
                                                    N_NODES, 128);

  // ---- 3 GRU layers: pull-agg (bf16) + fused MFMA GRU ----
  for (int l = 0; l < 3; l++) {
    agg_pull<<<N_NODES / 4, blk, 0, stream>>>(xbp, rowptr, epak, zbp);
    gru_fused<<<GB, blk, 0, stream>>>(
        (const short*)zbp, (short*)xbp, x,
        Fbp + (size_t)l * 384 * HDIM, Wbp, bih, bhh);
  }

  // ---- BatchNorm stats + fully fused head (BN apply + both GEMMs) ----
  zero_f32<<<2, blk, 0, stream>>>(sums, 512);
  bn_stats<<<(N_NODES + 127) / 128, blk, 0, stream>>>(x, sums);
  bn_finalize<<<1, 128, 0, stream>>>(sums, gamma, beta);
  head_fused<<<dim3(MB, 1), blk, 0, stream>>>(x, h, sums, mlpW, e2, c2, out);
}

// Round 7
// 988.059 us; speedup vs baseline: 1.6520x; 1.1111x over previous
//
#include <hip/hip_runtime.h>
#include <math.h>

#define N_NODES 100000
#define N_EDGES 3200000
#define HDIM 128

// ---- bucket sort CSR build ----
#define NB 196        // buckets of 512 consecutive dst nodes (100000/512 -> 196)
#define BSH 9         // 512 nodes per bucket
#define BSLOT 18432   // tmp slots per bucket (avg fill 16327, +16 sigma headroom)

typedef __attribute__((ext_vector_type(8))) short bf16x8;
typedef __attribute__((ext_vector_type(4))) float f32x4;

__device__ __forceinline__ unsigned short f2bf(float f) {
  union { float f; unsigned u; } v; v.f = f;
  unsigned r = v.u + 0x7fffu + ((v.u >> 16) & 1u);
  return (unsigned short)(r >> 16);
}
__device__ __forceinline__ float bflo(unsigned p) {
  union { unsigned u; float f; } v; v.u = p << 16; return v.f;
}
__device__ __forceinline__ float bfhi(unsigned p) {
  union { unsigned u; float f; } v; v.u = p & 0xffff0000u; return v.f;
}
// fast sigmoid/tanh: v_exp + v_rcp (approx err ~1e-6 << bf16 quantum 4e-3
// already present in the data path).
__device__ __forceinline__ float fsigmoid(float v) {
  return __builtin_amdgcn_rcpf(1.f + __expf(-v));
}
__device__ __forceinline__ float ftanh(float v) {
  return 1.f - 2.f * __builtin_amdgcn_rcpf(1.f + __expf(2.f * v));
}

// ---------------------------------------------------------------------------
__global__ __launch_bounds__(256) void zero_i32(int* __restrict__ p, int n) {
  int i = blockIdx.x * 256 + threadIdx.x;
  if (i < n) p[i] = 0;
}
__global__ __launch_bounds__(256) void zero_f32(float* __restrict__ p, int n) {
  int i = blockIdx.x * 256 + threadIdx.x;
  if (i < n) p[i] = 0.f;
}

// ---------------------------------------------------------------------------
// Repack a [384][128] fp32 weight matrix (row-major [col][k]) into
// MFMA-B-fragment-ordered bf16 (lane*16B contiguous per fragment).
// ---------------------------------------------------------------------------
__global__ __launch_bounds__(256) void repack_frag_b(
    const float* __restrict__ src, short* __restrict__ dst)
{
  int o = blockIdx.x * 256 + threadIdx.x;      // 0 .. 384*128-1
  if (o >= 384 * 128) return;
  int j    = o & 7;
  int lane = (o >> 3) & 63;
  int ks   = (o >> 9) & 3;
  int t    = o >> 11;
  int m  = lane & 15;
  int g4 = lane >> 4;
  dst[o] = (short)f2bf(src[(t * 16 + m) * 128 + ks * 32 + g4 * 8 + j]);
}

// ---------------------------------------------------------------------------
// Tiled fp32 GEMM, K fixed at 128 (emb, weight folds). Optional bf16-pack
// epilogue mirror (xpack != nullptr -> also emit packed bf16 rows).
// ---------------------------------------------------------------------------
template<bool BT>
__global__ __launch_bounds__(256) void gemm_k128(
    const float* __restrict__ A, const float* __restrict__ W,
    const float* __restrict__ bias, float* __restrict__ Y,
    unsigned* __restrict__ xpack, int M, int OUT)
{
  __shared__ alignas(16) float lds_a[32 * 68];
  __shared__ alignas(16) float lds_b[32 * 132];
  const int tid = threadIdx.x;
  const int tx = tid & 15;
  const int ty = tid >> 4;
  const int rowBase = blockIdx.x * 64;
  const int colBase = blockIdx.y * 128;

  float acc[4][8];
#pragma unroll
  for (int r = 0; r < 4; r++)
#pragma unroll
    for (int c = 0; c < 8; c++) acc[r][c] = 0.f;

  for (int k0 = 0; k0 < 128; k0 += 32) {
#pragma unroll
    for (int i = 0; i < 2; i++) {
      int idx = tid + i * 256;
      int r   = idx >> 3;
      int kk  = (idx & 7) << 2;
      int gr  = rowBase + r;
      float4 v = make_float4(0.f, 0.f, 0.f, 0.f);
      if (gr < M) v = *(const float4*)(A + (size_t)gr * HDIM + k0 + kk);
      lds_a[(kk + 0) * 68 + r] = v.x;
      lds_a[(kk + 1) * 68 + r] = v.y;
      lds_a[(kk + 2) * 68 + r] = v.z;
      lds_a[(kk + 3) * 68 + r] = v.w;
    }
    if (!BT) {
#pragma unroll
      for (int i = 0; i < 4; i++) {
        int idx = tid + i * 256;
        int kk  = idx >> 5;
        int j   = (idx & 31) << 2;
        int gj  = colBase + j;
        float4 v = make_float4(0.f, 0.f, 0.f, 0.f);
        if (gj < OUT) v = *(const float4*)(W + (size_t)(k0 + kk) * OUT + gj);
        *((float4*)&lds_b[kk * 132 + j]) = v;
      }
    } else {
#pragma unroll
      for (int i = 0; i < 4; i++) {
        int idx = tid + i * 256;
        int j   = idx >> 3;
        int k4  = (idx & 7) << 2;
        int gj  = colBase + j;
        float4 v = make_float4(0.f, 0.f, 0.f, 0.f);
        if (gj < OUT) v = *(const float4*)(W + (size_t)gj * HDIM + k0 + k4);
        lds_b[(k4 + 0) * 132 + j] = v.x;
        lds_b[(k4 + 1) * 132 + j] = v.y;
        lds_b[(k4 + 2) * 132 + j] = v.z;
        lds_b[(k4 + 3) * 132 + j] = v.w;
      }
    }
    __syncthreads();
#pragma unroll 8
    for (int kk = 0; kk < 32; kk++) {
      float4 a4 = *(const float4*)&lds_a[kk * 68 + ty * 4];
      float4 b0 = *(const float4*)&lds_b[kk * 132 + tx * 8];
      float4 b1 = *(const float4*)&lds_b[kk * 132 + tx * 8 + 4];
      float av[4] = {a4.x, a4.y, a4.z, a4.w};
      float bv[8] = {b0.x, b0.y, b0.z, b0.w, b1.x, b1.y, b1.z, b1.w};
#pragma unroll
      for (int r = 0; r < 4; r++)
#pragma unroll
        for (int c = 0; c < 8; c++)
          acc[r][c] = fmaf(av[r], bv[c], acc[r][c]);
    }
    __syncthreads();
  }

  int col = colBase + tx * 8;
  if (col >= OUT) return;
  float bv[8];
#pragma unroll
  for (int c = 0; c < 8; c++) bv[c] = bias ? bias[col + c] : 0.f;
#pragma unroll
  for (int r = 0; r < 4; r++) {
    int gr = rowBase + ty * 4 + r;
    if (gr >= M) continue;
    float* yp = Y + (size_t)gr * OUT + col;
    float4 o0 = make_float4(acc[r][0] + bv[0], acc[r][1] + bv[1],
                            acc[r][2] + bv[2], acc[r][3] + bv[3]);
    float4 o1 = make_float4(acc[r][4] + bv[4], acc[r][5] + bv[5],
                            acc[r][6] + bv[6], acc[r][7] + bv[7]);
    *(float4*)yp       = o0;
    *(float4*)(yp + 4) = o1;
    if (xpack) {                       // packed bf16 mirror (emb path)
      uint4 p;
      p.x = (unsigned)f2bf(o0.x) | ((unsigned)f2bf(o0.y) << 16);
      p.y = (unsigned)f2bf(o0.z) | ((unsigned)f2bf(o0.w) << 16);
      p.z = (unsigned)f2bf(o1.x) | ((unsigned)f2bf(o1.y) << 16);
      p.w = (unsigned)f2bf(o1.z) | ((unsigned)f2bf(o1.w) << 16);
      *(uint4*)&xpack[(size_t)gr * 64 + (col >> 1)] = p;
    }
  }
}

// ---------------------------------------------------------------------------
// CSR build, two-pass bucket sort (see round-2 notes: kills the random 8-B
// global scatter and csr_hist's 3.2M random atomics).
// Edge record in tmp: x = src | (local_dst << 17)  (17+9 = 26 bits), y = w.
// Final epak record: x = src << 8 (byte offset of the 256-B xbp row,
// pre-scaled so agg_pull's gather address is a single add), y = w.
// ---------------------------------------------------------------------------
__global__ __launch_bounds__(256) void csr_part1(
    const int* __restrict__ ei, const float* __restrict__ ew,
    int* __restrict__ bcnt,        // [NB*16] padded counters (one line each)
    int2* __restrict__ tmp)        // [NB*BSLOT]
{
  __shared__ int hist[NB];
  __shared__ int gbase[NB];
  const int tid = threadIdx.x;
  for (int i = tid; i < NB; i += 256) hist[i] = 0;
  __syncthreads();
  const int e0 = blockIdx.x * 2048 + tid * 8;   // 8 consecutive edges/thread
  const bool act = (e0 < N_EDGES);              // tail remainder is %8==0
  int4 s0, s1, d0, d1; float4 w0, w1;
  int rb[8];
  if (act) {
    s0 = *(const int4*)(ei + e0);
    s1 = *(const int4*)(ei + e0 + 4);
    d0 = *(const int4*)(ei + N_EDGES + e0);
    d1 = *(const int4*)(ei + N_EDGES + e0 + 4);
    w0 = *(const float4*)(ew + e0);
    w1 = *(const float4*)(ew + e0 + 4);
    int dv[8] = {d0.x, d0.y, d0.z, d0.w, d1.x, d1.y, d1.z, d1.w};
#pragma unroll
    for (int j = 0; j < 8; j++) {
      int b = dv[j] >> BSH;
      int r = atomicAdd(&hist[b], 1);
      rb[j] = (r << 8) | b;                     // rank<2048 (11b), b<196 (8b)
    }
  }
  __syncthreads();
  for (int i = tid; i < NB; i += 256) {
    int c = hist[i];
    gbase[i] = c ? atomicAdd(&bcnt[i * 16], c) : 0;  // one reserve per bucket
  }
  __syncthreads();
  if (act) {
    int sv[8] = {s0.x, s0.y, s0.z, s0.w, s1.x, s1.y, s1.z, s1.w};
    int dv[8] = {d0.x, d0.y, d0.z, d0.w, d1.x, d1.y, d1.z, d1.w};
    int wv[8] = {__float_as_int(w0.x), __float_as_int(w0.y),
                 __float_as_int(w0.z), __float_as_int(w0.w),
                 __float_as_int(w1.x), __float_as_int(w1.y),
                 __float_as_int(w1.z), __float_as_int(w1.w)};
#pragma unroll
    for (int j = 0; j < 8; j++) {
      int b  = rb[j] & 255;
      int of = gbase[b] + (rb[j] >> 8);
      if (of < BSLOT)                            // memory-safety guard only
        tmp[b * BSLOT + of] =
            make_int2(sv[j] | ((dv[j] & 511) << 17), wv[j]);
    }
  }
}

// exclusive scan of bucket counts -> bucket start offsets; rowptr[N] = E
__global__ void csr_scanb(const int* __restrict__ bcnt,
                          int* __restrict__ bstart, int* __restrict__ rowptr)
{
  __shared__ int l[256];
  int t = threadIdx.x;
  int v = (t < NB) ? min(bcnt[t * 16], BSLOT) : 0;
  l[t] = v;
  __syncthreads();
  for (int off = 1; off < 256; off <<= 1) {
    int u = (t >= off) ? l[t - off] : 0;
    __syncthreads();
    l[t] += u;
    __syncthreads();
  }
  if (t < NB) bstart[t] = l[t] - v;
  if (t == 255) rowptr[N_NODES] = l[255];
}

// per bucket: LDS node-hist -> LDS scan -> rowptr slice (coalesced) ->
// final in-bucket placement (reads+writes stay in ~130 KB, L2-resident).
__global__ __launch_bounds__(256) void csr_part2(
    const int2* __restrict__ tmp, const int* __restrict__ bcnt,
    const int* __restrict__ bstart, int* __restrict__ rowptr,
    int2* __restrict__ epak)
{
  __shared__ int cnt[512];
  __shared__ int lofs[512];
  __shared__ int s2[256];
  const int b      = blockIdx.x;
  const int tid    = threadIdx.x;
  const int nbase  = b << BSH;
  const int nn     = min(512, N_NODES - nbase);
  const int ecount = min(bcnt[b * 16], BSLOT);
  const long tbase = (long)b * BSLOT;
  const int obase  = bstart[b];
  for (int i = tid; i < 512; i += 256) cnt[i] = 0;
  __syncthreads();
  // pass A: per-node histogram of this bucket
  for (int e = tid; e < ecount; e += 256) {
    int2 rec = tmp[tbase + e];
    atomicAdd(&cnt[(rec.x >> 17) & 511], 1);
  }
  __syncthreads();
  // exclusive scan over 512 node counts (pairs + Hillis-Steele on 256)
  int c0 = cnt[2 * tid], c1 = cnt[2 * tid + 1];
  s2[tid] = c0 + c1;
  __syncthreads();
  int inc = s2[tid];
  for (int off = 1; off < 256; off <<= 1) {
    int u = (tid >= off) ? s2[tid - off] : 0;
    __syncthreads();
    s2[tid] += u;
    __syncthreads();
  }
  int ex = s2[tid] - inc;
  lofs[2 * tid]     = ex;
  lofs[2 * tid + 1] = ex + c0;
  __syncthreads();
  // rowptr slice, coalesced (replaces csr_hist + global scan entirely)
  for (int i = tid; i < nn; i += 256) rowptr[nbase + i] = obase + lofs[i];
  for (int i = tid; i < 512; i += 256) cnt[i] = 0;
  __syncthreads();
  // pass B: place edges at final CSR positions (within-row order arbitrary).
  // src is pre-scaled to its xbp byte offset (src*256) for agg_pull.
  for (int e = tid; e < ecount; e += 256) {
    int2 rec = tmp[tbase + e];
    int ldst = (rec.x >> 17) & 511;
    int r = atomicAdd(&cnt[ldst], 1);
    epak[obase + lofs[ldst] + r] = make_int2((rec.x & 0x1FFFF) << 8, rec.y);
  }
}

// ---------------------------------------------------------------------------
// Pull aggregation on bf16 x: z[n] = sum w_e * x[src_e], fp32 accumulate,
// bf16 packed output. One wave/node, lane covers cols {2*lane, 2*lane+1}.
// v3 (scalar path): node is readfirstlane-anchored -> rowptr/e/epak are
// wave-uniform, so the edge stream compiles to s_load (constant cache,
// SALU bookkeeping) and leaves the vector-memory pipe to the gathers.
// ---------------------------------------------------------------------------
__global__ __launch_bounds__(256) void agg_pull(
    const unsigned* __restrict__ xbp, const int* __restrict__ rowptr,
    const int2* __restrict__ epak, unsigned* __restrict__ zbp)
{
  const int node =
      __builtin_amdgcn_readfirstlane(blockIdx.x * 4 + (threadIdx.x >> 6));
  const int lane = threadIdx.x & 63;
  const unsigned lane4 = lane * 4;
  const char* xbc = (const char*)xbp;
  int e = rowptr[node];
  const int s1 = rowptr[node + 1];
  float v0 = 0.f, v1 = 0.f;
  // alignment pre-step: make e even so int4 loads on epak are 16-B aligned
  if ((e & 1) && e < s1) {
    int2 ep = epak[e++];
    unsigned p = *(const unsigned*)(xbc + (unsigned)ep.x + lane4);
    float w = __int_as_float(ep.y);
    v0 = fmaf(w, bflo(p), v0); v1 = fmaf(w, bfhi(p), v1);
  }
  const int n16 = e + ((s1 - e) & ~15);
  for (; e < n16; e += 16) {
    int4 q[8];
#pragma unroll
    for (int j = 0; j < 8; j++) q[j] = *(const int4*)(epak + e + 2 * j);
    unsigned p[16];
#pragma unroll
    for (int j = 0; j < 8; j++) {
      p[2 * j]     = *(const unsigned*)(xbc + (unsigned)q[j].x + lane4);
      p[2 * j + 1] = *(const unsigned*)(xbc + (unsigned)q[j].z + lane4);
    }
#pragma unroll
    for (int j = 0; j < 8; j++) {
      float wa = __int_as_float(q[j].y), wb = __int_as_float(q[j].w);
      v0 = fmaf(wa, bflo(p[2 * j]), v0);
      v1 = fmaf(wa, bfhi(p[2 * j]), v1);
      v0 = fmaf(wb, bflo(p[2 * j + 1]), v0);
      v1 = fmaf(wb, bfhi(p[2 * j + 1]), v1);
    }
  }
  const int n4 = e + ((s1 - e) & ~3);
  for (; e < n4; e += 4) {
    int4 qa = *(const int4*)(epak + e);
    int4 qb = *(const int4*)(epak + e + 2);
    unsigned p0 = *(const unsigned*)(xbc + (unsigned)qa.x + lane4);
    unsigned p1 = *(const unsigned*)(xbc + (unsigned)qa.z + lane4);
    unsigned p2 = *(const unsigned*)(xbc + (unsigned)qb.x + lane4);
    unsigned p3 = *(const unsigned*)(xbc + (unsigned)qb.z + lane4);
    float w0 = __int_as_float(qa.y), w1 = __int_as_float(qa.w);
    float w2 = __int_as_float(qb.y), w3 = __int_as_float(qb.w);
    v0 = fmaf(w0, bflo(p0), v0); v1 = fmaf(w0, bfhi(p0), v1);
    v0 = fmaf(w1, bflo(p1), v0); v1 = fmaf(w1, bfhi(p1), v1);
    v0 = fmaf(w2, bflo(p2), v0); v1 = fmaf(w2, bfhi(p2), v1);
    v0 = fmaf(w3, bflo(p3), v0); v1 = fmaf(w3, bfhi(p3), v1);
  }
  for (; e < s1; e++) {
    int2 ep = epak[e];
    unsigned p = *(const unsigned*)(xbc + (unsigned)ep.x + lane4);
    float w = __int_as_float(ep.y);
    v0 = fmaf(w, bflo(p), v0); v1 = fmaf(w, bfhi(p), v1);
  }
  zbp[(size_t)node * 64 + lane] =
      (unsigned)f2bf(v0) | ((unsigned)f2bf(v1) << 16);
}

// ---------------------------------------------------------------------------
// Fused GRU layer (bf16 MFMA), v3 partition: block = 32 rows (2 row-tiles),
// 4 waves each own 2 t-column-tiles for all 32 rows. Accumulators:
// 2rt x 2ti x 4 sets = 64 VGPR. launch_bounds(256,4) caps at 128 VGPR.
// 32 | 100000 exactly -> no row guards. Fast sigmoid/tanh (see helpers).
// ---------------------------------------------------------------------------
__global__ __launch_bounds__(256, 4) void gru_fused(
    const short* __restrict__ zb, short* __restrict__ xb,
    float* __restrict__ x,
    const short* __restrict__ Fb, const short* __restrict__ Wb,
    const float* __restrict__ bih, const float* __restrict__ bhh)
{
  const int wave = threadIdx.x >> 6, lane = threadIdx.x & 63;
  const int m  = lane & 15;
  const int g4 = lane >> 4;
  const int rowBase = blockIdx.x * 32;
  const int t0 = wave * 2;                 // this wave's t-pair (cols t0*16..)

  f32x4 aR[2][2], aZ[2][2], aN[2][2], aH[2][2];
#pragma unroll
  for (int rt = 0; rt < 2; rt++)
#pragma unroll
    for (int ti = 0; ti < 2; ti++) {
      aR[rt][ti] = (f32x4){0.f, 0.f, 0.f, 0.f};
      aZ[rt][ti] = (f32x4){0.f, 0.f, 0.f, 0.f};
      aN[rt][ti] = (f32x4){0.f, 0.f, 0.f, 0.f};
      aH[rt][ti] = (f32x4){0.f, 0.f, 0.f, 0.f};
    }

  size_t arowc[2];
#pragma unroll
  for (int rt = 0; rt < 2; rt++)
    arowc[rt] = (size_t)(rowBase + rt * 16 + m) * 128 + g4 * 8;

  // ---- phase 0: z @ F -> r,z,i_n ----
#pragma unroll
  for (int ks = 0; ks < 4; ks++) {
    bf16x8 a[2];
#pragma unroll
    for (int rt = 0; rt < 2; rt++)
      a[rt] = *(const bf16x8*)(zb + arowc[rt] + ks * 32);
    const int bo = ks * 512 + lane * 8;
#pragma unroll
    for (int ti = 0; ti < 2; ti++) {
      const short* bp = Fb + (t0 + ti) * 2048 + bo;
      bf16x8 br = *(const bf16x8*)(bp);
      bf16x8 bz = *(const bf16x8*)(bp + 16384);
      bf16x8 bn = *(const bf16x8*)(bp + 32768);
#pragma unroll
      for (int rt = 0; rt < 2; rt++) {
        aR[rt][ti] = __builtin_amdgcn_mfma_f32_16x16x32_bf16(a[rt], br, aR[rt][ti], 0, 0, 0);
        aZ[rt][ti] = __builtin_amdgcn_mfma_f32_16x16x32_bf16(a[rt], bz, aZ[rt][ti], 0, 0, 0);
        aN[rt][ti] = __builtin_amdgcn_mfma_f32_16x16x32_bf16(a[rt], bn, aN[rt][ti], 0, 0, 0);
      }
    }
  }
  // ---- phase 1: x @ Whh^T -> r,z,h_n ----
#pragma unroll
  for (int ks = 0; ks < 4; ks++) {
    bf16x8 a[2];
#pragma unroll
    for (int rt = 0; rt < 2; rt++)
      a[rt] = *(const bf16x8*)(xb + arowc[rt] + ks * 32);
    const int bo = ks * 512 + lane * 8;
#pragma unroll
    for (int ti = 0; ti < 2; ti++) {
      const short* bp = Wb + (t0 + ti) * 2048 + bo;
      bf16x8 br = *(const bf16x8*)(bp);
      bf16x8 bz = *(const bf16x8*)(bp + 16384);
      bf16x8 bn = *(const bf16x8*)(bp + 32768);
#pragma unroll
      for (int rt = 0; rt < 2; rt++) {
        aR[rt][ti] = __builtin_amdgcn_mfma_f32_16x16x32_bf16(a[rt], br, aR[rt][ti], 0, 0, 0);
        aZ[rt][ti] = __builtin_amdgcn_mfma_f32_16x16x32_bf16(a[rt], bz, aZ[rt][ti], 0, 0, 0);
        aH[rt][ti] = __builtin_amdgcn_mfma_f32_16x16x32_bf16(a[rt], bn, aH[rt][ti], 0, 0, 0);
      }
    }
  }

  // ---- epilogue: gates + state update (C/D: col=lane&15, row=g4*4+reg) ----
  // prefetch all 16 x_old values first so VMEM latency overlaps gate VALU
  float xo[2][2][4];
  size_t xoff[2][2];
#pragma unroll
  for (int ti = 0; ti < 2; ti++)
#pragma unroll
    for (int rt = 0; rt < 2; rt++) {
      size_t o = (size_t)(rowBase + rt * 16 + g4 * 4) * 128 + (t0 + ti) * 16 + m;
      xoff[ti][rt] = o;
#pragma unroll
      for (int r = 0; r < 4; r++) xo[ti][rt][r] = x[o + (size_t)r * 128];
    }
#pragma unroll
  for (int ti = 0; ti < 2; ti++) {
    int col = (t0 + ti) * 16 + m;
    float b_r = bih[col] + bhh[col];
    float b_z = bih[128 + col] + bhh[128 + col];
    float b_i = bih[256 + col];
    float b_h = bhh[256 + col];
#pragma unroll
    for (int rt = 0; rt < 2; rt++) {
#pragma unroll
      for (int r = 0; r < 4; r++) {
        float rg = fsigmoid(aR[rt][ti][r] + b_r);
        float zg = fsigmoid(aZ[rt][ti][r] + b_z);
        float ng = ftanh(aN[rt][ti][r] + b_i + rg * (aH[rt][ti][r] + b_h));
        float xn = (1.f - zg) * ng + zg * xo[ti][rt][r];
        size_t o = xoff[ti][rt] + (size_t)r * 128;
        x[o] = xn;
        xb[o] = (short)f2bf(xn);
      }
    }
  }
}

// ---------------------------------------------------------------------------
// BatchNorm stats (fp32 master x)
// ---------------------------------------------------------------------------
__global__ __launch_bounds__(256) void bn_stats(
    const float* __restrict__ x, float* __restrict__ sums)
{
  __shared__ float ls[256], lq[256];
  int tid  = threadIdx.x;
  int col  = tid & 127, half = tid >> 7;
  int r0   = blockIdx.x * 128;
  int rend = min(N_NODES, r0 + 128);
  float s = 0.f, q = 0.f;
  for (int r = r0 + half; r < rend; r += 2) {
    float v = x[(size_t)r * HDIM + col];
    s += v; q += v * v;
  }
  ls[tid] = s; lq[tid] = q;
  __syncthreads();
  if (tid < 128) {
    atomicAdd(&sums[col],       ls[tid] + ls[tid + 128]);
    atomicAdd(&sums[128 + col], lq[tid] + lq[tid + 128]);
  }
}

__global__ void bn_finalize(float* __restrict__ sums,
                            const float* __restrict__ gamma,
                            const float* __restrict__ beta)
{
  int j = threadIdx.x;
  float mean = sums[j] / (float)N_NODES;
  float var  = sums[128 + j] / (float)N_NODES - mean * mean;
  float inv  = rsqrtf(var + 1e-5f);
  sums[256 + j] = gamma[j] * inv;
  sums[384 + j] = beta[j] - mean * gamma[j] * inv;
}

// ---------------------------------------------------------------------------
// Fused head: out = bn(x) @ mlpW + h @ e2 + c2, BN folded into A-load of x.
// ---------------------------------------------------------------------------
__global__ __launch_bounds__(256) void head_fused(
    const float* __restrict__ x, const float* __restrict__ h,
    const float* __restrict__ sums,      // scale at [256..], shift at [384..]
    const float* __restrict__ mlpW,      // [128][40]
    const float* __restrict__ e2,        // [128][40]
    const float* __restrict__ c2,        // [40]
    float* __restrict__ out)             // [N][40]
{
  __shared__ alignas(16) float lds_a[32 * 68];
  __shared__ alignas(16) float lds_b[32 * 132];
  const int tid = threadIdx.x;
  const int tx = tid & 15;
  const int ty = tid >> 4;
  const int rowBase = blockIdx.x * 64;
  const int OUT = 40;

  float acc[4][8];
#pragma unroll
  for (int r = 0; r < 4; r++)
#pragma unroll
    for (int c = 0; c < 8; c++) acc[r][c] = 0.f;

  for (int src = 0; src < 2; src++) {
    const float* A = src ? h : x;
    const float* W = src ? e2 : mlpW;
    for (int k0 = 0; k0 < 128; k0 += 32) {
#pragma unroll
      for (int i = 0; i < 2; i++) {
        int idx = tid + i * 256;
        int r   = idx >> 3;
        int kk  = (idx & 7) << 2;
        int gr  = rowBase + r;
        float4 v = make_float4(0.f, 0.f, 0.f, 0.f);
        if (gr < N_NODES) v = *(const float4*)(A + (size_t)gr * HDIM + k0 + kk);
        if (src == 0) {   // fold BatchNorm apply into the x tile load
          float4 sc = *(const float4*)(sums + 256 + k0 + kk);
          float4 sh = *(const float4*)(sums + 384 + k0 + kk);
          v.x = fmaf(v.x, sc.x, sh.x);
          v.y = fmaf(v.y, sc.y, sh.y);
          v.z = fmaf(v.z, sc.z, sh.z);
          v.w = fmaf(v.w, sc.w, sh.w);
        }
        lds_a[(kk + 0) * 68 + r] = v.x;
        lds_a[(kk + 1) * 68 + r] = v.y;
        lds_a[(kk + 2) * 68 + r] = v.z;
        lds_a[(kk + 3) * 68 + r] = v.w;
      }
#pragma unroll
      for (int i = 0; i < 4; i++) {
        int idx = tid + i * 256;
        int kk  = idx >> 5;
        int j   = (idx & 31) << 2;
        float4 v = make_float4(0.f, 0.f, 0.f, 0.f);
        if (j < OUT) v = *(const float4*)(W + (size_t)(k0 + kk) * OUT + j);
        *((float4*)&lds_b[kk * 132 + j]) = v;
      }
      __syncthreads();
#pragma unroll 8
      for (int kk = 0; kk < 32; kk++) {
        float4 a4 = *(const float4*)&lds_a[kk * 68 + ty * 4];
        float4 b0 = *(const float4*)&lds_b[kk * 132 + tx * 8];
        float4 b1 = *(const float4*)&lds_b[kk * 132 + tx * 8 + 4];
        float av[4] = {a4.x, a4.y, a4.z, a4.w};
        float bv[8] = {b0.x, b0.y, b0.z, b0.w, b1.x, b1.y, b1.z, b1.w};
#pragma unroll
        for (int r = 0; r < 4; r++)
#pragma unroll
          for (int c = 0; c < 8; c++)
            acc[r][c] = fmaf(av[r], bv[c], acc[r][c]);
      }
      __syncthreads();
    }
  }

  int col = tx * 8;
  if (col >= OUT) return;            // tx 0..4 write (cols 0..39)
  float bv[8];
#pragma unroll
  for (int c = 0; c < 8; c++) bv[c] = c2[col + c];
#pragma unroll
  for (int r = 0; r < 4; r++) {
    int gr = rowBase + ty * 4 + r;
    if (gr >= N_NODES) continue;
    float* yp = out + (size_t)gr * OUT + col;
    float4 o0 = make_float4(acc[r][0] + bv[0], acc[r][1] + bv[1],
                            acc[r][2] + bv[2], acc[r][3] + bv[3]);
    float4 o1 = make_float4(acc[r][4] + bv[4], acc[r][5] + bv[5],
                            acc[r][6] + bv[6], acc[r][7] + bv[7]);
    *(float4*)yp       = o0;
    *(float4*)(yp + 4) = o1;
  }
}

// ---------------------------------------------------------------------------
// Residual fold constants: E2 = embW @ mlpW  [128][40], c2 = mlpB + embB@mlpW
// v2: one output per thread (was: 1 block, 20 serial dot products/thread ->
// 113 us latency-bound on a single CU). 21 blocks x 256 thr, data L2-hot.
// Same fmaf chain order per output -> bit-identical to v1.
// ---------------------------------------------------------------------------
__global__ __launch_bounds__(256) void prep_e2(
    const float* __restrict__ embW,
    const float* __restrict__ embB,
    const float* __restrict__ mlpW,
    const float* __restrict__ mlpB,
    float* __restrict__ e2, float* __restrict__ c2)
{
  int idx = blockIdx.x * 256 + threadIdx.x;
  if (idx < 5120) {
    int f = idx / 40, j = idx - f * 40;
    const float* er = embW + f * 128;
    float s = 0.f;
    for (int k = 0; k < 128; k++)
      s = fmaf(er[k], mlpW[k * 40 + j], s);
    e2[idx] = s;
  } else if (idx < 5160) {
    int j = idx - 5120;
    float s = mlpB[j];
    for (int k = 0; k < 128; k++)
      s = fmaf(embB[k], mlpW[k * 40 + j], s);
    c2[j] = s;
  }
}

// ---------------------------------------------------------------------------
extern "C" void kernel_launch(void* const* d_in, const int* in_sizes, int n_in,
                              void* d_out, int out_size, void* d_ws, size_t ws_size,
                              hipStream_t stream)
{
  const float* h     = (const float*)d_in[0];
  const int*   ei    = (const int*)d_in[1];
  const float* ew    = (const float*)d_in[2];
  const float* embW  = (const float*)d_in[3];
  const float* embB  = (const float*)d_in[4];
  const float* convW = (const float*)d_in[5];   // [3][128][128]
  const float* Wih   = (const float*)d_in[6];   // [384][128]
  const float* Whh   = (const float*)d_in[7];   // [384][128]
  const float* bih   = (const float*)d_in[8];
  const float* bhh   = (const float*)d_in[9];
  const float* gamma = (const float*)d_in[10];
  const float* beta  = (const float*)d_in[11];
  const float* mlpW  = (const float*)d_in[12];
  const float* mlpB  = (const float*)d_in[13];
  float* out = (float*)d_out;

  float* ws = (float*)d_ws;
  const size_t NH = (size_t)N_NODES * HDIM;      // 12.8M
  float*    x      = ws;                          // [N][128] fp32 master
  unsigned* xbp    = (unsigned*)(ws + NH);        // [N][64] packed bf16
  unsigned* zbp    = xbp + NH / 2;                // [N][64] packed bf16
  int2*     epak   = (int2*)(zbp + NH / 2);       // [E] {src_byteoff, w}
  int*      rowptr = (int*)(epak + N_EDGES);      // N+4
  int*      bcnt   = rowptr + N_NODES + 4;        // NB*16 padded counters
  int*      bstart = bcnt + NB * 16;              // NB (+pad)
  float*    Ffold  = (float*)(bstart + 256);      // [3][384][128] fp32
  short*    Fbp    = (short*)(Ffold + 3 * 384 * 128);  // frag-order bf16
  short*    Wbp    = Fbp + 3 * 384 * 128;         // frag-order bf16 of Whh
  float*    sums   = (float*)(Wbp + 384 * 128);
  float*    e2     = sums + 512;
  float*    c2     = e2 + 5120;
  // csr scratch: tmp [NB*BSLOT] int2 = 27.6 MB aliases xbp+zbp (both dead
  // until after the embedding GEMM / first agg_pull).
  int2*     tmp    = (int2*)xbp;

  dim3 blk(256);
  const int MB = (N_NODES + 63) / 64;
  const int GB = N_NODES / 32;                    // 3125, exact
  const int RB = (384 * 128 + 255) / 256;
  const int P1B = (N_EDGES + 2047) / 2048;        // 1563 (tail %8 == 0)

  // ---- constants ----
  prep_e2<<<21, blk, 0, stream>>>(embW, embB, mlpW, mlpB, e2, c2);
  for (int l = 0; l < 3; l++)
    gemm_k128<true><<<dim3(6, 1), blk, 0, stream>>>(
        Wih, convW + (size_t)l * HDIM * HDIM, nullptr,
        Ffold + (size_t)l * 384 * HDIM, nullptr, 384, 128);
  for (int l = 0; l < 3; l++)
    repack_frag_b<<<RB, blk, 0, stream>>>(
        Ffold + (size_t)l * 384 * HDIM, Fbp + (size_t)l * 384 * HDIM);
  repack_frag_b<<<RB, blk, 0, stream>>>(Whh, Wbp);

  // ---- CSR build: bucket partition -> per-bucket place (no global scatter)
  zero_i32<<<(NB * 16 + 255) / 256, blk, 0, stream>>>(bcnt, NB * 16);
  csr_part1<<<P1B, blk, 0, stream>>>(ei, ew, bcnt, tmp);
  csr_scanb<<<1, 256, 0, stream>>>(bcnt, bstart, rowptr);
  csr_part2<<<NB, blk, 0, stream>>>(tmp, bcnt, bstart, rowptr, epak);

  // ---- embedding: x = h @ embW + embB ; bf16 mirror fused in epilogue ----
  gemm_k128<false><<<dim3(MB, 1), blk, 0, stream>>>(h, embW, embB, x, xbp,
                                                    N_NODES, 128);

  // ---- 3 GRU layers: pull-agg (bf16) + fused MFMA GRU ----
  for (int l = 0; l < 3; l++) {
    agg_pull<<<N_NODES / 4, blk, 0, stream>>>(xbp, rowptr, epak, zbp);
    gru_fused<<<GB, blk, 0, stream>>>(
        (const short*)zbp, (short*)xbp, x,
        Fbp + (size_t)l * 384 * HDIM, Wbp, bih, bhh);
  }

  // ---- BatchNorm stats + fully fused head (BN apply + both GEMMs) ----
  zero_f32<<<2, blk, 0, stream>>>(sums, 512);
  bn_stats<<<(N_NODES + 127) / 128, blk, 0, stream>>>(x, sums);
  bn_finalize<<<1, 128, 0, stream>>>(sums, gamma, beta);
  head_fused<<<dim3(MB, 1), blk, 0, stream>>>(x, h, sums, mlpW, e2, c2, out);
}

// Round 9
// 950.513 us; speedup vs baseline: 1.7173x; 1.0395x over previous
//
#include <hip/hip_runtime.h>
#include <math.h>

#define N_NODES 100000
#define N_EDGES 3200000
#define HDIM 128

// ---- bucket sort CSR build ----
#define NB 196        // buckets of 512 consecutive dst nodes (100000/512 -> 196)
#define BSH 9         // 512 nodes per bucket
#define BSLOT 18432   // tmp slots per bucket (avg fill 16327, +16 sigma headroom)

typedef __attribute__((ext_vector_type(8))) short bf16x8;
typedef __attribute__((ext_vector_type(4))) float f32x4;

__device__ __forceinline__ unsigned short f2bf(float f) {
  union { float f; unsigned u; } v; v.f = f;
  unsigned r = v.u + 0x7fffu + ((v.u >> 16) & 1u);
  return (unsigned short)(r >> 16);
}
__device__ __forceinline__ float bflo(unsigned p) {
  union { unsigned u; float f; } v; v.u = p << 16; return v.f;
}
__device__ __forceinline__ float bfhi(unsigned p) {
  union { unsigned u; float f; } v; v.u = p & 0xffff0000u; return v.f;
}
// fast sigmoid/tanh: v_exp + v_rcp (approx err ~1e-6 << bf16 quantum 4e-3
// already present in the data path).
__device__ __forceinline__ float fsigmoid(float v) {
  return __builtin_amdgcn_rcpf(1.f + __expf(-v));
}
__device__ __forceinline__ float ftanh(float v) {
  return 1.f - 2.f * __builtin_amdgcn_rcpf(1.f + __expf(2.f * v));
}

// ---------------------------------------------------------------------------
__global__ __launch_bounds__(256) void zero_i32(int* __restrict__ p, int n) {
  int i = blockIdx.x * 256 + threadIdx.x;
  if (i < n) p[i] = 0;
}
__global__ __launch_bounds__(256) void zero_f32(float* __restrict__ p, int n) {
  int i = blockIdx.x * 256 + threadIdx.x;
  if (i < n) p[i] = 0.f;
}

// ---------------------------------------------------------------------------
// Repack a [384][128] fp32 weight matrix (row-major [col][k]) into
// MFMA-B-fragment-ordered bf16 (lane*16B contiguous per fragment).
// ---------------------------------------------------------------------------
__global__ __launch_bounds__(256) void repack_frag_b(
    const float* __restrict__ src, short* __restrict__ dst)
{
  int o = blockIdx.x * 256 + threadIdx.x;      // 0 .. 384*128-1
  if (o >= 384 * 128) return;
  int j    = o & 7;
  int lane = (o >> 3) & 63;
  int ks   = (o >> 9) & 3;
  int t    = o >> 11;
  int m  = lane & 15;
  int g4 = lane >> 4;
  dst[o] = (short)f2bf(src[(t * 16 + m) * 128 + ks * 32 + g4 * 8 + j]);
}

// ---------------------------------------------------------------------------
// Tiled fp32 GEMM, K fixed at 128 (emb, weight folds). Optional bf16-pack
// epilogue mirror (xpack != nullptr -> also emit packed bf16 rows).
// ---------------------------------------------------------------------------
template<bool BT>
__global__ __launch_bounds__(256) void gemm_k128(
    const float* __restrict__ A, const float* __restrict__ W,
    const float* __restrict__ bias, float* __restrict__ Y,
    unsigned* __restrict__ xpack, int M, int OUT)
{
  __shared__ alignas(16) float lds_a[32 * 68];
  __shared__ alignas(16) float lds_b[32 * 132];
  const int tid = threadIdx.x;
  const int tx = tid & 15;
  const int ty = tid >> 4;
  const int rowBase = blockIdx.x * 64;
  const int colBase = blockIdx.y * 128;

  float acc[4][8];
#pragma unroll
  for (int r = 0; r < 4; r++)
#pragma unroll
    for (int c = 0; c < 8; c++) acc[r][c] = 0.f;

  for (int k0 = 0; k0 < 128; k0 += 32) {
#pragma unroll
    for (int i = 0; i < 2; i++) {
      int idx = tid + i * 256;
      int r   = idx >> 3;
      int kk  = (idx & 7) << 2;
      int gr  = rowBase + r;
      float4 v = make_float4(0.f, 0.f, 0.f, 0.f);
      if (gr < M) v = *(const float4*)(A + (size_t)gr * HDIM + k0 + kk);
      lds_a[(kk + 0) * 68 + r] = v.x;
      lds_a[(kk + 1) * 68 + r] = v.y;
      lds_a[(kk + 2) * 68 + r] = v.z;
      lds_a[(kk + 3) * 68 + r] = v.w;
    }
    if (!BT) {
#pragma unroll
      for (int i = 0; i < 4; i++) {
        int idx = tid + i * 256;
        int kk  = idx >> 5;
        int j   = (idx & 31) << 2;
        int gj  = colBase + j;
        float4 v = make_float4(0.f, 0.f, 0.f, 0.f);
        if (gj < OUT) v = *(const float4*)(W + (size_t)(k0 + kk) * OUT + gj);
        *((float4*)&lds_b[kk * 132 + j]) = v;
      }
    } else {
#pragma unroll
      for (int i = 0; i < 4; i++) {
        int idx = tid + i * 256;
        int j   = idx >> 3;
        int k4  = (idx & 7) << 2;
        int gj  = colBase + j;
        float4 v = make_float4(0.f, 0.f, 0.f, 0.f);
        if (gj < OUT) v = *(const float4*)(W + (size_t)gj * HDIM + k0 + k4);
        lds_b[(k4 + 0) * 132 + j] = v.x;
        lds_b[(k4 + 1) * 132 + j] = v.y;
        lds_b[(k4 + 2) * 132 + j] = v.z;
        lds_b[(k4 + 3) * 132 + j] = v.w;
      }
    }
    __syncthreads();
#pragma unroll 8
    for (int kk = 0; kk < 32; kk++) {
      float4 a4 = *(const float4*)&lds_a[kk * 68 + ty * 4];
      float4 b0 = *(const float4*)&lds_b[kk * 132 + tx * 8];
      float4 b1 = *(const float4*)&lds_b[kk * 132 + tx * 8 + 4];
      float av[4] = {a4.x, a4.y, a4.z, a4.w};
      float bv[8] = {b0.x, b0.y, b0.z, b0.w, b1.x, b1.y, b1.z, b1.w};
#pragma unroll
      for (int r = 0; r < 4; r++)
#pragma unroll
        for (int c = 0; c < 8; c++)
          acc[r][c] = fmaf(av[r], bv[c], acc[r][c]);
    }
    __syncthreads();
  }

  int col = colBase + tx * 8;
  if (col >= OUT) return;
  float bv[8];
#pragma unroll
  for (int c = 0; c < 8; c++) bv[c] = bias ? bias[col + c] : 0.f;
#pragma unroll
  for (int r = 0; r < 4; r++) {
    int gr = rowBase + ty * 4 + r;
    if (gr >= M) continue;
    float* yp = Y + (size_t)gr * OUT + col;
    float4 o0 = make_float4(acc[r][0] + bv[0], acc[r][1] + bv[1],
                            acc[r][2] + bv[2], acc[r][3] + bv[3]);
    float4 o1 = make_float4(acc[r][4] + bv[4], acc[r][5] + bv[5],
                            acc[r][6] + bv[6], acc[r][7] + bv[7]);
    *(float4*)yp       = o0;
    *(float4*)(yp + 4) = o1;
    if (xpack) {                       // packed bf16 mirror (emb path)
      uint4 p;
      p.x = (unsigned)f2bf(o0.x) | ((unsigned)f2bf(o0.y) << 16);
      p.y = (unsigned)f2bf(o0.z) | ((unsigned)f2bf(o0.w) << 16);
      p.z = (unsigned)f2bf(o1.x) | ((unsigned)f2bf(o1.y) << 16);
      p.w = (unsigned)f2bf(o1.z) | ((unsigned)f2bf(o1.w) << 16);
      *(uint4*)&xpack[(size_t)gr * 64 + (col >> 1)] = p;
    }
  }
}

// ---------------------------------------------------------------------------
// CSR build, two-pass bucket sort (see round-2 notes: kills the random 8-B
// global scatter and csr_hist's 3.2M random atomics).
// Edge record in tmp: x = src | (local_dst << 17)  (17+9 = 26 bits), y = w.
// Final epak record: x = src << 8 (byte offset of the 256-B xbp row,
// pre-scaled so agg_pull's gather address is a single add), y = w.
// ---------------------------------------------------------------------------
__global__ __launch_bounds__(256) void csr_part1(
    const int* __restrict__ ei, const float* __restrict__ ew,
    int* __restrict__ bcnt,        // [NB*16] padded counters (one line each)
    int2* __restrict__ tmp)        // [NB*BSLOT]
{
  __shared__ int hist[NB];
  __shared__ int gbase[NB];
  const int tid = threadIdx.x;
  for (int i = tid; i < NB; i += 256) hist[i] = 0;
  __syncthreads();
  const int e0 = blockIdx.x * 2048 + tid * 8;   // 8 consecutive edges/thread
  const bool act = (e0 < N_EDGES);              // tail remainder is %8==0
  int4 s0, s1, d0, d1; float4 w0, w1;
  int rb[8];
  if (act) {
    s0 = *(const int4*)(ei + e0);
    s1 = *(const int4*)(ei + e0 + 4);
    d0 = *(const int4*)(ei + N_EDGES + e0);
    d1 = *(const int4*)(ei + N_EDGES + e0 + 4);
    w0 = *(const float4*)(ew + e0);
    w1 = *(const float4*)(ew + e0 + 4);
    int dv[8] = {d0.x, d0.y, d0.z, d0.w, d1.x, d1.y, d1.z, d1.w};
#pragma unroll
    for (int j = 0; j < 8; j++) {
      int b = dv[j] >> BSH;
      int r = atomicAdd(&hist[b], 1);
      rb[j] = (r << 8) | b;                     // rank<2048 (11b), b<196 (8b)
    }
  }
  __syncthreads();
  for (int i = tid; i < NB; i += 256) {
    int c = hist[i];
    gbase[i] = c ? atomicAdd(&bcnt[i * 16], c) : 0;  // one reserve per bucket
  }
  __syncthreads();
  if (act) {
    int sv[8] = {s0.x, s0.y, s0.z, s0.w, s1.x, s1.y, s1.z, s1.w};
    int dv[8] = {d0.x, d0.y, d0.z, d0.w, d1.x, d1.y, d1.z, d1.w};
    int wv[8] = {__float_as_int(w0.x), __float_as_int(w0.y),
                 __float_as_int(w0.z), __float_as_int(w0.w),
                 __float_as_int(w1.x), __float_as_int(w1.y),
                 __float_as_int(w1.z), __float_as_int(w1.w)};
#pragma unroll
    for (int j = 0; j < 8; j++) {
      int b  = rb[j] & 255;
      int of = gbase[b] + (rb[j] >> 8);
      if (of < BSLOT)                            // memory-safety guard only
        tmp[b * BSLOT + of] =
            make_int2(sv[j] | ((dv[j] & 511) << 17), wv[j]);
    }
  }
}

// exclusive scan of bucket counts -> bucket start offsets; rowptr[N] = E
__global__ void csr_scanb(const int* __restrict__ bcnt,
                          int* __restrict__ bstart, int* __restrict__ rowptr)
{
  __shared__ int l[256];
  int t = threadIdx.x;
  int v = (t < NB) ? min(bcnt[t * 16], BSLOT) : 0;
  l[t] = v;
  __syncthreads();
  for (int off = 1; off < 256; off <<= 1) {
    int u = (t >= off) ? l[t - off] : 0;
    __syncthreads();
    l[t] += u;
    __syncthreads();
  }
  if (t < NB) bstart[t] = l[t] - v;
  if (t == 255) rowptr[N_NODES] = l[255];
}

// per bucket: LDS node-hist -> LDS scan -> rowptr slice (coalesced) ->
// final in-bucket placement (reads+writes stay in ~130 KB, L2-resident).
__global__ __launch_bounds__(256) void csr_part2(
    const int2* __restrict__ tmp, const int* __restrict__ bcnt,
    const int* __restrict__ bstart, int* __restrict__ rowptr,
    int2* __restrict__ epak)
{
  __shared__ int cnt[512];
  __shared__ int lofs[512];
  __shared__ int s2[256];
  const int b      = blockIdx.x;
  const int tid    = threadIdx.x;
  const int nbase  = b << BSH;
  const int nn     = min(512, N_NODES - nbase);
  const int ecount = min(bcnt[b * 16], BSLOT);
  const long tbase = (long)b * BSLOT;
  const int obase  = bstart[b];
  for (int i = tid; i < 512; i += 256) cnt[i] = 0;
  __syncthreads();
  // pass A: per-node histogram of this bucket
  for (int e = tid; e < ecount; e += 256) {
    int2 rec = tmp[tbase + e];
    atomicAdd(&cnt[(rec.x >> 17) & 511], 1);
  }
  __syncthreads();
  // exclusive scan over 512 node counts (pairs + Hillis-Steele on 256)
  int c0 = cnt[2 * tid], c1 = cnt[2 * tid + 1];
  s2[tid] = c0 + c1;
  __syncthreads();
  int inc = s2[tid];
  for (int off = 1; off < 256; off <<= 1) {
    int u = (tid >= off) ? s2[tid - off] : 0;
    __syncthreads();
    s2[tid] += u;
    __syncthreads();
  }
  int ex = s2[tid] - inc;
  lofs[2 * tid]     = ex;
  lofs[2 * tid + 1] = ex + c0;
  __syncthreads();
  // rowptr slice, coalesced (replaces csr_hist + global scan entirely)
  for (int i = tid; i < nn; i += 256) rowptr[nbase + i] = obase + lofs[i];
  for (int i = tid; i < 512; i += 256) cnt[i] = 0;
  __syncthreads();
  // pass B: place edges at final CSR positions (within-row order arbitrary).
  // src is pre-scaled to its xbp byte offset (src*256) for agg_pull.
  for (int e = tid; e < ecount; e += 256) {
    int2 rec = tmp[tbase + e];
    int ldst = (rec.x >> 17) & 511;
    int r = atomicAdd(&cnt[ldst], 1);
    epak[obase + lofs[ldst] + r] = make_int2((rec.x & 0x1FFFF) << 8, rec.y);
  }
}

// ---------------------------------------------------------------------------
// Pull aggregation on bf16 x: z[n] = sum w_e * x[src_e], fp32 accumulate,
// bf16 packed output. One wave/node, lane covers cols {2*lane, 2*lane+1}.
// v3 (scalar path): node is readfirstlane-anchored -> rowptr/e/epak are
// wave-uniform, so the edge stream compiles to s_load (constant cache,
// SALU bookkeeping) and leaves the vector-memory pipe to the gathers.
// ---------------------------------------------------------------------------
__global__ __launch_bounds__(256) void agg_pull(
    const unsigned* __restrict__ xbp, const int* __restrict__ rowptr,
    const int2* __restrict__ epak, unsigned* __restrict__ zbp)
{
  const int node =
      __builtin_amdgcn_readfirstlane(blockIdx.x * 4 + (threadIdx.x >> 6));
  const int lane = threadIdx.x & 63;
  const unsigned lane4 = lane * 4;
  const char* xbc = (const char*)xbp;
  int e = rowptr[node];
  const int s1 = rowptr[node + 1];
  float v0 = 0.f, v1 = 0.f;
  // alignment pre-step: make e even so int4 loads on epak are 16-B aligned
  if ((e & 1) && e < s1) {
    int2 ep = epak[e++];
    unsigned p = *(const unsigned*)(xbc + (unsigned)ep.x + lane4);
    float w = __int_as_float(ep.y);
    v0 = fmaf(w, bflo(p), v0); v1 = fmaf(w, bfhi(p), v1);
  }
  const int n16 = e + ((s1 - e) & ~15);
  for (; e < n16; e += 16) {
    int4 q[8];
#pragma unroll
    for (int j = 0; j < 8; j++) q[j] = *(const int4*)(epak + e + 2 * j);
    unsigned p[16];
#pragma unroll
    for (int j = 0; j < 8; j++) {
      p[2 * j]     = *(const unsigned*)(xbc + (unsigned)q[j].x + lane4);
      p[2 * j + 1] = *(const unsigned*)(xbc + (unsigned)q[j].z + lane4);
    }
#pragma unroll
    for (int j = 0; j < 8; j++) {
      float wa = __int_as_float(q[j].y), wb = __int_as_float(q[j].w);
      v0 = fmaf(wa, bflo(p[2 * j]), v0);
      v1 = fmaf(wa, bfhi(p[2 * j]), v1);
      v0 = fmaf(wb, bflo(p[2 * j + 1]), v0);
      v1 = fmaf(wb, bfhi(p[2 * j + 1]), v1);
    }
  }
  const int n4 = e + ((s1 - e) & ~3);
  for (; e < n4; e += 4) {
    int4 qa = *(const int4*)(epak + e);
    int4 qb = *(const int4*)(epak + e + 2);
    unsigned p0 = *(const unsigned*)(xbc + (unsigned)qa.x + lane4);
    unsigned p1 = *(const unsigned*)(xbc + (unsigned)qa.z + lane4);
    unsigned p2 = *(const unsigned*)(xbc + (unsigned)qb.x + lane4);
    unsigned p3 = *(const unsigned*)(xbc + (unsigned)qb.z + lane4);
    float w0 = __int_as_float(qa.y), w1 = __int_as_float(qa.w);
    float w2 = __int_as_float(qb.y), w3 = __int_as_float(qb.w);
    v0 = fmaf(w0, bflo(p0), v0); v1 = fmaf(w0, bfhi(p0), v1);
    v0 = fmaf(w1, bflo(p1), v0); v1 = fmaf(w1, bfhi(p1), v1);
    v0 = fmaf(w2, bflo(p2), v0); v1 = fmaf(w2, bfhi(p2), v1);
    v0 = fmaf(w3, bflo(p3), v0); v1 = fmaf(w3, bfhi(p3), v1);
  }
  for (; e < s1; e++) {
    int2 ep = epak[e];
    unsigned p = *(const unsigned*)(xbc + (unsigned)ep.x + lane4);
    float w = __int_as_float(ep.y);
    v0 = fmaf(w, bflo(p), v0); v1 = fmaf(w, bfhi(p), v1);
  }
  zbp[(size_t)node * 64 + lane] =
      (unsigned)f2bf(v0) | ((unsigned)f2bf(v1) << 16);
}

// ---------------------------------------------------------------------------
// Fused GRU layer (bf16 MFMA), v3 partition: block = 32 rows (2 row-tiles),
// 4 waves each own 2 t-column-tiles for all 32 rows. Accumulators:
// 2rt x 2ti x 4 sets = 64 VGPR. launch_bounds(256,4) caps at 128 VGPR.
// 32 | 100000 exactly -> no row guards. Fast sigmoid/tanh (see helpers).
// ---------------------------------------------------------------------------
__global__ __launch_bounds__(256, 4) void gru_fused(
    const short* __restrict__ zb, short* __restrict__ xb,
    float* __restrict__ x,
    const short* __restrict__ Fb, const short* __restrict__ Wb,
    const float* __restrict__ bih, const float* __restrict__ bhh)
{
  const int wave = threadIdx.x >> 6, lane = threadIdx.x & 63;
  const int m  = lane & 15;
  const int g4 = lane >> 4;
  const int rowBase = blockIdx.x * 32;
  const int t0 = wave * 2;                 // this wave's t-pair (cols t0*16..)

  f32x4 aR[2][2], aZ[2][2], aN[2][2], aH[2][2];
#pragma unroll
  for (int rt = 0; rt < 2; rt++)
#pragma unroll
    for (int ti = 0; ti < 2; ti++) {
      aR[rt][ti] = (f32x4){0.f, 0.f, 0.f, 0.f};
      aZ[rt][ti] = (f32x4){0.f, 0.f, 0.f, 0.f};
      aN[rt][ti] = (f32x4){0.f, 0.f, 0.f, 0.f};
      aH[rt][ti] = (f32x4){0.f, 0.f, 0.f, 0.f};
    }

  size_t arowc[2];
#pragma unroll
  for (int rt = 0; rt < 2; rt++)
    arowc[rt] = (size_t)(rowBase + rt * 16 + m) * 128 + g4 * 8;

  // ---- phase 0: z @ F -> r,z,i_n ----
#pragma unroll
  for (int ks = 0; ks < 4; ks++) {
    bf16x8 a[2];
#pragma unroll
    for (int rt = 0; rt < 2; rt++)
      a[rt] = *(const bf16x8*)(zb + arowc[rt] + ks * 32);
    const int bo = ks * 512 + lane * 8;
#pragma unroll
    for (int ti = 0; ti < 2; ti++) {
      const short* bp = Fb + (t0 + ti) * 2048 + bo;
      bf16x8 br = *(const bf16x8*)(bp);
      bf16x8 bz = *(const bf16x8*)(bp + 16384);
      bf16x8 bn = *(const bf16x8*)(bp + 32768);
#pragma unroll
      for (int rt = 0; rt < 2; rt++) {
        aR[rt][ti] = __builtin_amdgcn_mfma_f32_16x16x32_bf16(a[rt], br, aR[rt][ti], 0, 0, 0);
        aZ[rt][ti] = __builtin_amdgcn_mfma_f32_16x16x32_bf16(a[rt], bz, aZ[rt][ti], 0, 0, 0);
        aN[rt][ti] = __builtin_amdgcn_mfma_f32_16x16x32_bf16(a[rt], bn, aN[rt][ti], 0, 0, 0);
      }
    }
  }
  // ---- phase 1: x @ Whh^T -> r,z,h_n ----
#pragma unroll
  for (int ks = 0; ks < 4; ks++) {
    bf16x8 a[2];
#pragma unroll
    for (int rt = 0; rt < 2; rt++)
      a[rt] = *(const bf16x8*)(xb + arowc[rt] + ks * 32);
    const int bo = ks * 512 + lane * 8;
#pragma unroll
    for (int ti = 0; ti < 2; ti++) {
      const short* bp = Wb + (t0 + ti) * 2048 + bo;
      bf16x8 br = *(const bf16x8*)(bp);
      bf16x8 bz = *(const bf16x8*)(bp + 16384);
      bf16x8 bn = *(const bf16x8*)(bp + 32768);
#pragma unroll
      for (int rt = 0; rt < 2; rt++) {
        aR[rt][ti] = __builtin_amdgcn_mfma_f32_16x16x32_bf16(a[rt], br, aR[rt][ti], 0, 0, 0);
        aZ[rt][ti] = __builtin_amdgcn_mfma_f32_16x16x32_bf16(a[rt], bz, aZ[rt][ti], 0, 0, 0);
        aH[rt][ti] = __builtin_amdgcn_mfma_f32_16x16x32_bf16(a[rt], bn, aH[rt][ti], 0, 0, 0);
      }
    }
  }

  // ---- epilogue: gates + state update (C/D: col=lane&15, row=g4*4+reg) ----
  // prefetch all 16 x_old values first so VMEM latency overlaps gate VALU
  float xo[2][2][4];
  size_t xoff[2][2];
#pragma unroll
  for (int ti = 0; ti < 2; ti++)
#pragma unroll
    for (int rt = 0; rt < 2; rt++) {
      size_t o = (size_t)(rowBase + rt * 16 + g4 * 4) * 128 + (t0 + ti) * 16 + m;
      xoff[ti][rt] = o;
#pragma unroll
      for (int r = 0; r < 4; r++) xo[ti][rt][r] = x[o + (size_t)r * 128];
    }
#pragma unroll
  for (int ti = 0; ti < 2; ti++) {
    int col = (t0 + ti) * 16 + m;
    float b_r = bih[col] + bhh[col];
    float b_z = bih[128 + col] + bhh[128 + col];
    float b_i = bih[256 + col];
    float b_h = bhh[256 + col];
#pragma unroll
    for (int rt = 0; rt < 2; rt++) {
#pragma unroll
      for (int r = 0; r < 4; r++) {
        float rg = fsigmoid(aR[rt][ti][r] + b_r);
        float zg = fsigmoid(aZ[rt][ti][r] + b_z);
        float ng = ftanh(aN[rt][ti][r] + b_i + rg * (aH[rt][ti][r] + b_h));
        float xn = (1.f - zg) * ng + zg * xo[ti][rt][r];
        size_t o = xoff[ti][rt] + (size_t)r * 128;
        x[o] = xn;
        xb[o] = (short)f2bf(xn);
      }
    }
  }
}

// ---------------------------------------------------------------------------
// BatchNorm stats (fp32 master x)
// ---------------------------------------------------------------------------
__global__ __launch_bounds__(256) void bn_stats(
    const float* __restrict__ x, float* __restrict__ sums)
{
  __shared__ float ls[256], lq[256];
  int tid  = threadIdx.x;
  int col  = tid & 127, half = tid >> 7;
  int r0   = blockIdx.x * 128;
  int rend = min(N_NODES, r0 + 128);
  float s = 0.f, q = 0.f;
  for (int r = r0 + half; r < rend; r += 2) {
    float v = x[(size_t)r * HDIM + col];
    s += v; q += v * v;
  }
  ls[tid] = s; lq[tid] = q;
  __syncthreads();
  if (tid < 128) {
    atomicAdd(&sums[col],       ls[tid] + ls[tid + 128]);
    atomicAdd(&sums[128 + col], lq[tid] + lq[tid + 128]);
  }
}

__global__ void bn_finalize(float* __restrict__ sums,
                            const float* __restrict__ gamma,
                            const float* __restrict__ beta)
{
  int j = threadIdx.x;
  float mean = sums[j] / (float)N_NODES;
  float var  = sums[128 + j] / (float)N_NODES - mean * mean;
  float inv  = rsqrtf(var + 1e-5f);
  sums[256 + j] = gamma[j] * inv;
  sums[384 + j] = beta[j] - mean * gamma[j] * inv;
}

// ---------------------------------------------------------------------------
// Fused head v2: out = bn(x) @ mlpW + h @ e2 + c2.
// Old version: 128-wide col tile (only 40 cols real -> 69% wasted FMAs) and
// lds_b reads at 32-B lane stride -> 4-way bank conflict (1.52e7 measured).
// New: B is tiny (2 x 128 x 40 = 40 KB) -> load BOTH weights to LDS once.
// Block = 256 rows; thread (tx 0..7, ty 0..31) owns 8 rows x 5 cols
// ({tx*4..+3} via b128: 8 tx x 4 banks = all 32 banks once, conflict-free;
// + col 32+tx via b32: 8 consecutive banks). A staged per 32-k chunk with
// stride 260 (b128-aligned, 2-way-free reads). Same k accumulation order
// as v1 -> bit-identical output. LDS 78336 B/wg (gfx950 allows up to 160K).
// ---------------------------------------------------------------------------
__global__ __launch_bounds__(256) void head_fused(
    const float* __restrict__ x, const float* __restrict__ h,
    const float* __restrict__ sums,      // scale at [256..], shift at [384..]
    const float* __restrict__ mlpW,      // [128][40]
    const float* __restrict__ e2,        // [128][40]
    const float* __restrict__ c2,        // [40]
    float* __restrict__ out)             // [N][40]
{
  __shared__ alignas(16) float lds_b[2][128][44];   // 45056 B
  __shared__ alignas(16) float lds_a[32 * 260];     // 33280 B
  const int tid = threadIdx.x;
  const int tx = tid & 7;          // col group: cols {tx*4..+3, 32+tx}
  const int ty = tid >> 3;         // row group: rows {ty*8..+7}
  const int rowBase = blockIdx.x * 256;

  // load both B matrices once (coalesced; barrier below covers first use)
  for (int i = tid; i < 128 * 40; i += 256) {
    int kk = i / 40, j = i - kk * 40;
    lds_b[0][kk][j] = mlpW[i];
    lds_b[1][kk][j] = e2[i];
  }

  float acc[8][5];
#pragma unroll
  for (int r = 0; r < 8; r++)
#pragma unroll
    for (int c = 0; c < 5; c++) acc[r][c] = 0.f;

  for (int src = 0; src < 2; src++) {
    const float* A = src ? h : x;
    for (int k0 = 0; k0 < 128; k0 += 32) {
      __syncthreads();               // prev-iter readers done (+ B ready)
#pragma unroll
      for (int i = 0; i < 8; i++) {
        int idx = tid + i * 256;
        int r   = idx >> 3;          // 0..255
        int kk  = (idx & 7) << 2;
        int gr  = rowBase + r;
        float4 v = make_float4(0.f, 0.f, 0.f, 0.f);
        if (gr < N_NODES) v = *(const float4*)(A + (size_t)gr * HDIM + k0 + kk);
        if (src == 0) {              // fold BatchNorm apply into x tile load
          float4 sc = *(const float4*)(sums + 256 + k0 + kk);
          float4 sh = *(const float4*)(sums + 384 + k0 + kk);
          v.x = fmaf(v.x, sc.x, sh.x);
          v.y = fmaf(v.y, sc.y, sh.y);
          v.z = fmaf(v.z, sc.z, sh.z);
          v.w = fmaf(v.w, sc.w, sh.w);
        }
        lds_a[(kk + 0) * 260 + r] = v.x;
        lds_a[(kk + 1) * 260 + r] = v.y;
        lds_a[(kk + 2) * 260 + r] = v.z;
        lds_a[(kk + 3) * 260 + r] = v.w;
      }
      __syncthreads();
#pragma unroll 4
      for (int kk = 0; kk < 32; kk++) {
        float4 b4 = *(const float4*)&lds_b[src][k0 + kk][tx * 4];
        float  b1 = lds_b[src][k0 + kk][32 + tx];
        float4 a0 = *(const float4*)&lds_a[kk * 260 + ty * 8];
        float4 a1 = *(const float4*)&lds_a[kk * 260 + ty * 8 + 4];
        float av[8] = {a0.x, a0.y, a0.z, a0.w, a1.x, a1.y, a1.z, a1.w};
#pragma unroll
        for (int r = 0; r < 8; r++) {
          acc[r][0] = fmaf(av[r], b4.x, acc[r][0]);
          acc[r][1] = fmaf(av[r], b4.y, acc[r][1]);
          acc[r][2] = fmaf(av[r], b4.z, acc[r][2]);
          acc[r][3] = fmaf(av[r], b4.w, acc[r][3]);
          acc[r][4] = fmaf(av[r], b1,   acc[r][4]);
        }
      }
    }
  }

  const int c0 = tx * 4, c4 = 32 + tx;
  float bv0 = c2[c0], bv1 = c2[c0 + 1], bv2 = c2[c0 + 2], bv3 = c2[c0 + 3];
  float bv4 = c2[c4];
#pragma unroll
  for (int r = 0; r < 8; r++) {
    int gr = rowBase + ty * 8 + r;
    if (gr >= N_NODES) continue;
    float* yp = out + (size_t)gr * 40;
    float4 o = make_float4(acc[r][0] + bv0, acc[r][1] + bv1,
                           acc[r][2] + bv2, acc[r][3] + bv3);
    *(float4*)(yp + c0) = o;
    yp[c4] = acc[r][4] + bv4;
  }
}

// ---------------------------------------------------------------------------
// Residual fold constants: E2 = embW @ mlpW  [128][40], c2 = mlpB + embB@mlpW
// v2: one output per thread; data L2-hot; bit-identical fmaf chain.
// ---------------------------------------------------------------------------
__global__ __launch_bounds__(256) void prep_e2(
    const float* __restrict__ embW,
    const float* __restrict__ embB,
    const float* __restrict__ mlpW,
    const float* __restrict__ mlpB,
    float* __restrict__ e2, float* __restrict__ c2)
{
  int idx = blockIdx.x * 256 + threadIdx.x;
  if (idx < 5120) {
    int f = idx / 40, j = idx - f * 40;
    const float* er = embW + f * 128;
    float s = 0.f;
    for (int k = 0; k < 128; k++)
      s = fmaf(er[k], mlpW[k * 40 + j], s);
    e2[idx] = s;
  } else if (idx < 5160) {
    int j = idx - 5120;
    float s = mlpB[j];
    for (int k = 0; k < 128; k++)
      s = fmaf(embB[k], mlpW[k * 40 + j], s);
    c2[j] = s;
  }
}

// ---------------------------------------------------------------------------
extern "C" void kernel_launch(void* const* d_in, const int* in_sizes, int n_in,
                              void* d_out, int out_size, void* d_ws, size_t ws_size,
                              hipStream_t stream)
{
  const float* h     = (const float*)d_in[0];
  const int*   ei    = (const int*)d_in[1];
  const float* ew    = (const float*)d_in[2];
  const float* embW  = (const float*)d_in[3];
  const float* embB  = (const float*)d_in[4];
  const float* convW = (const float*)d_in[5];   // [3][128][128]
  const float* Wih   = (const float*)d_in[6];   // [384][128]
  const float* Whh   = (const float*)d_in[7];   // [384][128]
  const float* bih   = (const float*)d_in[8];
  const float* bhh   = (const float*)d_in[9];
  const float* gamma = (const float*)d_in[10];
  const float* beta  = (const float*)d_in[11];
  const float* mlpW  = (const float*)d_in[12];
  const float* mlpB  = (const float*)d_in[13];
  float* out = (float*)d_out;

  float* ws = (float*)d_ws;
  const size_t NH = (size_t)N_NODES * HDIM;      // 12.8M
  float*    x      = ws;                          // [N][128] fp32 master
  unsigned* xbp    = (unsigned*)(ws + NH);        // [N][64] packed bf16
  unsigned* zbp    = xbp + NH / 2;                // [N][64] packed bf16
  int2*     epak   = (int2*)(zbp + NH / 2);       // [E] {src_byteoff, w}
  int*      rowptr = (int*)(epak + N_EDGES);      // N+4
  int*      bcnt   = rowptr + N_NODES + 4;        // NB*16 padded counters
  int*      bstart = bcnt + NB * 16;              // NB (+pad)
  float*    Ffold  = (float*)(bstart + 256);      // [3][384][128] fp32
  short*    Fbp    = (short*)(Ffold + 3 * 384 * 128);  // frag-order bf16
  short*    Wbp    = Fbp + 3 * 384 * 128;         // frag-order bf16 of Whh
  float*    sums   = (float*)(Wbp + 384 * 128);
  float*    e2     = sums + 512;
  float*    c2     = e2 + 5120;
  // csr scratch: tmp [NB*BSLOT] int2 = 27.6 MB aliases xbp+zbp (both dead
  // until after the embedding GEMM / first agg_pull).
  int2*     tmp    = (int2*)xbp;

  dim3 blk(256);
  const int MB = (N_NODES + 63) / 64;
  const int GB = N_NODES / 32;                    // 3125, exact
  const int HB = (N_NODES + 255) / 256;           // 391
  const int RB = (384 * 128 + 255) / 256;
  const int P1B = (N_EDGES + 2047) / 2048;        // 1563 (tail %8 == 0)

  // ---- constants ----
  prep_e2<<<21, blk, 0, stream>>>(embW, embB, mlpW, mlpB, e2, c2);
  for (int l = 0; l < 3; l++)
    gemm_k128<true><<<dim3(6, 1), blk, 0, stream>>>(
        Wih, convW + (size_t)l * HDIM * HDIM, nullptr,
        Ffold + (size_t)l * 384 * HDIM, nullptr, 384, 128);
  for (int l = 0; l < 3; l++)
    repack_frag_b<<<RB, blk, 0, stream>>>(
        Ffold + (size_t)l * 384 * HDIM, Fbp + (size_t)l * 384 * HDIM);
  repack_frag_b<<<RB, blk, 0, stream>>>(Whh, Wbp);

  // ---- CSR build: bucket partition -> per-bucket place (no global scatter)
  zero_i32<<<(NB * 16 + 255) / 256, blk, 0, stream>>>(bcnt, NB * 16);
  csr_part1<<<P1B, blk, 0, stream>>>(ei, ew, bcnt, tmp);
  csr_scanb<<<1, 256, 0, stream>>>(bcnt, bstart, rowptr);
  csr_part2<<<NB, blk, 0, stream>>>(tmp, bcnt, bstart, rowptr, epak);

  // ---- embedding: x = h @ embW + embB ; bf16 mirror fused in epilogue ----
  gemm_k128<false><<<dim3(MB, 1), blk, 0, stream>>>(h, embW, embB, x, xbp,
                                                    N_NODES, 128);

  // ---- 3 GRU layers: pull-agg (bf16) + fused MFMA GRU ----
  for (int l = 0; l < 3; l++) {
    agg_pull<<<N_NODES / 4, blk, 0, stream>>>(xbp, rowptr, epak, zbp);
    gru_fused<<<GB, blk, 0, stream>>>(
        (const short*)zbp, (short*)xbp, x,
        Fbp + (size_t)l * 384 * HDIM, Wbp, bih, bhh);
  }

  // ---- BatchNorm stats + fully fused head (BN apply + both GEMMs) ----
  zero_f32<<<2, blk, 0, stream>>>(sums, 512);
  bn_stats<<<(N_NODES + 127) / 128, blk, 0, stream>>>(x, sums);
  bn_finalize<<<1, 128, 0, stream>>>(sums, gamma, beta);
  head_fused<<<HB, blk, 0, stream>>>(x, h, sums, mlpW, e2, c2, out);
}